// Round 11
// baseline (438.444 us; speedup 1.0000x reference)
//
#include <hip/hip_runtime.h>
#include <hip/hip_fp16.h>
#include <math.h>

#define N 4096
#define C 512
#define H 128
#define PAD 40  // ushort row pitch for 32-col MFMA LDS staging tiles
#define WP 136  // ushort row pitch for full-K (128 col) LDS tiles
#define FWP 136 // ushort row pitch for flash Q/P tiles
#define SP 136  // ushort row pitch for S-tile scan buffer

typedef __attribute__((ext_vector_type(8))) short bf16x8;
typedef __attribute__((ext_vector_type(4))) float f32x4;

// ---------------- helpers ----------------

__device__ inline float wave_reduce_sum(float v) {
#pragma unroll
  for (int m = 32; m; m >>= 1) v += __shfl_xor(v, m);
  return v;
}

__device__ inline float lrelu(float v) { return v > 0.f ? v : 0.01f * v; }

__device__ inline bool better(float v, int j, float w, int k) {
  return (v > w) || (v == w && j < k);
}

__device__ inline void top3_ins(float v, int j, float& v0, int& j0,
                                float& v1, int& j1, float& v2, int& j2) {
  if (better(v, j, v0, j0)) { v2 = v1; j2 = j1; v1 = v0; j1 = j0; v0 = v; j0 = j; }
  else if (better(v, j, v1, j1)) { v2 = v1; j2 = j1; v1 = v; j1 = j; }
  else if (better(v, j, v2, j2)) { v2 = v; j2 = j; }
}

__device__ inline void ins5(float s, int j, float v[5], int jx[5]) {
  if (!better(s, j, v[4], jx[4])) return;
  if (better(s, j, v[0], jx[0])) {
    v[4]=v[3]; jx[4]=jx[3]; v[3]=v[2]; jx[3]=jx[2]; v[2]=v[1]; jx[2]=jx[1];
    v[1]=v[0]; jx[1]=jx[0]; v[0]=s; jx[0]=j;
  } else if (better(s, j, v[1], jx[1])) {
    v[4]=v[3]; jx[4]=jx[3]; v[3]=v[2]; jx[3]=jx[2]; v[2]=v[1]; jx[2]=jx[1];
    v[1]=s; jx[1]=j;
  } else if (better(s, j, v[2], jx[2])) {
    v[4]=v[3]; jx[4]=jx[3]; v[3]=v[2]; jx[3]=jx[2]; v[2]=s; jx[2]=j;
  } else if (better(s, j, v[3], jx[3])) {
    v[4]=v[3]; jx[4]=jx[3]; v[3]=s; jx[3]=j;
  } else {
    v[4]=s; jx[4]=j;
  }
}

__device__ inline unsigned short f2bf(float f) {
  unsigned u = __float_as_uint(f);
  unsigned r = u + 0x7fffu + ((u >> 16) & 1u);
  return (unsigned short)(r >> 16);
}
__device__ inline float bf2f(unsigned short h) {
  return __uint_as_float(((unsigned)h) << 16);
}

// ---- x prep: linear pairs + xnorm + transposed pairs + workspace zeroing ----
__global__ __launch_bounds__(256) void k_xprep(
    const float* __restrict__ in, unsigned short* __restrict__ hi,
    unsigned short* __restrict__ lo, float* __restrict__ nrm,
    unsigned short* __restrict__ thi, unsigned short* __restrict__ tlo,
    float* __restrict__ hidden2, float* __restrict__ colsum_c,
    float* __restrict__ colsum_m) {
  __shared__ float tile[32][132];
  int r0 = blockIdx.x * 32, tid = threadIdx.x;
  float4 zf = {0.f, 0.f, 0.f, 0.f};
#pragma unroll
  for (int q = 0; q < 4; q++) {
    size_t zi = ((size_t)blockIdx.x * 1024 + q * 256 + tid) * 4;
    *(float4*)&hidden2[zi] = zf;
  }
  if (blockIdx.x == 0 && tid < 128) *(float4*)&colsum_c[tid * 4] = zf;
  if (blockIdx.x == 1) {
#pragma unroll
    for (int q = 0; q < 4; q++) *(float4*)&colsum_m[(q * 256 + tid) * 4] = zf;
  }
#pragma unroll
  for (int q = 0; q < 4; q++) {
    int f = q * 256 + tid;
    int row = f >> 5, ch = f & 31;
    size_t gi = (size_t)(r0 + row) * 128 + ch * 4;
    float4 v = *(const float4*)&in[gi];
    *(float4*)&tile[row][ch * 4] = v;
    float vv[4] = {v.x, v.y, v.z, v.w};
    unsigned short hq[4], lq[4];
    float ss = 0.f;
#pragma unroll
    for (int c = 0; c < 4; c++) {
      ss += vv[c] * vv[c];
      hq[c] = f2bf(vv[c]);
      lq[c] = f2bf(vv[c] - bf2f(hq[c]));
    }
    uint2 ph = {(unsigned)hq[0] | ((unsigned)hq[1] << 16),
                (unsigned)hq[2] | ((unsigned)hq[3] << 16)};
    uint2 pl = {(unsigned)lq[0] | ((unsigned)lq[1] << 16),
                (unsigned)lq[2] | ((unsigned)lq[3] << 16)};
    *(uint2*)&hi[gi] = ph;
    *(uint2*)&lo[gi] = pl;
#pragma unroll
    for (int m = 16; m; m >>= 1) ss += __shfl_xor(ss, m);
    if ((tid & 31) == 0) nrm[r0 + row] = sqrtf(ss);
  }
  __syncthreads();
  int c = tid & 127, half = tid >> 7;
  unsigned short hh[16], ll[16];
#pragma unroll
  for (int rr = 0; rr < 16; rr++) {
    float v = tile[half * 16 + rr][c];
    hh[rr] = f2bf(v);
    ll[rr] = f2bf(v - bf2f(hh[rr]));
  }
  size_t off = (size_t)c * N + r0 + half * 16;
  uint4 ph0 = {(unsigned)hh[0] | ((unsigned)hh[1] << 16), (unsigned)hh[2] | ((unsigned)hh[3] << 16),
               (unsigned)hh[4] | ((unsigned)hh[5] << 16), (unsigned)hh[6] | ((unsigned)hh[7] << 16)};
  uint4 ph1 = {(unsigned)hh[8] | ((unsigned)hh[9] << 16), (unsigned)hh[10] | ((unsigned)hh[11] << 16),
               (unsigned)hh[12] | ((unsigned)hh[13] << 16), (unsigned)hh[14] | ((unsigned)hh[15] << 16)};
  uint4 pl0 = {(unsigned)ll[0] | ((unsigned)ll[1] << 16), (unsigned)ll[2] | ((unsigned)ll[3] << 16),
               (unsigned)ll[4] | ((unsigned)ll[5] << 16), (unsigned)ll[6] | ((unsigned)ll[7] << 16)};
  uint4 pl1 = {(unsigned)ll[8] | ((unsigned)ll[9] << 16), (unsigned)ll[10] | ((unsigned)ll[11] << 16),
               (unsigned)ll[12] | ((unsigned)ll[13] << 16), (unsigned)ll[14] | ((unsigned)ll[15] << 16)};
  *(uint4*)&thi[off] = ph0; *(uint4*)&thi[off + 8] = ph1;
  *(uint4*)&tlo[off] = pl0; *(uint4*)&tlo[off + 8] = pl1;
}

// transpose + split: in [R,128] fp32 -> thi/tlo [128,R] ushort
__global__ __launch_bounds__(256) void k_tsplit(const float* __restrict__ in,
                                                unsigned short* __restrict__ thi,
                                                unsigned short* __restrict__ tlo,
                                                int R) {
  __shared__ float tile[32][132];
  int r0 = blockIdx.x * 32, tid = threadIdx.x;
#pragma unroll
  for (int q = 0; q < 4; q++) {
    int f = q * 256 + tid;
    int row = f >> 5, ch = f & 31;
    *(float4*)&tile[row][ch * 4] = *(const float4*)&in[(size_t)(r0 + row) * 128 + ch * 4];
  }
  __syncthreads();
  int c = tid & 127, half = tid >> 7;
  unsigned short hh[16], ll[16];
#pragma unroll
  for (int rr = 0; rr < 16; rr++) {
    float v = tile[half * 16 + rr][c];
    hh[rr] = f2bf(v);
    ll[rr] = f2bf(v - bf2f(hh[rr]));
  }
  size_t off = (size_t)c * R + r0 + half * 16;
  uint4 ph0 = {(unsigned)hh[0] | ((unsigned)hh[1] << 16), (unsigned)hh[2] | ((unsigned)hh[3] << 16),
               (unsigned)hh[4] | ((unsigned)hh[5] << 16), (unsigned)hh[6] | ((unsigned)hh[7] << 16)};
  uint4 ph1 = {(unsigned)hh[8] | ((unsigned)hh[9] << 16), (unsigned)hh[10] | ((unsigned)hh[11] << 16),
               (unsigned)hh[12] | ((unsigned)hh[13] << 16), (unsigned)hh[14] | ((unsigned)hh[15] << 16)};
  uint4 pl0 = {(unsigned)ll[0] | ((unsigned)ll[1] << 16), (unsigned)ll[2] | ((unsigned)ll[3] << 16),
               (unsigned)ll[4] | ((unsigned)ll[5] << 16), (unsigned)ll[6] | ((unsigned)ll[7] << 16)};
  uint4 pl1 = {(unsigned)ll[8] | ((unsigned)ll[9] << 16), (unsigned)ll[10] | ((unsigned)ll[11] << 16),
               (unsigned)ll[12] | ((unsigned)ll[13] << 16), (unsigned)ll[14] | ((unsigned)ll[15] << 16)};
  *(uint4*)&thi[off] = ph0; *(uint4*)&thi[off + 8] = ph1;
  *(uint4*)&tlo[off] = pl0; *(uint4*)&tlo[off + 8] = pl1;
}

// ---------------- small kernels ----------------

__global__ __launch_bounds__(64) void k_colsum_s2c(
    const float* __restrict__ cm, const float* __restrict__ mv,
    float* __restrict__ colsum_c) {
  int c = blockIdx.x * 64 + threadIdx.x;
  int i0 = blockIdx.y * 256;
  float acc = 0.f;
  for (int i = i0; i < i0 + 256; i++) acc += cm[(size_t)i * C + c] * mv[i];
  atomicAdd(&colsum_c[c], acc);
}

__global__ __launch_bounds__(256) void k_colstats(const float* __restrict__ sc,
                                                  float* __restrict__ colmax,
                                                  float* __restrict__ colsum) {
  __shared__ float red[256];
  int c = blockIdx.x, t = threadIdx.x;
  float v[16];
  float m = -3e38f;
#pragma unroll
  for (int q = 0; q < 16; q++) {
    v[q] = sc[(size_t)(q * 256 + t) * C + c];
    m = fmaxf(m, v[q]);
  }
  red[t] = m; __syncthreads();
  for (int s = 128; s; s >>= 1) { if (t < s) red[t] = fmaxf(red[t], red[t + s]); __syncthreads(); }
  m = red[0]; __syncthreads();
  float sum = 0.f;
#pragma unroll
  for (int q = 0; q < 16; q++) sum += __expf(v[q] - m);
  red[t] = sum; __syncthreads();
  for (int s = 128; s; s >>= 1) { if (t < s) red[t] += red[t + s]; __syncthreads(); }
  if (t == 0) { colmax[c] = m; colsum[c] = red[0]; }
}

// row softmax of cos-sim -> bf16 hi/lo pairs
__global__ __launch_bounds__(256) void k_cs_softmax(
    const float* __restrict__ sc, const float* __restrict__ xnorm,
    const float* __restrict__ hnorm, const float* __restrict__ valid1,
    unsigned short* __restrict__ cshi, unsigned short* __restrict__ cslo) {
  __shared__ float red[256];
  int i = blockIdx.x, t = threadIdx.x;
  float xn = xnorm[i];
  float r0 = sc[(size_t)i * C + t], r1 = sc[(size_t)i * C + 256 + t];
  float d0 = xn * hnorm[t], d1 = xn * hnorm[256 + t];
  float c0 = r0 / (d0 == 0.f ? 1.f : d0);
  float c1 = r1 / (d1 == 0.f ? 1.f : d1);
  float s0 = (valid1[t] != 0.f) ? c0 : -3e38f;
  float s1 = (valid1[256 + t] != 0.f) ? c1 : -3e38f;
  red[t] = fmaxf(s0, s1); __syncthreads();
  for (int s = 128; s; s >>= 1) { if (t < s) red[t] = fmaxf(red[t], red[t + s]); __syncthreads(); }
  float m = red[0]; __syncthreads();
  float p0 = (s0 > -1e37f) ? __expf(s0 - m) : 0.f;
  float p1 = (s1 > -1e37f) ? __expf(s1 - m) : 0.f;
  red[t] = p0 + p1; __syncthreads();
  for (int s = 128; s; s >>= 1) { if (t < s) red[t] += red[t + s]; __syncthreads(); }
  float inv = 1.f / red[0];
  float a = p0 * inv, b = p1 * inv;
  unsigned short ha = f2bf(a), hb = f2bf(b);
  cshi[(size_t)i * C + t] = ha;
  cslo[(size_t)i * C + t] = f2bf(a - bf2f(ha));
  cshi[(size_t)i * C + 256 + t] = hb;
  cslo[(size_t)i * C + 256 + t] = f2bf(b - bf2f(hb));
}

// finalize hidden2 (32 rows/block) + h2hat pairs + valid2f + transposed pairs
__global__ __launch_bounds__(256) void k_fin2t(
    const float* __restrict__ h, const float* __restrict__ diagv,
    const float* __restrict__ colsum_m, float* __restrict__ hidden2,
    unsigned short* __restrict__ h2hi, unsigned short* __restrict__ h2lo,
    float* __restrict__ valid2f, unsigned short* __restrict__ thi,
    unsigned short* __restrict__ tlo) {
  __shared__ float tile[32][132];
  int j0 = blockIdx.x * 32, tid = threadIdx.x;
  int row = tid >> 3, c0 = (tid & 7) * 16;
  int j = j0 + row;
  float add = (colsum_m[j] != 0.f) ? diagv[j] : 0.f;
  float a16[16];
  float s = 0.f, ss = 0.f;
#pragma unroll
  for (int q = 0; q < 16; q++) {
    float a = hidden2[(size_t)j * H + c0 + q] + add * h[(size_t)j * H + c0 + q];
    a16[q] = a;
    s += a; ss += a * a;
  }
#pragma unroll
  for (int m = 4; m; m >>= 1) { s += __shfl_xor(s, m); ss += __shfl_xor(ss, m); }
  bool valid = (s != 0.f);
  float inv = (valid && ss > 0.f) ? (1.f / sqrtf(ss)) : 1.f;
  size_t base = (size_t)j * H + c0;
  unsigned short hh16[16], ll16[16];
#pragma unroll
  for (int q = 0; q < 16; q++) {
    a16[q] = valid ? a16[q] : 0.f;
    float va = a16[q] * inv;
    hh16[q] = f2bf(va);
    ll16[q] = f2bf(va - bf2f(hh16[q]));
    tile[row][c0 + q] = a16[q];
  }
#pragma unroll
  for (int q4 = 0; q4 < 4; q4++) {
    float4 fv = {a16[q4 * 4], a16[q4 * 4 + 1], a16[q4 * 4 + 2], a16[q4 * 4 + 3]};
    *(float4*)&hidden2[base + q4 * 4] = fv;
  }
  uint4 ph0 = {(unsigned)hh16[0] | ((unsigned)hh16[1] << 16), (unsigned)hh16[2] | ((unsigned)hh16[3] << 16),
               (unsigned)hh16[4] | ((unsigned)hh16[5] << 16), (unsigned)hh16[6] | ((unsigned)hh16[7] << 16)};
  uint4 ph1 = {(unsigned)hh16[8] | ((unsigned)hh16[9] << 16), (unsigned)hh16[10] | ((unsigned)hh16[11] << 16),
               (unsigned)hh16[12] | ((unsigned)hh16[13] << 16), (unsigned)hh16[14] | ((unsigned)hh16[15] << 16)};
  uint4 pl0 = {(unsigned)ll16[0] | ((unsigned)ll16[1] << 16), (unsigned)ll16[2] | ((unsigned)ll16[3] << 16),
               (unsigned)ll16[4] | ((unsigned)ll16[5] << 16), (unsigned)ll16[6] | ((unsigned)ll16[7] << 16)};
  uint4 pl1 = {(unsigned)ll16[8] | ((unsigned)ll16[9] << 16), (unsigned)ll16[10] | ((unsigned)ll16[11] << 16),
               (unsigned)ll16[12] | ((unsigned)ll16[13] << 16), (unsigned)ll16[14] | ((unsigned)ll16[15] << 16)};
  *(uint4*)&h2hi[base] = ph0; *(uint4*)&h2hi[base + 8] = ph1;
  *(uint4*)&h2lo[base] = pl0; *(uint4*)&h2lo[base + 8] = pl1;
  if ((tid & 7) == 0) valid2f[j] = valid ? 1.f : 0.f;
  __syncthreads();
  int c = tid & 127, half = tid >> 7;
  unsigned short th[16], tl[16];
#pragma unroll
  for (int rr = 0; rr < 16; rr++) {
    float v = tile[half * 16 + rr][c];
    th[rr] = f2bf(v);
    tl[rr] = f2bf(v - bf2f(th[rr]));
  }
  size_t off = (size_t)c * N + j0 + half * 16;
  uint4 tp0 = {(unsigned)th[0] | ((unsigned)th[1] << 16), (unsigned)th[2] | ((unsigned)th[3] << 16),
               (unsigned)th[4] | ((unsigned)th[5] << 16), (unsigned)th[6] | ((unsigned)th[7] << 16)};
  uint4 tp1 = {(unsigned)th[8] | ((unsigned)th[9] << 16), (unsigned)th[10] | ((unsigned)th[11] << 16),
               (unsigned)th[12] | ((unsigned)th[13] << 16), (unsigned)th[14] | ((unsigned)th[15] << 16)};
  uint4 tq0 = {(unsigned)tl[0] | ((unsigned)tl[1] << 16), (unsigned)tl[2] | ((unsigned)tl[3] << 16),
               (unsigned)tl[4] | ((unsigned)tl[5] << 16), (unsigned)tl[6] | ((unsigned)tl[7] << 16)};
  uint4 tq1 = {(unsigned)tl[8] | ((unsigned)tl[9] << 16), (unsigned)tl[10] | ((unsigned)tl[11] << 16),
               (unsigned)tl[12] | ((unsigned)tl[13] << 16), (unsigned)tl[14] | ((unsigned)tl[15] << 16)};
  *(uint4*)&thi[off] = tp0; *(uint4*)&thi[off + 8] = tp1;
  *(uint4*)&tlo[off] = tq0; *(uint4*)&tlo[off + 8] = tq1;
}

// ---------------- bf16x3 MFMA NT GEMM: A[64,128] @ B[128,128]^T, fp32 out ----
__global__ __launch_bounds__(256) void k_mfma_nt(
    const unsigned short* __restrict__ Ahi, const unsigned short* __restrict__ Alo,
    const unsigned short* __restrict__ Bhi, const unsigned short* __restrict__ Blo,
    float* __restrict__ out, int Nn) {
  __shared__ __align__(16) unsigned short sAh[64 * PAD];
  __shared__ __align__(16) unsigned short sAl[64 * PAD];
  __shared__ __align__(16) unsigned short sBh[128 * PAD];
  __shared__ __align__(16) unsigned short sBl[128 * PAD];
  int tid = threadIdx.x;
  int bm = blockIdx.y * 64, bn = blockIdx.x * 128;
  int lane = tid & 63, w = tid >> 6;
  int wm = (w & 1) * 32, wn = (w >> 1) * 64;
  int l15 = lane & 15, quad = lane >> 4;
  f32x4 zero = {0.f, 0.f, 0.f, 0.f};
  f32x4 acc[2][4];
#pragma unroll
  for (int mt = 0; mt < 2; mt++)
#pragma unroll
    for (int nt = 0; nt < 4; nt++) acc[mt][nt] = zero;

  for (int kt = 0; kt < 128; kt += 32) {
    {
      int row = tid >> 2, ch = tid & 3;
      size_t ga = (size_t)(bm + row) * 128 + kt + ch * 8;
      int ls = row * PAD + ch * 8;
      *(uint4*)&sAh[ls] = *(const uint4*)&Ahi[ga];
      *(uint4*)&sAl[ls] = *(const uint4*)&Alo[ga];
    }
#pragma unroll
    for (int q = 0; q < 2; q++) {
      int f = q * 256 + tid;
      int row = f >> 2, ch = f & 3;
      size_t gb = (size_t)(bn + row) * 128 + kt + ch * 8;
      int ls = row * PAD + ch * 8;
      *(uint4*)&sBh[ls] = *(const uint4*)&Bhi[gb];
      *(uint4*)&sBl[ls] = *(const uint4*)&Blo[gb];
    }
    __syncthreads();
    bf16x8 ah[2], al[2], bh[4], bl[4];
#pragma unroll
    for (int t = 0; t < 2; t++) {
      int ar = (wm + t * 16 + l15) * PAD + quad * 8;
      ah[t] = *(const bf16x8*)&sAh[ar];
      al[t] = *(const bf16x8*)&sAl[ar];
    }
#pragma unroll
    for (int t = 0; t < 4; t++) {
      int br = (wn + t * 16 + l15) * PAD + quad * 8;
      bh[t] = *(const bf16x8*)&sBh[br];
      bl[t] = *(const bf16x8*)&sBl[br];
    }
#pragma unroll
    for (int mt = 0; mt < 2; mt++)
#pragma unroll
      for (int nt = 0; nt < 4; nt++) {
        acc[mt][nt] = __builtin_amdgcn_mfma_f32_16x16x32_bf16(ah[mt], bh[nt], acc[mt][nt], 0, 0, 0);
        acc[mt][nt] = __builtin_amdgcn_mfma_f32_16x16x32_bf16(ah[mt], bl[nt], acc[mt][nt], 0, 0, 0);
        acc[mt][nt] = __builtin_amdgcn_mfma_f32_16x16x32_bf16(al[mt], bh[nt], acc[mt][nt], 0, 0, 0);
      }
    __syncthreads();
  }
#pragma unroll
  for (int mt = 0; mt < 2; mt++) {
#pragma unroll
    for (int nt = 0; nt < 4; nt++) {
      int col = bn + wn + nt * 16 + l15;
#pragma unroll
      for (int rg = 0; rg < 4; rg++) {
        int row = bm + wm + mt * 16 + quad * 4 + rg;
        out[(size_t)row * Nn + col] = acc[mt][nt][rg];
      }
    }
  }
}

// ---------------- S = hhat@hhat^T + fused quarter-row top-5 screen -----------
__global__ __launch_bounds__(512) void k_snt(
    const unsigned short* __restrict__ Ahi, const unsigned short* __restrict__ Alo,
    float2* __restrict__ cand) {
  __shared__ __align__(16) unsigned short sAh[128 * PAD];
  __shared__ __align__(16) unsigned short sAl[128 * PAD];
  __shared__ __align__(16) unsigned short sBh[128 * PAD];
  __shared__ __align__(16) unsigned short sBl[128 * PAD];
  __shared__ __align__(16) unsigned short sS[128 * SP];
  int tid = threadIdx.x;
  int bm = blockIdx.y * 128, bn = blockIdx.x * 128;
  int lane = tid & 63, w = tid >> 6;
  int wm = (w & 3) * 32, wn = (w >> 2) * 64;
  int l15 = lane & 15, quad = lane >> 4;
  f32x4 zero = {0.f, 0.f, 0.f, 0.f};
  f32x4 acc[2][4];
#pragma unroll
  for (int mt = 0; mt < 2; mt++)
#pragma unroll
    for (int nt = 0; nt < 4; nt++) acc[mt][nt] = zero;

  for (int kt = 0; kt < 128; kt += 32) {
    {
      int row = tid >> 2, ch = tid & 3;
      size_t ga = (size_t)(bm + row) * 128 + kt + ch * 8;
      size_t gb = (size_t)(bn + row) * 128 + kt + ch * 8;
      int ls = row * PAD + ch * 8;
      *(uint4*)&sAh[ls] = *(const uint4*)&Ahi[ga];
      *(uint4*)&sAl[ls] = *(const uint4*)&Alo[ga];
      *(uint4*)&sBh[ls] = *(const uint4*)&Ahi[gb];
      *(uint4*)&sBl[ls] = *(const uint4*)&Alo[gb];
    }
    __syncthreads();
    bf16x8 ah[2], al[2], bh[4], bl[4];
#pragma unroll
    for (int t = 0; t < 2; t++) {
      int ar = (wm + t * 16 + l15) * PAD + quad * 8;
      ah[t] = *(const bf16x8*)&sAh[ar];
      al[t] = *(const bf16x8*)&sAl[ar];
    }
#pragma unroll
    for (int t = 0; t < 4; t++) {
      int br = (wn + t * 16 + l15) * PAD + quad * 8;
      bh[t] = *(const bf16x8*)&sBh[br];
      bl[t] = *(const bf16x8*)&sBl[br];
    }
#pragma unroll
    for (int mt = 0; mt < 2; mt++)
#pragma unroll
      for (int nt = 0; nt < 4; nt++) {
        acc[mt][nt] = __builtin_amdgcn_mfma_f32_16x16x32_bf16(ah[mt], bh[nt], acc[mt][nt], 0, 0, 0);
        acc[mt][nt] = __builtin_amdgcn_mfma_f32_16x16x32_bf16(ah[mt], bl[nt], acc[mt][nt], 0, 0, 0);
        acc[mt][nt] = __builtin_amdgcn_mfma_f32_16x16x32_bf16(al[mt], bh[nt], acc[mt][nt], 0, 0, 0);
      }
    __syncthreads();
  }
#pragma unroll
  for (int mt = 0; mt < 2; mt++)
#pragma unroll
    for (int nt = 0; nt < 4; nt++) {
      int coll = wn + nt * 16 + l15;
#pragma unroll
      for (int rg = 0; rg < 4; rg++) {
        int rowl = wm + mt * 16 + quad * 4 + rg;
        float v = (bm + rowl == bn + coll) ? 0.f : acc[mt][nt][rg];
        sS[rowl * SP + coll] = __half_as_ushort(__float2half(v));
      }
    }
  __syncthreads();
  int r = tid >> 2, qf = tid & 3;
  const unsigned short* rowp = &sS[r * SP + qf * 32];
  int cbase = bn + qf * 32;
  float v5[5] = {-3e38f, -3e38f, -3e38f, -3e38f, -3e38f};
  int j5[5] = {0x7fffffff, 0x7fffffff, 0x7fffffff, 0x7fffffff, 0x7fffffff};
#pragma unroll
  for (int q = 0; q < 4; q++) {
    uint4 p = *(const uint4*)&rowp[q * 8];
    unsigned pk[4] = {p.x, p.y, p.z, p.w};
#pragma unroll
    for (int c2 = 0; c2 < 4; c2++) {
      float e0 = __half2float(__ushort_as_half((unsigned short)(pk[c2] & 0xffffu)));
      float e1 = __half2float(__ushort_as_half((unsigned short)(pk[c2] >> 16)));
      ins5(e0, cbase + q * 8 + c2 * 2, v5, j5);
      ins5(e1, cbase + q * 8 + c2 * 2 + 1, v5, j5);
    }
  }
  int slot = (bn >> 5) + qf;
  float2* cp = &cand[((size_t)(bm + r) * 128 + slot) * 5];
#pragma unroll
  for (int c2 = 0; c2 < 5; c2++) cp[c2] = {v5[c2], __int_as_float(j5[c2])};
}

// -------- row top-k merge + exact fp32 rescore + fused scatter --------
__global__ __launch_bounds__(256) void k_rowtop2s(
    const float2* __restrict__ cand, const float* __restrict__ hhat,
    const float* __restrict__ h, float* __restrict__ hidden2,
    float* __restrict__ colsum_m) {
  int i = blockIdx.x * 4 + (threadIdx.x >> 6);
  int lane = threadIdx.x & 63;
  const float2* cr = &cand[(size_t)i * 640];
  float v[5] = {-3e38f, -3e38f, -3e38f, -3e38f, -3e38f};
  int jx[5] = {0x7fffffff, 0x7fffffff, 0x7fffffff, 0x7fffffff, 0x7fffffff};
#pragma unroll
  for (int c = 0; c < 10; c++) {
    float2 p = cr[lane * 10 + c];
    ins5(p.x, __float_as_int(p.y), v, jx);
  }
#pragma unroll
  for (int d = 1; d < 64; d <<= 1) {
    float fv[5]; int fj[5];
#pragma unroll
    for (int c = 0; c < 5; c++) { fv[c] = __shfl_xor(v[c], d); fj[c] = __shfl_xor(jx[c], d); }
#pragma unroll
    for (int c = 0; c < 5; c++) ins5(fv[c], fj[c], v, jx);
  }
  const float* hi = &hhat[(size_t)i * H];
  float b0 = -3e38f, b1 = -3e38f, b2 = -3e38f;
  int q0 = 0, q1 = 0, q2 = 0;
#pragma unroll
  for (int c = 0; c < 5; c++) {
    int j = jx[c];
    float s;
    if (j == i) {
      s = 0.f;
    } else {
      const float* hj = &hhat[(size_t)j * H];
      float p = hi[lane] * hj[lane] + hi[lane + 64] * hj[lane + 64];
      s = wave_reduce_sum(p);
    }
    top3_ins(s, j, b0, q0, b1, q1, b2, q2);
  }
  // fused scatter (all 64 lanes hold identical b/q)
  float h0 = h[(size_t)i * H + lane], h1 = h[(size_t)i * H + 64 + lane];
  float bv[3] = {b0, b1, b2};
  int qv[3] = {q0, q1, q2};
#pragma unroll
  for (int s = 0; s < 3; s++) {
    float vv = bv[s];
    int j = qv[s];
    atomicAdd(&hidden2[(size_t)j * H + lane], vv * h0);
    atomicAdd(&hidden2[(size_t)j * H + 64 + lane], vv * h1);
    if (lane == s) atomicAdd(&colsum_m[j], vv);
  }
}

// ---------------- flash-fused hs_pre numerator (ring double-buffer) ----------
__global__ __launch_bounds__(512) void k_flash(
    const unsigned short* __restrict__ Qhi, const unsigned short* __restrict__ Qlo,
    const unsigned short* __restrict__ Khi, const unsigned short* __restrict__ Klo,
    const unsigned short* __restrict__ Vthi, const unsigned short* __restrict__ Vtlo,
    const float* __restrict__ valid2f, float* __restrict__ partialU,
    float* __restrict__ plsum, int KVC) {
  __shared__ __align__(16) unsigned short sQh[128 * FWP];
  __shared__ __align__(16) unsigned short sQl[128 * FWP];
  __shared__ __align__(16) unsigned short sP[128 * FWP];
  __shared__ __align__(16) unsigned short sBh[2][128 * PAD];
  __shared__ __align__(16) unsigned short sBl[2][128 * PAD];
  __shared__ float lsum_s[128];
  int tid = threadIdx.x;
  int z = blockIdx.x;
  int bm = blockIdx.y * 128;
  int j0 = z * KVC;
  int lane = tid & 63, w = tid >> 6;
  int wm = (w & 3) * 32, wn = (w >> 2) * 64;
  int l15 = lane & 15, quad = lane >> 4;
  int srow = tid >> 2, sch = tid & 3;
  int sls = srow * PAD + sch * 8;
#pragma unroll
  for (int q = 0; q < 4; q++) {
    int f = q * 512 + tid;
    int row = f >> 4, ch = f & 15;
    size_t ga = (size_t)(bm + row) * 128 + ch * 8;
    int ls = row * FWP + ch * 8;
    *(uint4*)&sQh[ls] = *(const uint4*)&Qhi[ga];
    *(uint4*)&sQl[ls] = *(const uint4*)&Qlo[ga];
  }
  if (tid < 128) lsum_s[tid] = 0.f;
  {
    size_t a = (size_t)(j0 + srow) * 128 + sch * 8;
    uint4 rh = *(const uint4*)&Khi[a];
    uint4 rl = *(const uint4*)&Klo[a];
    __syncthreads();
    *(uint4*)&sBh[0][sls] = rh;
    *(uint4*)&sBl[0][sls] = rl;
  }
  __syncthreads();
  int cur = 0;
  f32x4 zero = {0.f, 0.f, 0.f, 0.f};
  f32x4 uacc[2][4];
#pragma unroll
  for (int mt = 0; mt < 2; mt++)
#pragma unroll
    for (int nt = 0; nt < 4; nt++) uacc[mt][nt] = zero;

  for (int jb = j0; jb < j0 + KVC; jb += 128) {
    float vm[4];
#pragma unroll
    for (int nt = 0; nt < 4; nt++) vm[nt] = valid2f[jb + wn + nt * 16 + l15];
    f32x4 qacc[2][4];
#pragma unroll
    for (int mt = 0; mt < 2; mt++)
#pragma unroll
      for (int nt = 0; nt < 4; nt++) qacc[mt][nt] = zero;
#pragma unroll
    for (int t = 0; t < 4; t++) {
      uint4 nrh, nrl;
      if (t < 3) {
        size_t a = (size_t)(jb + srow) * 128 + (t + 1) * 32 + sch * 8;
        nrh = *(const uint4*)&Khi[a];
        nrl = *(const uint4*)&Klo[a];
      } else {
        size_t a = (size_t)srow * N + jb + sch * 8;
        nrh = *(const uint4*)&Vthi[a];
        nrl = *(const uint4*)&Vtlo[a];
      }
      int kt = t * 32;
      bf16x8 ah[2], al[2], bh[4], bl[4];
#pragma unroll
      for (int tt = 0; tt < 2; tt++) {
        int ar = (wm + tt * 16 + l15) * FWP + kt + quad * 8;
        ah[tt] = *(const bf16x8*)&sQh[ar];
        al[tt] = *(const bf16x8*)&sQl[ar];
      }
#pragma unroll
      for (int tt = 0; tt < 4; tt++) {
        int br = (wn + tt * 16 + l15) * PAD + quad * 8;
        bh[tt] = *(const bf16x8*)&sBh[cur][br];
        bl[tt] = *(const bf16x8*)&sBl[cur][br];
      }
#pragma unroll
      for (int mt = 0; mt < 2; mt++)
#pragma unroll
        for (int nt = 0; nt < 4; nt++) {
          qacc[mt][nt] = __builtin_amdgcn_mfma_f32_16x16x32_bf16(ah[mt], bh[nt], qacc[mt][nt], 0, 0, 0);
          qacc[mt][nt] = __builtin_amdgcn_mfma_f32_16x16x32_bf16(ah[mt], bl[nt], qacc[mt][nt], 0, 0, 0);
          qacc[mt][nt] = __builtin_amdgcn_mfma_f32_16x16x32_bf16(al[mt], bh[nt], qacc[mt][nt], 0, 0, 0);
        }
      *(uint4*)&sBh[cur ^ 1][sls] = nrh;
      *(uint4*)&sBl[cur ^ 1][sls] = nrl;
      __syncthreads();
      cur ^= 1;
    }
#pragma unroll
    for (int mt = 0; mt < 2; mt++) {
#pragma unroll
      for (int rg = 0; rg < 4; rg++) {
        int row = wm + mt * 16 + quad * 4 + rg;
        float rs = 0.f;
#pragma unroll
        for (int nt = 0; nt < 4; nt++) {
          float e = (vm[nt] != 0.f) ? __expf(qacc[mt][nt][rg] - 1.f) : 0.f;
          rs += e;
          sP[row * FWP + wn + nt * 16 + l15] = f2bf(e);
        }
#pragma unroll
        for (int d = 1; d < 16; d <<= 1) rs += __shfl_xor(rs, d);
        if (l15 == 0) atomicAdd(&lsum_s[row], rs);
      }
    }
    __syncthreads();
#pragma unroll
    for (int t = 0; t < 4; t++) {
      uint4 nrh = {0, 0, 0, 0}, nrl = {0, 0, 0, 0};
      bool have;
      if (t < 3) {
        have = true;
        size_t a = (size_t)srow * N + jb + (t + 1) * 32 + sch * 8;
        nrh = *(const uint4*)&Vthi[a];
        nrl = *(const uint4*)&Vtlo[a];
      } else {
        have = (jb + 128 < j0 + KVC);
        if (have) {
          size_t a = (size_t)(jb + 128 + srow) * 128 + sch * 8;
          nrh = *(const uint4*)&Khi[a];
          nrl = *(const uint4*)&Klo[a];
        }
      }
      int kt = t * 32;
      bf16x8 pa[2], vh[4], vl[4];
#pragma unroll
      for (int tt = 0; tt < 2; tt++) {
        int ar = (wm + tt * 16 + l15) * FWP + kt + quad * 8;
        pa[tt] = *(const bf16x8*)&sP[ar];
      }
#pragma unroll
      for (int tt = 0; tt < 4; tt++) {
        int br = (wn + tt * 16 + l15) * PAD + quad * 8;
        vh[tt] = *(const bf16x8*)&sBh[cur][br];
        vl[tt] = *(const bf16x8*)&sBl[cur][br];
      }
#pragma unroll
      for (int mt = 0; mt < 2; mt++)
#pragma unroll
        for (int nt = 0; nt < 4; nt++) {
          uacc[mt][nt] = __builtin_amdgcn_mfma_f32_16x16x32_bf16(pa[mt], vh[nt], uacc[mt][nt], 0, 0, 0);
          uacc[mt][nt] = __builtin_amdgcn_mfma_f32_16x16x32_bf16(pa[mt], vl[nt], uacc[mt][nt], 0, 0, 0);
        }
      if (have) {
        *(uint4*)&sBh[cur ^ 1][sls] = nrh;
        *(uint4*)&sBl[cur ^ 1][sls] = nrl;
      }
      __syncthreads();
      cur ^= 1;
    }
  }
  float* pU = partialU + (size_t)z * N * 128;
#pragma unroll
  for (int mt = 0; mt < 2; mt++)
#pragma unroll
    for (int nt = 0; nt < 4; nt++) {
      int col = wn + nt * 16 + l15;
#pragma unroll
      for (int rg = 0; rg < 4; rg++) {
        int row = bm + wm + mt * 16 + quad * 4 + rg;
        pU[(size_t)row * 128 + col] = uacc[mt][nt][rg];
      }
    }
  if (tid < 128) plsum[(size_t)z * N + bm + tid] = lsum_s[tid];
}

// ---------------- bf16 MFMA KN GEMM (split-K): partial[z] = A @ B ------------
__global__ __launch_bounds__(256) void k_mfma_kn(
    const unsigned short* __restrict__ Ahi, const unsigned short* __restrict__ Alo,
    const unsigned short* __restrict__ Bthi, const unsigned short* __restrict__ Btlo,
    float* __restrict__ partial, int lda, int KC) {
  __shared__ __align__(16) unsigned short sAh[128 * PAD];
  __shared__ __align__(16) unsigned short sAl[128 * PAD];
  __shared__ __align__(16) unsigned short sBh[128 * PAD];
  __shared__ __align__(16) unsigned short sBl[128 * PAD];
  int tid = threadIdx.x;
  int bm = blockIdx.y * 128;
  int k0 = blockIdx.z * KC;
  int lane = tid & 63, w = tid >> 6;
  int wm = (w & 1) * 64, wn = (w >> 1) * 64;
  int l15 = lane & 15, quad = lane >> 4;
  f32x4 zero = {0.f, 0.f, 0.f, 0.f};
  f32x4 acc[4][4];
#pragma unroll
  for (int mt = 0; mt < 4; mt++)
#pragma unroll
    for (int nt = 0; nt < 4; nt++) acc[mt][nt] = zero;

  for (int kt = 0; kt < KC; kt += 32) {
#pragma unroll
    for (int q = 0; q < 2; q++) {
      int f = tid * 2 + q;
      int row = f >> 2, ch = f & 3;
      size_t ga = (size_t)(bm + row) * lda + k0 + kt + ch * 8;
      size_t gb = (size_t)row * lda + k0 + kt + ch * 8;
      int ls = row * PAD + ch * 8;
      *(uint4*)&sAh[ls] = *(const uint4*)&Ahi[ga];
      *(uint4*)&sAl[ls] = *(const uint4*)&Alo[ga];
      *(uint4*)&sBh[ls] = *(const uint4*)&Bthi[gb];
      *(uint4*)&sBl[ls] = *(const uint4*)&Btlo[gb];
    }
    __syncthreads();
    bf16x8 ah[4], al[4], bh[4], bl[4];
#pragma unroll
    for (int t = 0; t < 4; t++) {
      int ar = (wm + t * 16 + l15) * PAD + quad * 8;
      ah[t] = *(const bf16x8*)&sAh[ar];
      al[t] = *(const bf16x8*)&sAl[ar];
      int br = (wn + t * 16 + l15) * PAD + quad * 8;
      bh[t] = *(const bf16x8*)&sBh[br];
      bl[t] = *(const bf16x8*)&sBl[br];
    }
#pragma unroll
    for (int mt = 0; mt < 4; mt++)
#pragma unroll
      for (int nt = 0; nt < 4; nt++) {
        acc[mt][nt] = __builtin_amdgcn_mfma_f32_16x16x32_bf16(ah[mt], bh[nt], acc[mt][nt], 0, 0, 0);
        acc[mt][nt] = __builtin_amdgcn_mfma_f32_16x16x32_bf16(ah[mt], bl[nt], acc[mt][nt], 0, 0, 0);
        acc[mt][nt] = __builtin_amdgcn_mfma_f32_16x16x32_bf16(al[mt], bh[nt], acc[mt][nt], 0, 0, 0);
      }
    __syncthreads();
  }
  float* pp = partial + (size_t)blockIdx.z * N * 128;
#pragma unroll
  for (int mt = 0; mt < 4; mt++)
#pragma unroll
    for (int nt = 0; nt < 4; nt++) {
      int col = wn + nt * 16 + l15;
#pragma unroll
      for (int rg = 0; rg < 4; rg++) {
        int row = bm + wm + mt * 16 + quad * 4 + rg;
        pp[(size_t)row * 128 + col] = acc[mt][nt][rg];
      }
    }
}

// ---------------- bf16x3 MFMA genA GEMM (split-K) ----------------
template <int AMODE>
__global__ __launch_bounds__(256) void k_mfma_genA(
    const float* __restrict__ P, const float* __restrict__ mv,
    const float* __restrict__ col1, const float* __restrict__ col2,
    const unsigned short* __restrict__ Bthi, const unsigned short* __restrict__ Btlo,
    float* __restrict__ partial, int KC) {
  __shared__ __align__(16) unsigned short sAh[128 * PAD];
  __shared__ __align__(16) unsigned short sAl[128 * PAD];
  __shared__ __align__(16) unsigned short sBh[128 * PAD];
  __shared__ __align__(16) unsigned short sBl[128 * PAD];
  int tid = threadIdx.x;
  int bm = blockIdx.y * 128;
  int k0 = blockIdx.z * KC;
  int lane = tid & 63, w = tid >> 6;
  int wm = (w & 1) * 64, wn = (w >> 1) * 64;
  int l15 = lane & 15, quad = lane >> 4;
  f32x4 zero = {0.f, 0.f, 0.f, 0.f};
  f32x4 acc[4][4];
#pragma unroll
  for (int mt = 0; mt < 4; mt++)
#pragma unroll
    for (int nt = 0; nt < 4; nt++) acc[mt][nt] = zero;

  for (int kt = 0; kt < KC; kt += 32) {
    int kr = tid >> 3;
    int mc = (tid & 7) * 16;
    int k = k0 + kt + kr;
    float mvk = (AMODE == 1) ? mv[k] : 0.f;
#pragma unroll
    for (int q = 0; q < 4; q++) {
      int m0 = mc + q * 4;
      float4 pv = *(const float4*)&P[(size_t)k * C + bm + m0];
      float4 c1 = *(const float4*)&col1[bm + m0];
      float wv[4];
      if (AMODE == 1) {
        wv[0] = pv.x * mvk / (c1.x * pv.x + 1.f);
        wv[1] = pv.y * mvk / (c1.y * pv.y + 1.f);
        wv[2] = pv.z * mvk / (c1.z * pv.z + 1.f);
        wv[3] = pv.w * mvk / (c1.w * pv.w + 1.f);
      } else {
        float4 c2 = *(const float4*)&col2[bm + m0];
        wv[0] = __expf(pv.x - c1.x) / c2.x;
        wv[1] = __expf(pv.y - c1.y) / c2.y;
        wv[2] = __expf(pv.z - c1.z) / c2.z;
        wv[3] = __expf(pv.w - c1.w) / c2.w;
      }
#pragma unroll
      for (int j = 0; j < 4; j++) {
        unsigned short hh = f2bf(wv[j]);
        sAh[(m0 + j) * PAD + kr] = hh;
        sAl[(m0 + j) * PAD + kr] = f2bf(wv[j] - bf2f(hh));
      }
    }
#pragma unroll
    for (int q = 0; q < 2; q++) {
      int f = q * 256 + tid;
      int row = f >> 2, ch = f & 3;
      size_t gb = (size_t)row * N + k0 + kt + ch * 8;
      int ls = row * PAD + ch * 8;
      *(uint4*)&sBh[ls] = *(const uint4*)&Bthi[gb];
      *(uint4*)&sBl[ls] = *(const uint4*)&Btlo[gb];
    }
    __syncthreads();
    bf16x8 ah[4], al[4], bh[4], bl[4];
#pragma unroll
    for (int t = 0; t < 4; t++) {
      int ar = (wm + t * 16 + l15) * PAD + quad * 8;
      ah[t] = *(const bf16x8*)&sAh[ar];
      al[t] = *(const bf16x8*)&sAl[ar];
      int br = (wn + t * 16 + l15) * PAD + quad * 8;
      bh[t] = *(const bf16x8*)&sBh[br];
      bl[t] = *(const bf16x8*)&sBl[br];
    }
#pragma unroll
    for (int mt = 0; mt < 4; mt++)
#pragma unroll
      for (int nt = 0; nt < 4; nt++) {
        acc[mt][nt] = __builtin_amdgcn_mfma_f32_16x16x32_bf16(ah[mt], bh[nt], acc[mt][nt], 0, 0, 0);
        acc[mt][nt] = __builtin_amdgcn_mfma_f32_16x16x32_bf16(ah[mt], bl[nt], acc[mt][nt], 0, 0, 0);
        acc[mt][nt] = __builtin_amdgcn_mfma_f32_16x16x32_bf16(al[mt], bh[nt], acc[mt][nt], 0, 0, 0);
      }
    __syncthreads();
  }
  float* pp = partial + (size_t)blockIdx.z * C * 128;
#pragma unroll
  for (int mt = 0; mt < 4; mt++)
#pragma unroll
    for (int nt = 0; nt < 4; nt++) {
      int col = wn + nt * 16 + l15;
#pragma unroll
      for (int rg = 0; rg < 4; rg++) {
        int row = bm + wm + mt * 16 + quad * 4 + rg;
        pp[(size_t)row * 128 + col] = acc[mt][nt][rg];
      }
    }
}

// reduce split-K partials (C*H shapes); optional per-row scale; pair emission;
// row-norm / row-valid emission
__global__ __launch_bounds__(256) void k_reduce(
    const float* __restrict__ partial, float* __restrict__ out, int cnt,
    size_t slot, size_t size4, const float* __restrict__ scalem,
    unsigned short* __restrict__ hi, unsigned short* __restrict__ lo,
    float* __restrict__ nrmout, float* __restrict__ validout) {
  size_t idx = (size_t)blockIdx.x * 256 + threadIdx.x;
  if (idx >= size4) return;
  float4 s = {0, 0, 0, 0};
  for (int c = 0; c < cnt; c++) {
    float4 v = *(const float4*)&partial[c * slot + idx * 4];
    s.x += v.x; s.y += v.y; s.z += v.z; s.w += v.w;
  }
  if (scalem) {
    float sc = scalem[idx >> 5];
    s.x *= sc; s.y *= sc; s.z *= sc; s.w *= sc;
  }
  *(float4*)&out[idx * 4] = s;
  if (hi) {
    float vv[4] = {s.x, s.y, s.z, s.w};
    unsigned short h[4], l[4];
#pragma unroll
    for (int c = 0; c < 4; c++) {
      h[c] = f2bf(vv[c]);
      l[c] = f2bf(vv[c] - bf2f(h[c]));
    }
    uint2 ph = {(unsigned)h[0] | ((unsigned)h[1] << 16),
                (unsigned)h[2] | ((unsigned)h[3] << 16)};
    uint2 pl = {(unsigned)l[0] | ((unsigned)l[1] << 16),
                (unsigned)l[2] | ((unsigned)l[3] << 16)};
    *(uint2*)&hi[idx * 4] = ph;
    *(uint2*)&lo[idx * 4] = pl;
  }
  if (nrmout || validout) {
    float rs = s.x + s.y + s.z + s.w;
    float rq = s.x * s.x + s.y * s.y + s.z * s.z + s.w * s.w;
#pragma unroll
    for (int m = 16; m; m >>= 1) { rs += __shfl_xor(rs, m); rq += __shfl_xor(rq, m); }
    if ((threadIdx.x & 31) == 0) {
      if (nrmout) nrmout[idx >> 5] = sqrtf(rq);
      if (validout) validout[idx >> 5] = (rs != 0.f) ? 1.f : 0.f;
    }
  }
}

// ---------------- fused branch-tail kernels ----------------

#define LOAD_W(Wt)                                                        \
  do {                                                                    \
    _Pragma("unroll") for (int q = 0; q < 16; q++) {                      \
      int f = q * 256 + tid;                                              \
      int wr = f >> 5, wc = (f & 31) * 4;                                 \
      float4 wv = *(const float4*)&(Wt)[(size_t)wr * 128 + wc];           \
      float ww[4] = {wv.x, wv.y, wv.z, wv.w};                             \
      _Pragma("unroll") for (int c = 0; c < 4; c++) {                     \
        unsigned short hh = f2bf(ww[c]);                                  \
        sWh[wr * WP + wc + c] = hh;                                       \
        sWl[wr * WP + wc + c] = f2bf(ww[c] - bf2f(hh));                   \
      }                                                                   \
    }                                                                     \
  } while (0)

#define GEMM32(accv)                                                              \
  do {                                                                            \
    _Pragma("unroll") for (int nt = 0; nt < 4; nt++) accv[nt] = zero;             \
    _Pragma("unroll") for (int kt = 0; kt < 128; kt += 32) {                      \
      bf16x8 ah = *(const bf16x8*)&sAh[(rt + l15) * WP + kt + quad * 8];          \
      bf16x8 al = *(const bf16x8*)&sAl[(rt + l15) * WP + kt + quad * 8];          \
      _Pragma("unroll") for (int nt = 0; nt < 4; nt++) {                          \
        int br = (ch2 + nt * 16 + l15) * WP + kt + quad * 8;                      \
        bf16x8 bh = *(const bf16x8*)&sWh[br];                                     \
        bf16x8 bl = *(const bf16x8*)&sWl[br];                                     \
        accv[nt] = __builtin_amdgcn_mfma_f32_16x16x32_bf16(ah, bh, accv[nt], 0, 0, 0); \
        accv[nt] = __builtin_amdgcn_mfma_f32_16x16x32_bf16(ah, bl, accv[nt], 0, 0, 0); \
        accv[nt] = __builtin_amdgcn_mfma_f32_16x16x32_bf16(al, bh, accv[nt], 0, 0, 0); \
      }                                                                           \
    }                                                                             \
  } while (0)

// ps tail: ps_pre = sum_z partial; p_shared = lin(ps_pre,W_ps);
// h = x - lin(p_shared,W_psb); out_ps -> all_info; hhat/pairs/diagv from h.
__global__ __launch_bounds__(256) void k_ps_tail(
    const float* __restrict__ partial, int zcnt, const float* __restrict__ x,
    const float* __restrict__ W_ps, const float* __restrict__ b_ps,
    const float* __restrict__ W_psb, const float* __restrict__ b_psb,
    const float* __restrict__ W_psf, const float* __restrict__ b_psf,
    float* __restrict__ hbuf, float* __restrict__ hhat,
    unsigned short* __restrict__ hhi, unsigned short* __restrict__ hlo,
    float* __restrict__ diagv, float* __restrict__ all_info) {
  __shared__ __align__(16) unsigned short sWh[128 * WP];
  __shared__ __align__(16) unsigned short sWl[128 * WP];
  __shared__ __align__(16) unsigned short sAh[32 * WP];
  __shared__ __align__(16) unsigned short sAl[32 * WP];
  __shared__ __align__(16) float sF[32][132];
  int tid = threadIdx.x;
  int bm = blockIdx.x * 32;
  int lane = tid & 63, w = tid >> 6;
  int rt = (w & 1) * 16, ch2 = (w >> 1) * 64;
  int l15 = lane & 15, quad = lane >> 4;
  f32x4 zero = {0.f, 0.f, 0.f, 0.f};
  f32x4 acc[4];

  {
    int row = tid >> 3, c0 = (tid & 7) * 16;
    size_t off0 = (size_t)(bm + row) * 128 + c0;
#pragma unroll
    for (int q = 0; q < 4; q++) {
      float vv[4] = {0.f, 0.f, 0.f, 0.f};
      for (int z = 0; z < zcnt; z++) {
        float4 v = *(const float4*)&partial[(size_t)z * N * H + off0 + q * 4];
        vv[0] += v.x; vv[1] += v.y; vv[2] += v.z; vv[3] += v.w;
      }
#pragma unroll
      for (int c = 0; c < 4; c++) {
        unsigned short hh = f2bf(vv[c]);
        sAh[row * WP + c0 + q * 4 + c] = hh;
        sAl[row * WP + c0 + q * 4 + c] = f2bf(vv[c] - bf2f(hh));
      }
    }
  }
  LOAD_W(W_ps);
  __syncthreads();
  GEMM32(acc);  // p_shared (pre-bias)
  __syncthreads();
#pragma unroll
  for (int nt = 0; nt < 4; nt++) {
    int col = ch2 + nt * 16 + l15;
    float bv = b_ps[col];
#pragma unroll
    for (int rg = 0; rg < 4; rg++) {
      int row = rt + quad * 4 + rg;
      float v = acc[nt][rg] + bv;
      unsigned short hh = f2bf(v);
      sAh[row * WP + col] = hh;
      sAl[row * WP + col] = f2bf(v - bf2f(hh));
    }
  }
  LOAD_W(W_psb);
  __syncthreads();
  GEMM32(acc);  // p_back (pre-bias)
#pragma unroll
  for (int nt = 0; nt < 4; nt++) {
    int col = ch2 + nt * 16 + l15;
    float bv = b_psb[col];
#pragma unroll
    for (int rg = 0; rg < 4; rg++) {
      int row = rt + quad * 4 + rg;
      size_t off = (size_t)(bm + row) * 128 + col;
      float hv = x[off] - (acc[nt][rg] + bv);
      hbuf[off] = hv;
      sF[row][col] = hv;
    }
  }
  __syncthreads();
  {
    int row = tid >> 3, c0 = (tid & 7) * 16;
    float hv16[16];
    float ssp = 0.f;
#pragma unroll
    for (int q = 0; q < 16; q++) {
      float v = sF[row][c0 + q];
      hv16[q] = v;
      ssp += v * v;
    }
    ssp += __shfl_xor(ssp, 1);
    ssp += __shfl_xor(ssp, 2);
    ssp += __shfl_xor(ssp, 4);
    float ss = ssp;
    float hn = sqrtf(ss);
    float den = hn * hn;
    float dg = (den == 0.f) ? 0.f : ss / den;
    float inv = (ss > 0.f) ? (1.f / hn) : 1.f;
    size_t base = (size_t)(bm + row) * H + c0;
    float va16[16];
    unsigned short hh16[16], ll16[16];
#pragma unroll
    for (int q = 0; q < 16; q++) {
      va16[q] = hv16[q] * inv;
      hh16[q] = f2bf(va16[q]);
      ll16[q] = f2bf(va16[q] - bf2f(hh16[q]));
    }
#pragma unroll
    for (int q4 = 0; q4 < 4; q4++) {
      float4 fv = {va16[q4 * 4], va16[q4 * 4 + 1], va16[q4 * 4 + 2], va16[q4 * 4 + 3]};
      *(float4*)&hhat[base + q4 * 4] = fv;
    }
    uint4 ph0 = {(unsigned)hh16[0] | ((unsigned)hh16[1] << 16), (unsigned)hh16[2] | ((unsigned)hh16[3] << 16),
                 (unsigned)hh16[4] | ((unsigned)hh16[5] << 16), (unsigned)hh16[6] | ((unsigned)hh16[7] << 16)};
    uint4 ph1 = {(unsigned)hh16[8] | ((unsigned)hh16[9] << 16), (unsigned)hh16[10] | ((unsigned)hh16[11] << 16),
                 (unsigned)hh16[12] | ((unsigned)hh16[13] << 16), (unsigned)hh16[14] | ((unsigned)hh16[15] << 16)};
    uint4 pl0 = {(unsigned)ll16[0] | ((unsigned)ll16[1] << 16), (unsigned)ll16[2] | ((unsigned)ll16[3] << 16),
                 (unsigned)ll16[4] | ((unsigned)ll16[5] << 16), (unsigned)ll16[6] | ((unsigned)ll16[7] << 16)};
    uint4 pl1 = {(unsigned)ll16[8] | ((unsigned)ll16[9] << 16), (unsigned)ll16[10] | ((unsigned)ll16[11] << 16),
                 (unsigned)ll16[12] | ((unsigned)ll16[13] << 16), (unsigned)ll16[14] | ((unsigned)ll16[15] << 16)};
    *(uint4*)&hhi[base] = ph0; *(uint4*)&hhi[base + 8] = ph1;
    *(uint4*)&hlo[base] = pl0; *(uint4*)&hlo[base + 8] = pl1;
    if ((tid & 7) == 0) diagv[bm + row] = dg;
  }
  LOAD_W(W_psf);
  __syncthreads();
  GEMM32(acc);  // out_ps (pre-bias)
#pragma unroll
  for (int nt = 0; nt < 4; nt++) {
    int col = ch2 + nt * 16 + l15;
    float bv = b_psf[col];
#pragma unroll
    for (int rg = 0; rg < 4; rg++) {
      int row = rt + quad * 4 + rg;
      size_t off = (size_t)(bm + row) * 128 + col;
      all_info[off] = lrelu(acc[nt][rg] + bv);
    }
  }
}

// hs tail: hs_pre = (sum_z partialU)/lsum; h_shared = lin(hs_pre,W_hs);
// all = all_info + lrelu(lin(h_shared,W_hsf)); indiv = h - lin(h_shared,W_hsb);
// all += lrelu(lin(indiv,W_in)); out = all @ W_out + b.
__global__ __launch_bounds__(256) void k_hs_tail(
    const float* __restrict__ partial, const float* __restrict__ plsum, int zcnt,
    const float* __restrict__ hbuf, const float* __restrict__ all_info,
    const float* __restrict__ W_hs, const float* __restrict__ b_hs,
    const float* __restrict__ W_hsf, const float* __restrict__ b_hsf,
    const float* __restrict__ W_hsb, const float* __restrict__ b_hsb,
    const float* __restrict__ W_in, const float* __restrict__ b_in,
    const float* __restrict__ W_out, const float* __restrict__ b_out,
    float* __restrict__ out) {
  __shared__ __align__(16) unsigned short sWh[128 * WP];
  __shared__ __align__(16) unsigned short sWl[128 * WP];
  __shared__ __align__(16) unsigned short sAh[32 * WP];
  __shared__ __align__(16) unsigned short sAl[32 * WP];
  __shared__ __align__(16) float sF[32][132];
  int tid = threadIdx.x;
  int bm = blockIdx.x * 32;
  int lane = tid & 63, w = tid >> 6;
  int rt = (w & 1) * 16, ch2 = (w >> 1) * 64;
  int l15 = lane & 15, quad = lane >> 4;
  f32x4 zero = {0.f, 0.f, 0.f, 0.f};
  f32x4 acc[4];
  float allv[4][4];

  {
    int row = tid >> 3, c0 = (tid & 7) * 16;
    float d = 0.f;
    for (int z = 0; z < zcnt; z++) d += plsum[(size_t)z * N + bm + row];
    float sc = 1.f / d;
    size_t off0 = (size_t)(bm + row) * 128 + c0;
#pragma unroll
    for (int q = 0; q < 4; q++) {
      float vv[4] = {0.f, 0.f, 0.f, 0.f};
      for (int z = 0; z < zcnt; z++) {
        float4 v = *(const float4*)&partial[(size_t)z * N * H + off0 + q * 4];
        vv[0] += v.x; vv[1] += v.y; vv[2] += v.z; vv[3] += v.w;
      }
#pragma unroll
      for (int c = 0; c < 4; c++) {
        float val = vv[c] * sc;
        unsigned short hh = f2bf(val);
        sAh[row * WP + c0 + q * 4 + c] = hh;
        sAl[row * WP + c0 + q * 4 + c] = f2bf(val - bf2f(hh));
      }
    }
  }
  LOAD_W(W_hs);
  __syncthreads();
  GEMM32(acc);  // h_shared (pre-bias)
  __syncthreads();
#pragma unroll
  for (int nt = 0; nt < 4; nt++) {
    int col = ch2 + nt * 16 + l15;
    float bv = b_hs[col];
#pragma unroll
    for (int rg = 0; rg < 4; rg++) {
      int row = rt + quad * 4 + rg;
      float v = acc[nt][rg] + bv;
      unsigned short hh = f2bf(v);
      sAh[row * WP + col] = hh;
      sAl[row * WP + col] = f2bf(v - bf2f(hh));
    }
  }
  LOAD_W(W_hsf);
  __syncthreads();
  GEMM32(acc);  // out_hs (pre-bias)
#pragma unroll
  for (int nt = 0; nt < 4; nt++) {
    int col = ch2 + nt * 16 + l15;
    float bv = b_hsf[col];
#pragma unroll
    for (int rg = 0; rg < 4; rg++) {
      int row = rt + quad * 4 + rg;
      size_t off = (size_t)(bm + row) * 128 + col;
      allv[nt][rg] = all_info[off] + lrelu(acc[nt][rg] + bv);
    }
  }
  __syncthreads();
  LOAD_W(W_hsb);
  __syncthreads();
  GEMM32(acc);  // h_back (pre-bias)
  float iv[4][4];
#pragma unroll
  for (int nt = 0; nt < 4; nt++) {
    int col = ch2 + nt * 16 + l15;
    float bv = b_hsb[col];
#pragma unroll
    for (int rg = 0; rg < 4; rg++) {
      int row = rt + quad * 4 + rg;
      size_t off = (size_t)(bm + row) * 128 + col;
      iv[nt][rg] = hbuf[off] - (acc[nt][rg] + bv);
    }
  }
  __syncthreads();
#pragma unroll
  for (int nt = 0; nt < 4; nt++) {
    int col = ch2 + nt * 16 + l15;
#pragma unroll
    for (int rg = 0; rg < 4; rg++) {
      int row = rt + quad * 4 + rg;
      unsigned short hh = f2bf(iv[nt][rg]);
      sAh[row * WP + col] = hh;
      sAl[row * WP + col] = f2bf(iv[nt][rg] - bf2f(hh));
    }
  }
  LOAD_W(W_in);
  __syncthreads();
  GEMM32(acc);  // out_indi (pre-bias)
#pragma unroll
  for (int nt = 0; nt < 4; nt++) {
    int col = ch2 + nt * 16 + l15;
    float bv = b_in[col];
#pragma unroll
    for (int rg = 0; rg < 4; rg++) {
      int row = rt + quad * 4 + rg;
      allv[nt][rg] += lrelu(acc[nt][rg] + bv);
      sF[row][col] = allv[nt][rg];
    }
  }
  __syncthreads();
  {
    int row = tid >> 3, c0 = (tid & 7) * 16;
    float s = 0.f;
#pragma unroll
    for (int q = 0; q < 16; q++) s += sF[row][c0 + q] * W_out[c0 + q];
    s += __shfl_xor(s, 1);
    s += __shfl_xor(s, 2);
    s += __shfl_xor(s, 4);
    if ((tid & 7) == 0) out[bm + row] = s + b_out[0];
  }
}

// ---------------- launch ----------------

extern "C" void kernel_launch(void* const* d_in, const int* in_sizes, int n_in,
                              void* d_out, int out_size, void* d_ws, size_t ws_size,
                              hipStream_t stream) {
  (void)in_sizes; (void)n_in; (void)out_size; (void)ws_size;
  const float* x   = (const float*)d_in[0];
  const float* cm  = (const float*)d_in[1];
  const float* mv  = (const float*)d_in[2];
  const float* W_ps = (const float*)d_in[3],  *b_ps = (const float*)d_in[4];
  const float* W_psf = (const float*)d_in[5], *b_psf = (const float*)d_in[6];
  const float* W_psb = (const float*)d_in[7], *b_psb = (const float*)d_in[8];
  const float* W_hs = (const float*)d_in[9],  *b_hs = (const float*)d_in[10];
  const float* W_hsf = (const float*)d_in[11], *b_hsf = (const float*)d_in[12];
  const float* W_hsb = (const float*)d_in[13], *b_hsb = (const float*)d_in[14];
  const float* W_in = (const float*)d_in[15], *b_in = (const float*)d_in[16];
  const float* W_out = (const float*)d_in[17], *b_out = (const float*)d_in[18];
  float* out = (float*)d_out;

  float* W = (float*)d_ws;
  size_t o = 0;
  auto alloc = [&](size_t n) { float* p = W + o; o += n; return p; };
  float* colsum_c = alloc(C);
  float* colmax   = alloc(C);
  float* colsumexp= alloc(C);
  float* valid1   = alloc(C);
  float* hnorm_ps = alloc(C);
  float* xnorm    = alloc(N);
  float* diagv    = alloc(N);
  float* colsum_m = alloc(N);
  float* valid2f  = alloc(N);
  float* plsum    = alloc((size_t)8 * N);
  float* hidden1  = alloc((size_t)C * H);
  float* hidden_ps= alloc((size_t)C * H);
  float* scores   = alloc((size_t)N * C);
  float* all_info = alloc((size_t)N * H);
  float* hbuf     = alloc((size_t)N * H);   // h
  float* hhat     = alloc((size_t)N * H);
  float* hidden2  = alloc((size_t)N * H);
  unsigned short* xhi    = (unsigned short*)alloc((size_t)N * H / 2);
  unsigned short* xlo    = (unsigned short*)alloc((size_t)N * H / 2);
  unsigned short* hhathi = (unsigned short*)alloc((size_t)N * H / 2);
  unsigned short* hhatlo = (unsigned short*)alloc((size_t)N * H / 2);
  unsigned short* h2hi   = (unsigned short*)alloc((size_t)N * H / 2);
  unsigned short* h2lo   = (unsigned short*)alloc((size_t)N * H / 2);
  unsigned short* h1hi   = (unsigned short*)alloc((size_t)C * H / 2);
  unsigned short* h1lo   = (unsigned short*)alloc((size_t)C * H / 2);
  unsigned short* hpshi  = (unsigned short*)alloc((size_t)C * H / 2);
  unsigned short* hpslo  = (unsigned short*)alloc((size_t)C * H / 2);
  unsigned short* cshi   = (unsigned short*)alloc((size_t)N * C / 2);
  unsigned short* cslo   = (unsigned short*)alloc((size_t)N * C / 2);
  unsigned short* hpst_hi= (unsigned short*)alloc((size_t)H * C / 2);
  unsigned short* hpst_lo= (unsigned short*)alloc((size_t)H * C / 2);
  unsigned short* h2t_hi = (unsigned short*)alloc((size_t)H * N / 2);
  unsigned short* h2t_lo = (unsigned short*)alloc((size_t)H * N / 2);
  unsigned short* xt_hi  = (unsigned short*)alloc((size_t)H * N / 2);
  unsigned short* xt_lo  = (unsigned short*)alloc((size_t)H * N / 2);
  float2* cand    = (float2*)alloc((size_t)N * 128 * 5 * 2);
  float* partial  = W + o;
  const int Z = 8;        // flash split-KV (8*N*128 fp32)
  const int ZG = 64;      // genA split-K (64*C*128 fp32); same region
  const int ZK = 8;       // cs-GEMM split-K (8*N*128 fp32); same region

  dim3 blk(256);
  // --- ps branch ---
  k_xprep<<<dim3(N / 32), blk, 0, stream>>>(x, xhi, xlo, xnorm, xt_hi, xt_lo,
                                            hidden2, colsum_c, colsum_m);
  k_colsum_s2c<<<dim3(C / 64, 16), dim3(64), 0, stream>>>(cm, mv, colsum_c);
  k_mfma_genA<1><<<dim3(1, C / 128, ZG), blk, 0, stream>>>(
      cm, mv, colsum_c, nullptr, xt_hi, xt_lo, partial, N / ZG);
  k_reduce<<<dim3(C * H / 4 / 256), blk, 0, stream>>>(
      partial, hidden1, ZG, (size_t)C * H, (size_t)C * H / 4, nullptr,
      h1hi, h1lo, nullptr, valid1);
  k_mfma_nt<<<dim3(C / 128, N / 64), blk, 0, stream>>>(
      xhi, xlo, h1hi, h1lo, scores, C);
  k_colstats<<<dim3(C), blk, 0, stream>>>(scores, colmax, colsumexp);
  k_mfma_genA<2><<<dim3(1, C / 128, ZG), blk, 0, stream>>>(
      scores, nullptr, colmax, colsumexp, xt_hi, xt_lo, partial, N / ZG);
  k_reduce<<<dim3(C * H / 4 / 256), blk, 0, stream>>>(
      partial, hidden_ps, ZG, (size_t)C * H, (size_t)C * H / 4, valid1,
      hpshi, hpslo, hnorm_ps, nullptr);
  k_mfma_nt<<<dim3(C / 128, N / 64), blk, 0, stream>>>(
      xhi, xlo, hpshi, hpslo, scores, C);
  k_cs_softmax<<<dim3(N), blk, 0, stream>>>(scores, xnorm, hnorm_ps, valid1,
                                            cshi, cslo);
  k_tsplit<<<dim3(C / 32), blk, 0, stream>>>(hidden_ps, hpst_hi, hpst_lo, C);
  k_mfma_kn<<<dim3(1, N / 128, ZK), blk, 0, stream>>>(
      cshi, cslo, hpst_hi, hpst_lo, partial, C, C / ZK);
  k_ps_tail<<<dim3(N / 32), blk, 0, stream>>>(
      partial, ZK, x, W_ps, b_ps, W_psb, b_psb, W_psf, b_psf,
      hbuf, hhat, hhathi, hhatlo, diagv, all_info);
  // --- hs branch ---
  k_snt<<<dim3(N / 128, N / 128), dim3(512), 0, stream>>>(
      hhathi, hhatlo, cand);
  k_rowtop2s<<<dim3(N / 4), blk, 0, stream>>>(cand, hhat, hbuf, hidden2,
                                              colsum_m);
  k_fin2t<<<dim3(N / 32), blk, 0, stream>>>(hbuf, diagv, colsum_m, hidden2,
                                            h2hi, h2lo, valid2f, h2t_hi, h2t_lo);
  k_flash<<<dim3(Z, N / 128), dim3(512), 0, stream>>>(
      hhathi, hhatlo, h2hi, h2lo, h2t_hi, h2t_lo, valid2f, partial, plsum,
      N / Z);
  k_hs_tail<<<dim3(N / 32), blk, 0, stream>>>(
      partial, plsum, Z, hbuf, all_info, W_hs, b_hs, W_hsf, b_hsf, W_hsb, b_hsb,
      W_in, b_in, W_out, b_out, out);
}

// Round 12
// 350.352 us; speedup vs baseline: 1.2514x; 1.2514x over previous
//
#include <hip/hip_runtime.h>
#include <hip/hip_fp16.h>
#include <math.h>

#define N 4096
#define C 512
#define H 128
#define PAD 40  // ushort row pitch for 32-col MFMA LDS staging tiles
#define WP 136  // ushort row pitch for full-K (128 col) LDS tiles
#define FWP 136 // ushort row pitch for flash Q/P tiles
#define SP 136  // ushort row pitch for S-tile scan buffer

typedef __attribute__((ext_vector_type(8))) short bf16x8;
typedef __attribute__((ext_vector_type(4))) float f32x4;

// ---------------- helpers ----------------

__device__ inline float wave_reduce_sum(float v) {
#pragma unroll
  for (int m = 32; m; m >>= 1) v += __shfl_xor(v, m);
  return v;
}

__device__ inline float lrelu(float v) { return v > 0.f ? v : 0.01f * v; }

__device__ inline bool better(float v, int j, float w, int k) {
  return (v > w) || (v == w && j < k);
}

__device__ inline void top3_ins(float v, int j, float& v0, int& j0,
                                float& v1, int& j1, float& v2, int& j2) {
  if (better(v, j, v0, j0)) { v2 = v1; j2 = j1; v1 = v0; j1 = j0; v0 = v; j0 = j; }
  else if (better(v, j, v1, j1)) { v2 = v1; j2 = j1; v1 = v; j1 = j; }
  else if (better(v, j, v2, j2)) { v2 = v; j2 = j; }
}

__device__ inline void ins5(float s, int j, float v[5], int jx[5]) {
  if (!better(s, j, v[4], jx[4])) return;
  if (better(s, j, v[0], jx[0])) {
    v[4]=v[3]; jx[4]=jx[3]; v[3]=v[2]; jx[3]=jx[2]; v[2]=v[1]; jx[2]=jx[1];
    v[1]=v[0]; jx[1]=jx[0]; v[0]=s; jx[0]=j;
  } else if (better(s, j, v[1], jx[1])) {
    v[4]=v[3]; jx[4]=jx[3]; v[3]=v[2]; jx[3]=jx[2]; v[2]=v[1]; jx[2]=jx[1];
    v[1]=s; jx[1]=j;
  } else if (better(s, j, v[2], jx[2])) {
    v[4]=v[3]; jx[4]=jx[3]; v[3]=v[2]; jx[3]=jx[2]; v[2]=s; jx[2]=j;
  } else if (better(s, j, v[3], jx[3])) {
    v[4]=v[3]; jx[4]=jx[3]; v[3]=s; jx[3]=j;
  } else {
    v[4]=s; jx[4]=j;
  }
}

__device__ inline unsigned short f2bf(float f) {
  unsigned u = __float_as_uint(f);
  unsigned r = u + 0x7fffu + ((u >> 16) & 1u);
  return (unsigned short)(r >> 16);
}
__device__ inline float bf2f(unsigned short h) {
  return __uint_as_float(((unsigned)h) << 16);
}

// ---- x prep: linear pairs + xnorm + transposed pairs + workspace zeroing ----
__global__ __launch_bounds__(256) void k_xprep(
    const float* __restrict__ in, unsigned short* __restrict__ hi,
    unsigned short* __restrict__ lo, float* __restrict__ nrm,
    unsigned short* __restrict__ thi, unsigned short* __restrict__ tlo,
    float* __restrict__ hidden2, float* __restrict__ colsum_c,
    float* __restrict__ colsum_m) {
  __shared__ float tile[32][132];
  int r0 = blockIdx.x * 32, tid = threadIdx.x;
  float4 zf = {0.f, 0.f, 0.f, 0.f};
#pragma unroll
  for (int q = 0; q < 4; q++) {
    size_t zi = ((size_t)blockIdx.x * 1024 + q * 256 + tid) * 4;
    *(float4*)&hidden2[zi] = zf;
  }
  if (blockIdx.x == 0 && tid < 128) *(float4*)&colsum_c[tid * 4] = zf;
  if (blockIdx.x == 1) {
#pragma unroll
    for (int q = 0; q < 4; q++) *(float4*)&colsum_m[(q * 256 + tid) * 4] = zf;
  }
#pragma unroll
  for (int q = 0; q < 4; q++) {
    int f = q * 256 + tid;
    int row = f >> 5, ch = f & 31;
    size_t gi = (size_t)(r0 + row) * 128 + ch * 4;
    float4 v = *(const float4*)&in[gi];
    *(float4*)&tile[row][ch * 4] = v;
    float vv[4] = {v.x, v.y, v.z, v.w};
    unsigned short hq[4], lq[4];
    float ss = 0.f;
#pragma unroll
    for (int c = 0; c < 4; c++) {
      ss += vv[c] * vv[c];
      hq[c] = f2bf(vv[c]);
      lq[c] = f2bf(vv[c] - bf2f(hq[c]));
    }
    uint2 ph = {(unsigned)hq[0] | ((unsigned)hq[1] << 16),
                (unsigned)hq[2] | ((unsigned)hq[3] << 16)};
    uint2 pl = {(unsigned)lq[0] | ((unsigned)lq[1] << 16),
                (unsigned)lq[2] | ((unsigned)lq[3] << 16)};
    *(uint2*)&hi[gi] = ph;
    *(uint2*)&lo[gi] = pl;
#pragma unroll
    for (int m = 16; m; m >>= 1) ss += __shfl_xor(ss, m);
    if ((tid & 31) == 0) nrm[r0 + row] = sqrtf(ss);
  }
  __syncthreads();
  int c = tid & 127, half = tid >> 7;
  unsigned short hh[16], ll[16];
#pragma unroll
  for (int rr = 0; rr < 16; rr++) {
    float v = tile[half * 16 + rr][c];
    hh[rr] = f2bf(v);
    ll[rr] = f2bf(v - bf2f(hh[rr]));
  }
  size_t off = (size_t)c * N + r0 + half * 16;
  uint4 ph0 = {(unsigned)hh[0] | ((unsigned)hh[1] << 16), (unsigned)hh[2] | ((unsigned)hh[3] << 16),
               (unsigned)hh[4] | ((unsigned)hh[5] << 16), (unsigned)hh[6] | ((unsigned)hh[7] << 16)};
  uint4 ph1 = {(unsigned)hh[8] | ((unsigned)hh[9] << 16), (unsigned)hh[10] | ((unsigned)hh[11] << 16),
               (unsigned)hh[12] | ((unsigned)hh[13] << 16), (unsigned)hh[14] | ((unsigned)hh[15] << 16)};
  uint4 pl0 = {(unsigned)ll[0] | ((unsigned)ll[1] << 16), (unsigned)ll[2] | ((unsigned)ll[3] << 16),
               (unsigned)ll[4] | ((unsigned)ll[5] << 16), (unsigned)ll[6] | ((unsigned)ll[7] << 16)};
  uint4 pl1 = {(unsigned)ll[8] | ((unsigned)ll[9] << 16), (unsigned)ll[10] | ((unsigned)ll[11] << 16),
               (unsigned)ll[12] | ((unsigned)ll[13] << 16), (unsigned)ll[14] | ((unsigned)ll[15] << 16)};
  *(uint4*)&thi[off] = ph0; *(uint4*)&thi[off + 8] = ph1;
  *(uint4*)&tlo[off] = pl0; *(uint4*)&tlo[off + 8] = pl1;
}

// transpose + split: in [R,128] fp32 -> thi/tlo [128,R] ushort
__global__ __launch_bounds__(256) void k_tsplit(const float* __restrict__ in,
                                                unsigned short* __restrict__ thi,
                                                unsigned short* __restrict__ tlo,
                                                int R) {
  __shared__ float tile[32][132];
  int r0 = blockIdx.x * 32, tid = threadIdx.x;
#pragma unroll
  for (int q = 0; q < 4; q++) {
    int f = q * 256 + tid;
    int row = f >> 5, ch = f & 31;
    *(float4*)&tile[row][ch * 4] = *(const float4*)&in[(size_t)(r0 + row) * 128 + ch * 4];
  }
  __syncthreads();
  int c = tid & 127, half = tid >> 7;
  unsigned short hh[16], ll[16];
#pragma unroll
  for (int rr = 0; rr < 16; rr++) {
    float v = tile[half * 16 + rr][c];
    hh[rr] = f2bf(v);
    ll[rr] = f2bf(v - bf2f(hh[rr]));
  }
  size_t off = (size_t)c * R + r0 + half * 16;
  uint4 ph0 = {(unsigned)hh[0] | ((unsigned)hh[1] << 16), (unsigned)hh[2] | ((unsigned)hh[3] << 16),
               (unsigned)hh[4] | ((unsigned)hh[5] << 16), (unsigned)hh[6] | ((unsigned)hh[7] << 16)};
  uint4 ph1 = {(unsigned)hh[8] | ((unsigned)hh[9] << 16), (unsigned)hh[10] | ((unsigned)hh[11] << 16),
               (unsigned)hh[12] | ((unsigned)hh[13] << 16), (unsigned)hh[14] | ((unsigned)hh[15] << 16)};
  uint4 pl0 = {(unsigned)ll[0] | ((unsigned)ll[1] << 16), (unsigned)ll[2] | ((unsigned)ll[3] << 16),
               (unsigned)ll[4] | ((unsigned)ll[5] << 16), (unsigned)ll[6] | ((unsigned)ll[7] << 16)};
  uint4 pl1 = {(unsigned)ll[8] | ((unsigned)ll[9] << 16), (unsigned)ll[10] | ((unsigned)ll[11] << 16),
               (unsigned)ll[12] | ((unsigned)ll[13] << 16), (unsigned)ll[14] | ((unsigned)ll[15] << 16)};
  *(uint4*)&thi[off] = ph0; *(uint4*)&thi[off + 8] = ph1;
  *(uint4*)&tlo[off] = pl0; *(uint4*)&tlo[off + 8] = pl1;
}

// ---------------- small kernels ----------------

__global__ __launch_bounds__(64) void k_colsum_s2c(
    const float* __restrict__ cm, const float* __restrict__ mv,
    float* __restrict__ colsum_c) {
  int c = blockIdx.x * 64 + threadIdx.x;
  int i0 = blockIdx.y * 256;
  float acc = 0.f;
  for (int i = i0; i < i0 + 256; i++) acc += cm[(size_t)i * C + c] * mv[i];
  atomicAdd(&colsum_c[c], acc);
}

__global__ __launch_bounds__(256) void k_colstats(const float* __restrict__ sc,
                                                  float* __restrict__ colmax,
                                                  float* __restrict__ colsum) {
  __shared__ float red[256];
  int c = blockIdx.x, t = threadIdx.x;
  float v[16];
  float m = -3e38f;
#pragma unroll
  for (int q = 0; q < 16; q++) {
    v[q] = sc[(size_t)(q * 256 + t) * C + c];
    m = fmaxf(m, v[q]);
  }
  red[t] = m; __syncthreads();
  for (int s = 128; s; s >>= 1) { if (t < s) red[t] = fmaxf(red[t], red[t + s]); __syncthreads(); }
  m = red[0]; __syncthreads();
  float sum = 0.f;
#pragma unroll
  for (int q = 0; q < 16; q++) sum += __expf(v[q] - m);
  red[t] = sum; __syncthreads();
  for (int s = 128; s; s >>= 1) { if (t < s) red[t] += red[t + s]; __syncthreads(); }
  if (t == 0) { colmax[c] = m; colsum[c] = red[0]; }
}

// row softmax of cos-sim -> bf16 hi/lo pairs
__global__ __launch_bounds__(256) void k_cs_softmax(
    const float* __restrict__ sc, const float* __restrict__ xnorm,
    const float* __restrict__ hnorm, const float* __restrict__ valid1,
    unsigned short* __restrict__ cshi, unsigned short* __restrict__ cslo) {
  __shared__ float red[256];
  int i = blockIdx.x, t = threadIdx.x;
  float xn = xnorm[i];
  float r0 = sc[(size_t)i * C + t], r1 = sc[(size_t)i * C + 256 + t];
  float d0 = xn * hnorm[t], d1 = xn * hnorm[256 + t];
  float c0 = r0 / (d0 == 0.f ? 1.f : d0);
  float c1 = r1 / (d1 == 0.f ? 1.f : d1);
  float s0 = (valid1[t] != 0.f) ? c0 : -3e38f;
  float s1 = (valid1[256 + t] != 0.f) ? c1 : -3e38f;
  red[t] = fmaxf(s0, s1); __syncthreads();
  for (int s = 128; s; s >>= 1) { if (t < s) red[t] = fmaxf(red[t], red[t + s]); __syncthreads(); }
  float m = red[0]; __syncthreads();
  float p0 = (s0 > -1e37f) ? __expf(s0 - m) : 0.f;
  float p1 = (s1 > -1e37f) ? __expf(s1 - m) : 0.f;
  red[t] = p0 + p1; __syncthreads();
  for (int s = 128; s; s >>= 1) { if (t < s) red[t] += red[t + s]; __syncthreads(); }
  float inv = 1.f / red[0];
  float a = p0 * inv, b = p1 * inv;
  unsigned short ha = f2bf(a), hb = f2bf(b);
  cshi[(size_t)i * C + t] = ha;
  cslo[(size_t)i * C + t] = f2bf(a - bf2f(ha));
  cshi[(size_t)i * C + 256 + t] = hb;
  cslo[(size_t)i * C + 256 + t] = f2bf(b - bf2f(hb));
}

// finalize hidden2 (32 rows/block) + h2hat pairs + valid2f + transposed pairs
__global__ __launch_bounds__(256) void k_fin2t(
    const float* __restrict__ h, const float* __restrict__ diagv,
    const float* __restrict__ colsum_m, float* __restrict__ hidden2,
    unsigned short* __restrict__ h2hi, unsigned short* __restrict__ h2lo,
    float* __restrict__ valid2f, unsigned short* __restrict__ thi,
    unsigned short* __restrict__ tlo) {
  __shared__ float tile[32][132];
  int j0 = blockIdx.x * 32, tid = threadIdx.x;
  int row = tid >> 3, c0 = (tid & 7) * 16;
  int j = j0 + row;
  float add = (colsum_m[j] != 0.f) ? diagv[j] : 0.f;
  float a16[16];
  float s = 0.f, ss = 0.f;
#pragma unroll
  for (int q = 0; q < 16; q++) {
    float a = hidden2[(size_t)j * H + c0 + q] + add * h[(size_t)j * H + c0 + q];
    a16[q] = a;
    s += a; ss += a * a;
  }
#pragma unroll
  for (int m = 4; m; m >>= 1) { s += __shfl_xor(s, m); ss += __shfl_xor(ss, m); }
  bool valid = (s != 0.f);
  float inv = (valid && ss > 0.f) ? (1.f / sqrtf(ss)) : 1.f;
  size_t base = (size_t)j * H + c0;
  unsigned short hh16[16], ll16[16];
#pragma unroll
  for (int q = 0; q < 16; q++) {
    a16[q] = valid ? a16[q] : 0.f;
    float va = a16[q] * inv;
    hh16[q] = f2bf(va);
    ll16[q] = f2bf(va - bf2f(hh16[q]));
    tile[row][c0 + q] = a16[q];
  }
#pragma unroll
  for (int q4 = 0; q4 < 4; q4++) {
    float4 fv = {a16[q4 * 4], a16[q4 * 4 + 1], a16[q4 * 4 + 2], a16[q4 * 4 + 3]};
    *(float4*)&hidden2[base + q4 * 4] = fv;
  }
  uint4 ph0 = {(unsigned)hh16[0] | ((unsigned)hh16[1] << 16), (unsigned)hh16[2] | ((unsigned)hh16[3] << 16),
               (unsigned)hh16[4] | ((unsigned)hh16[5] << 16), (unsigned)hh16[6] | ((unsigned)hh16[7] << 16)};
  uint4 ph1 = {(unsigned)hh16[8] | ((unsigned)hh16[9] << 16), (unsigned)hh16[10] | ((unsigned)hh16[11] << 16),
               (unsigned)hh16[12] | ((unsigned)hh16[13] << 16), (unsigned)hh16[14] | ((unsigned)hh16[15] << 16)};
  uint4 pl0 = {(unsigned)ll16[0] | ((unsigned)ll16[1] << 16), (unsigned)ll16[2] | ((unsigned)ll16[3] << 16),
               (unsigned)ll16[4] | ((unsigned)ll16[5] << 16), (unsigned)ll16[6] | ((unsigned)ll16[7] << 16)};
  uint4 pl1 = {(unsigned)ll16[8] | ((unsigned)ll16[9] << 16), (unsigned)ll16[10] | ((unsigned)ll16[11] << 16),
               (unsigned)ll16[12] | ((unsigned)ll16[13] << 16), (unsigned)ll16[14] | ((unsigned)ll16[15] << 16)};
  *(uint4*)&h2hi[base] = ph0; *(uint4*)&h2hi[base + 8] = ph1;
  *(uint4*)&h2lo[base] = pl0; *(uint4*)&h2lo[base + 8] = pl1;
  if ((tid & 7) == 0) valid2f[j] = valid ? 1.f : 0.f;
  __syncthreads();
  int c = tid & 127, half = tid >> 7;
  unsigned short th[16], tl[16];
#pragma unroll
  for (int rr = 0; rr < 16; rr++) {
    float v = tile[half * 16 + rr][c];
    th[rr] = f2bf(v);
    tl[rr] = f2bf(v - bf2f(th[rr]));
  }
  size_t off = (size_t)c * N + j0 + half * 16;
  uint4 tp0 = {(unsigned)th[0] | ((unsigned)th[1] << 16), (unsigned)th[2] | ((unsigned)th[3] << 16),
               (unsigned)th[4] | ((unsigned)th[5] << 16), (unsigned)th[6] | ((unsigned)th[7] << 16)};
  uint4 tp1 = {(unsigned)th[8] | ((unsigned)th[9] << 16), (unsigned)th[10] | ((unsigned)th[11] << 16),
               (unsigned)th[12] | ((unsigned)th[13] << 16), (unsigned)th[14] | ((unsigned)th[15] << 16)};
  uint4 tq0 = {(unsigned)tl[0] | ((unsigned)tl[1] << 16), (unsigned)tl[2] | ((unsigned)tl[3] << 16),
               (unsigned)tl[4] | ((unsigned)tl[5] << 16), (unsigned)tl[6] | ((unsigned)tl[7] << 16)};
  uint4 tq1 = {(unsigned)tl[8] | ((unsigned)tl[9] << 16), (unsigned)tl[10] | ((unsigned)tl[11] << 16),
               (unsigned)tl[12] | ((unsigned)tl[13] << 16), (unsigned)tl[14] | ((unsigned)tl[15] << 16)};
  *(uint4*)&thi[off] = tp0; *(uint4*)&thi[off + 8] = tp1;
  *(uint4*)&tlo[off] = tq0; *(uint4*)&tlo[off + 8] = tq1;
}

// ---------------- bf16x3 MFMA NT GEMM: A[64,128] @ B[128,128]^T, fp32 out ----
__global__ __launch_bounds__(256) void k_mfma_nt(
    const unsigned short* __restrict__ Ahi, const unsigned short* __restrict__ Alo,
    const unsigned short* __restrict__ Bhi, const unsigned short* __restrict__ Blo,
    float* __restrict__ out, int Nn) {
  __shared__ __align__(16) unsigned short sAh[64 * PAD];
  __shared__ __align__(16) unsigned short sAl[64 * PAD];
  __shared__ __align__(16) unsigned short sBh[128 * PAD];
  __shared__ __align__(16) unsigned short sBl[128 * PAD];
  int tid = threadIdx.x;
  int bm = blockIdx.y * 64, bn = blockIdx.x * 128;
  int lane = tid & 63, w = tid >> 6;
  int wm = (w & 1) * 32, wn = (w >> 1) * 64;
  int l15 = lane & 15, quad = lane >> 4;
  f32x4 zero = {0.f, 0.f, 0.f, 0.f};
  f32x4 acc[2][4];
#pragma unroll
  for (int mt = 0; mt < 2; mt++)
#pragma unroll
    for (int nt = 0; nt < 4; nt++) acc[mt][nt] = zero;

  for (int kt = 0; kt < 128; kt += 32) {
    {
      int row = tid >> 2, ch = tid & 3;
      size_t ga = (size_t)(bm + row) * 128 + kt + ch * 8;
      int ls = row * PAD + ch * 8;
      *(uint4*)&sAh[ls] = *(const uint4*)&Ahi[ga];
      *(uint4*)&sAl[ls] = *(const uint4*)&Alo[ga];
    }
#pragma unroll
    for (int q = 0; q < 2; q++) {
      int f = q * 256 + tid;
      int row = f >> 2, ch = f & 3;
      size_t gb = (size_t)(bn + row) * 128 + kt + ch * 8;
      int ls = row * PAD + ch * 8;
      *(uint4*)&sBh[ls] = *(const uint4*)&Bhi[gb];
      *(uint4*)&sBl[ls] = *(const uint4*)&Blo[gb];
    }
    __syncthreads();
    bf16x8 ah[2], al[2], bh[4], bl[4];
#pragma unroll
    for (int t = 0; t < 2; t++) {
      int ar = (wm + t * 16 + l15) * PAD + quad * 8;
      ah[t] = *(const bf16x8*)&sAh[ar];
      al[t] = *(const bf16x8*)&sAl[ar];
    }
#pragma unroll
    for (int t = 0; t < 4; t++) {
      int br = (wn + t * 16 + l15) * PAD + quad * 8;
      bh[t] = *(const bf16x8*)&sBh[br];
      bl[t] = *(const bf16x8*)&sBl[br];
    }
#pragma unroll
    for (int mt = 0; mt < 2; mt++)
#pragma unroll
      for (int nt = 0; nt < 4; nt++) {
        acc[mt][nt] = __builtin_amdgcn_mfma_f32_16x16x32_bf16(ah[mt], bh[nt], acc[mt][nt], 0, 0, 0);
        acc[mt][nt] = __builtin_amdgcn_mfma_f32_16x16x32_bf16(ah[mt], bl[nt], acc[mt][nt], 0, 0, 0);
        acc[mt][nt] = __builtin_amdgcn_mfma_f32_16x16x32_bf16(al[mt], bh[nt], acc[mt][nt], 0, 0, 0);
      }
    __syncthreads();
  }
#pragma unroll
  for (int mt = 0; mt < 2; mt++) {
#pragma unroll
    for (int nt = 0; nt < 4; nt++) {
      int col = bn + wn + nt * 16 + l15;
#pragma unroll
      for (int rg = 0; rg < 4; rg++) {
        int row = bm + wm + mt * 16 + quad * 4 + rg;
        out[(size_t)row * Nn + col] = acc[mt][nt][rg];
      }
    }
  }
}

// ---------------- S = hhat@hhat^T + fused quarter-row top-5 screen -----------
__global__ __launch_bounds__(512) void k_snt(
    const unsigned short* __restrict__ Ahi, const unsigned short* __restrict__ Alo,
    float2* __restrict__ cand) {
  __shared__ __align__(16) unsigned short sAh[128 * PAD];
  __shared__ __align__(16) unsigned short sAl[128 * PAD];
  __shared__ __align__(16) unsigned short sBh[128 * PAD];
  __shared__ __align__(16) unsigned short sBl[128 * PAD];
  __shared__ __align__(16) unsigned short sS[128 * SP];
  int tid = threadIdx.x;
  int bm = blockIdx.y * 128, bn = blockIdx.x * 128;
  int lane = tid & 63, w = tid >> 6;
  int wm = (w & 3) * 32, wn = (w >> 2) * 64;
  int l15 = lane & 15, quad = lane >> 4;
  f32x4 zero = {0.f, 0.f, 0.f, 0.f};
  f32x4 acc[2][4];
#pragma unroll
  for (int mt = 0; mt < 2; mt++)
#pragma unroll
    for (int nt = 0; nt < 4; nt++) acc[mt][nt] = zero;

  for (int kt = 0; kt < 128; kt += 32) {
    {
      int row = tid >> 2, ch = tid & 3;
      size_t ga = (size_t)(bm + row) * 128 + kt + ch * 8;
      size_t gb = (size_t)(bn + row) * 128 + kt + ch * 8;
      int ls = row * PAD + ch * 8;
      *(uint4*)&sAh[ls] = *(const uint4*)&Ahi[ga];
      *(uint4*)&sAl[ls] = *(const uint4*)&Alo[ga];
      *(uint4*)&sBh[ls] = *(const uint4*)&Ahi[gb];
      *(uint4*)&sBl[ls] = *(const uint4*)&Alo[gb];
    }
    __syncthreads();
    bf16x8 ah[2], al[2], bh[4], bl[4];
#pragma unroll
    for (int t = 0; t < 2; t++) {
      int ar = (wm + t * 16 + l15) * PAD + quad * 8;
      ah[t] = *(const bf16x8*)&sAh[ar];
      al[t] = *(const bf16x8*)&sAl[ar];
    }
#pragma unroll
    for (int t = 0; t < 4; t++) {
      int br = (wn + t * 16 + l15) * PAD + quad * 8;
      bh[t] = *(const bf16x8*)&sBh[br];
      bl[t] = *(const bf16x8*)&sBl[br];
    }
#pragma unroll
    for (int mt = 0; mt < 2; mt++)
#pragma unroll
      for (int nt = 0; nt < 4; nt++) {
        acc[mt][nt] = __builtin_amdgcn_mfma_f32_16x16x32_bf16(ah[mt], bh[nt], acc[mt][nt], 0, 0, 0);
        acc[mt][nt] = __builtin_amdgcn_mfma_f32_16x16x32_bf16(ah[mt], bl[nt], acc[mt][nt], 0, 0, 0);
        acc[mt][nt] = __builtin_amdgcn_mfma_f32_16x16x32_bf16(al[mt], bh[nt], acc[mt][nt], 0, 0, 0);
      }
    __syncthreads();
  }
#pragma unroll
  for (int mt = 0; mt < 2; mt++)
#pragma unroll
    for (int nt = 0; nt < 4; nt++) {
      int coll = wn + nt * 16 + l15;
#pragma unroll
      for (int rg = 0; rg < 4; rg++) {
        int rowl = wm + mt * 16 + quad * 4 + rg;
        float v = (bm + rowl == bn + coll) ? 0.f : acc[mt][nt][rg];
        sS[rowl * SP + coll] = __half_as_ushort(__float2half(v));
      }
    }
  __syncthreads();
  int r = tid >> 2, qf = tid & 3;
  const unsigned short* rowp = &sS[r * SP + qf * 32];
  int cbase = bn + qf * 32;
  float v5[5] = {-3e38f, -3e38f, -3e38f, -3e38f, -3e38f};
  int j5[5] = {0x7fffffff, 0x7fffffff, 0x7fffffff, 0x7fffffff, 0x7fffffff};
#pragma unroll
  for (int q = 0; q < 4; q++) {
    uint4 p = *(const uint4*)&rowp[q * 8];
    unsigned pk[4] = {p.x, p.y, p.z, p.w};
#pragma unroll
    for (int c2 = 0; c2 < 4; c2++) {
      float e0 = __half2float(__ushort_as_half((unsigned short)(pk[c2] & 0xffffu)));
      float e1 = __half2float(__ushort_as_half((unsigned short)(pk[c2] >> 16)));
      ins5(e0, cbase + q * 8 + c2 * 2, v5, j5);
      ins5(e1, cbase + q * 8 + c2 * 2 + 1, v5, j5);
    }
  }
  int slot = (bn >> 5) + qf;
  float2* cp = &cand[((size_t)(bm + r) * 128 + slot) * 5];
#pragma unroll
  for (int c2 = 0; c2 < 5; c2++) cp[c2] = {v5[c2], __int_as_float(j5[c2])};
}

// -------- row top-k merge + exact fp32 rescore + fused scatter --------
__global__ __launch_bounds__(256) void k_rowtop2s(
    const float2* __restrict__ cand, const float* __restrict__ hhat,
    const float* __restrict__ h, float* __restrict__ hidden2,
    float* __restrict__ colsum_m) {
  int i = blockIdx.x * 4 + (threadIdx.x >> 6);
  int lane = threadIdx.x & 63;
  const float2* cr = &cand[(size_t)i * 640];
  float v[5] = {-3e38f, -3e38f, -3e38f, -3e38f, -3e38f};
  int jx[5] = {0x7fffffff, 0x7fffffff, 0x7fffffff, 0x7fffffff, 0x7fffffff};
#pragma unroll
  for (int c = 0; c < 10; c++) {
    float2 p = cr[lane * 10 + c];
    ins5(p.x, __float_as_int(p.y), v, jx);
  }
#pragma unroll
  for (int d = 1; d < 64; d <<= 1) {
    float fv[5]; int fj[5];
#pragma unroll
    for (int c = 0; c < 5; c++) { fv[c] = __shfl_xor(v[c], d); fj[c] = __shfl_xor(jx[c], d); }
#pragma unroll
    for (int c = 0; c < 5; c++) ins5(fv[c], fj[c], v, jx);
  }
  const float* hi = &hhat[(size_t)i * H];
  float b0 = -3e38f, b1 = -3e38f, b2 = -3e38f;
  int q0 = 0, q1 = 0, q2 = 0;
#pragma unroll
  for (int c = 0; c < 5; c++) {
    int j = jx[c];
    float s;
    if (j == i) {
      s = 0.f;
    } else {
      const float* hj = &hhat[(size_t)j * H];
      float p = hi[lane] * hj[lane] + hi[lane + 64] * hj[lane + 64];
      s = wave_reduce_sum(p);
    }
    top3_ins(s, j, b0, q0, b1, q1, b2, q2);
  }
  float h0 = h[(size_t)i * H + lane], h1 = h[(size_t)i * H + 64 + lane];
  float bv[3] = {b0, b1, b2};
  int qv[3] = {q0, q1, q2};
#pragma unroll
  for (int s = 0; s < 3; s++) {
    float vv = bv[s];
    int j = qv[s];
    atomicAdd(&hidden2[(size_t)j * H + lane], vv * h0);
    atomicAdd(&hidden2[(size_t)j * H + 64 + lane], vv * h1);
    if (lane == s) atomicAdd(&colsum_m[j], vv);
  }
}

// ---------------- flash-fused hs_pre numerator (ring double-buffer) ----------
__global__ __launch_bounds__(512) void k_flash(
    const unsigned short* __restrict__ Qhi, const unsigned short* __restrict__ Qlo,
    const unsigned short* __restrict__ Khi, const unsigned short* __restrict__ Klo,
    const unsigned short* __restrict__ Vthi, const unsigned short* __restrict__ Vtlo,
    const float* __restrict__ valid2f, float* __restrict__ partialU,
    float* __restrict__ plsum, int KVC) {
  __shared__ __align__(16) unsigned short sQh[128 * FWP];
  __shared__ __align__(16) unsigned short sQl[128 * FWP];
  __shared__ __align__(16) unsigned short sP[128 * FWP];
  __shared__ __align__(16) unsigned short sBh[2][128 * PAD];
  __shared__ __align__(16) unsigned short sBl[2][128 * PAD];
  __shared__ float lsum_s[128];
  int tid = threadIdx.x;
  int z = blockIdx.x;
  int bm = blockIdx.y * 128;
  int j0 = z * KVC;
  int lane = tid & 63, w = tid >> 6;
  int wm = (w & 3) * 32, wn = (w >> 2) * 64;
  int l15 = lane & 15, quad = lane >> 4;
  int srow = tid >> 2, sch = tid & 3;
  int sls = srow * PAD + sch * 8;
#pragma unroll
  for (int q = 0; q < 4; q++) {
    int f = q * 512 + tid;
    int row = f >> 4, ch = f & 15;
    size_t ga = (size_t)(bm + row) * 128 + ch * 8;
    int ls = row * FWP + ch * 8;
    *(uint4*)&sQh[ls] = *(const uint4*)&Qhi[ga];
    *(uint4*)&sQl[ls] = *(const uint4*)&Qlo[ga];
  }
  if (tid < 128) lsum_s[tid] = 0.f;
  {
    size_t a = (size_t)(j0 + srow) * 128 + sch * 8;
    uint4 rh = *(const uint4*)&Khi[a];
    uint4 rl = *(const uint4*)&Klo[a];
    __syncthreads();
    *(uint4*)&sBh[0][sls] = rh;
    *(uint4*)&sBl[0][sls] = rl;
  }
  __syncthreads();
  int cur = 0;
  f32x4 zero = {0.f, 0.f, 0.f, 0.f};
  f32x4 uacc[2][4];
#pragma unroll
  for (int mt = 0; mt < 2; mt++)
#pragma unroll
    for (int nt = 0; nt < 4; nt++) uacc[mt][nt] = zero;

  for (int jb = j0; jb < j0 + KVC; jb += 128) {
    float vm[4];
#pragma unroll
    for (int nt = 0; nt < 4; nt++) vm[nt] = valid2f[jb + wn + nt * 16 + l15];
    f32x4 qacc[2][4];
#pragma unroll
    for (int mt = 0; mt < 2; mt++)
#pragma unroll
      for (int nt = 0; nt < 4; nt++) qacc[mt][nt] = zero;
#pragma unroll
    for (int t = 0; t < 4; t++) {
      uint4 nrh, nrl;
      if (t < 3) {
        size_t a = (size_t)(jb + srow) * 128 + (t + 1) * 32 + sch * 8;
        nrh = *(const uint4*)&Khi[a];
        nrl = *(const uint4*)&Klo[a];
      } else {
        size_t a = (size_t)srow * N + jb + sch * 8;
        nrh = *(const uint4*)&Vthi[a];
        nrl = *(const uint4*)&Vtlo[a];
      }
      int kt = t * 32;
      bf16x8 ah[2], al[2], bh[4], bl[4];
#pragma unroll
      for (int tt = 0; tt < 2; tt++) {
        int ar = (wm + tt * 16 + l15) * FWP + kt + quad * 8;
        ah[tt] = *(const bf16x8*)&sQh[ar];
        al[tt] = *(const bf16x8*)&sQl[ar];
      }
#pragma unroll
      for (int tt = 0; tt < 4; tt++) {
        int br = (wn + tt * 16 + l15) * PAD + quad * 8;
        bh[tt] = *(const bf16x8*)&sBh[cur][br];
        bl[tt] = *(const bf16x8*)&sBl[cur][br];
      }
#pragma unroll
      for (int mt = 0; mt < 2; mt++)
#pragma unroll
        for (int nt = 0; nt < 4; nt++) {
          qacc[mt][nt] = __builtin_amdgcn_mfma_f32_16x16x32_bf16(ah[mt], bh[nt], qacc[mt][nt], 0, 0, 0);
          qacc[mt][nt] = __builtin_amdgcn_mfma_f32_16x16x32_bf16(ah[mt], bl[nt], qacc[mt][nt], 0, 0, 0);
          qacc[mt][nt] = __builtin_amdgcn_mfma_f32_16x16x32_bf16(al[mt], bh[nt], qacc[mt][nt], 0, 0, 0);
        }
      *(uint4*)&sBh[cur ^ 1][sls] = nrh;
      *(uint4*)&sBl[cur ^ 1][sls] = nrl;
      __syncthreads();
      cur ^= 1;
    }
#pragma unroll
    for (int mt = 0; mt < 2; mt++) {
#pragma unroll
      for (int rg = 0; rg < 4; rg++) {
        int row = wm + mt * 16 + quad * 4 + rg;
        float rs = 0.f;
#pragma unroll
        for (int nt = 0; nt < 4; nt++) {
          float e = (vm[nt] != 0.f) ? __expf(qacc[mt][nt][rg] - 1.f) : 0.f;
          rs += e;
          sP[row * FWP + wn + nt * 16 + l15] = f2bf(e);
        }
#pragma unroll
        for (int d = 1; d < 16; d <<= 1) rs += __shfl_xor(rs, d);
        if (l15 == 0) atomicAdd(&lsum_s[row], rs);
      }
    }
    __syncthreads();
#pragma unroll
    for (int t = 0; t < 4; t++) {
      uint4 nrh = {0, 0, 0, 0}, nrl = {0, 0, 0, 0};
      bool have;
      if (t < 3) {
        have = true;
        size_t a = (size_t)srow * N + jb + (t + 1) * 32 + sch * 8;
        nrh = *(const uint4*)&Vthi[a];
        nrl = *(const uint4*)&Vtlo[a];
      } else {
        have = (jb + 128 < j0 + KVC);
        if (have) {
          size_t a = (size_t)(jb + 128 + srow) * 128 + sch * 8;
          nrh = *(const uint4*)&Khi[a];
          nrl = *(const uint4*)&Klo[a];
        }
      }
      int kt = t * 32;
      bf16x8 pa[2], vh[4], vl[4];
#pragma unroll
      for (int tt = 0; tt < 2; tt++) {
        int ar = (wm + tt * 16 + l15) * FWP + kt + quad * 8;
        pa[tt] = *(const bf16x8*)&sP[ar];
      }
#pragma unroll
      for (int tt = 0; tt < 4; tt++) {
        int br = (wn + tt * 16 + l15) * PAD + quad * 8;
        vh[tt] = *(const bf16x8*)&sBh[cur][br];
        vl[tt] = *(const bf16x8*)&sBl[cur][br];
      }
#pragma unroll
      for (int mt = 0; mt < 2; mt++)
#pragma unroll
        for (int nt = 0; nt < 4; nt++) {
          uacc[mt][nt] = __builtin_amdgcn_mfma_f32_16x16x32_bf16(pa[mt], vh[nt], uacc[mt][nt], 0, 0, 0);
          uacc[mt][nt] = __builtin_amdgcn_mfma_f32_16x16x32_bf16(pa[mt], vl[nt], uacc[mt][nt], 0, 0, 0);
        }
      if (have) {
        *(uint4*)&sBh[cur ^ 1][sls] = nrh;
        *(uint4*)&sBl[cur ^ 1][sls] = nrl;
      }
      __syncthreads();
      cur ^= 1;
    }
  }
  float* pU = partialU + (size_t)z * N * 128;
#pragma unroll
  for (int mt = 0; mt < 2; mt++)
#pragma unroll
    for (int nt = 0; nt < 4; nt++) {
      int col = wn + nt * 16 + l15;
#pragma unroll
      for (int rg = 0; rg < 4; rg++) {
        int row = bm + wm + mt * 16 + quad * 4 + rg;
        pU[(size_t)row * 128 + col] = uacc[mt][nt][rg];
      }
    }
  if (tid < 128) plsum[(size_t)z * N + bm + tid] = lsum_s[tid];
}

// ---------------- bf16 MFMA KN GEMM (split-K): partial[z] = A @ B ------------
__global__ __launch_bounds__(256) void k_mfma_kn(
    const unsigned short* __restrict__ Ahi, const unsigned short* __restrict__ Alo,
    const unsigned short* __restrict__ Bthi, const unsigned short* __restrict__ Btlo,
    float* __restrict__ partial, int lda, int KC) {
  __shared__ __align__(16) unsigned short sAh[128 * PAD];
  __shared__ __align__(16) unsigned short sAl[128 * PAD];
  __shared__ __align__(16) unsigned short sBh[128 * PAD];
  __shared__ __align__(16) unsigned short sBl[128 * PAD];
  int tid = threadIdx.x;
  int bm = blockIdx.y * 128;
  int k0 = blockIdx.z * KC;
  int lane = tid & 63, w = tid >> 6;
  int wm = (w & 1) * 64, wn = (w >> 1) * 64;
  int l15 = lane & 15, quad = lane >> 4;
  f32x4 zero = {0.f, 0.f, 0.f, 0.f};
  f32x4 acc[4][4];
#pragma unroll
  for (int mt = 0; mt < 4; mt++)
#pragma unroll
    for (int nt = 0; nt < 4; nt++) acc[mt][nt] = zero;

  for (int kt = 0; kt < KC; kt += 32) {
#pragma unroll
    for (int q = 0; q < 2; q++) {
      int f = tid * 2 + q;
      int row = f >> 2, ch = f & 3;
      size_t ga = (size_t)(bm + row) * lda + k0 + kt + ch * 8;
      size_t gb = (size_t)row * lda + k0 + kt + ch * 8;
      int ls = row * PAD + ch * 8;
      *(uint4*)&sAh[ls] = *(const uint4*)&Ahi[ga];
      *(uint4*)&sAl[ls] = *(const uint4*)&Alo[ga];
      *(uint4*)&sBh[ls] = *(const uint4*)&Bthi[gb];
      *(uint4*)&sBl[ls] = *(const uint4*)&Btlo[gb];
    }
    __syncthreads();
    bf16x8 ah[4], al[4], bh[4], bl[4];
#pragma unroll
    for (int t = 0; t < 4; t++) {
      int ar = (wm + t * 16 + l15) * PAD + quad * 8;
      ah[t] = *(const bf16x8*)&sAh[ar];
      al[t] = *(const bf16x8*)&sAl[ar];
      int br = (wn + t * 16 + l15) * PAD + quad * 8;
      bh[t] = *(const bf16x8*)&sBh[br];
      bl[t] = *(const bf16x8*)&sBl[br];
    }
#pragma unroll
    for (int mt = 0; mt < 4; mt++)
#pragma unroll
      for (int nt = 0; nt < 4; nt++) {
        acc[mt][nt] = __builtin_amdgcn_mfma_f32_16x16x32_bf16(ah[mt], bh[nt], acc[mt][nt], 0, 0, 0);
        acc[mt][nt] = __builtin_amdgcn_mfma_f32_16x16x32_bf16(ah[mt], bl[nt], acc[mt][nt], 0, 0, 0);
        acc[mt][nt] = __builtin_amdgcn_mfma_f32_16x16x32_bf16(al[mt], bh[nt], acc[mt][nt], 0, 0, 0);
      }
    __syncthreads();
  }
  float* pp = partial + (size_t)blockIdx.z * N * 128;
#pragma unroll
  for (int mt = 0; mt < 4; mt++)
#pragma unroll
    for (int nt = 0; nt < 4; nt++) {
      int col = wn + nt * 16 + l15;
#pragma unroll
      for (int rg = 0; rg < 4; rg++) {
        int row = bm + wm + mt * 16 + quad * 4 + rg;
        pp[(size_t)row * 128 + col] = acc[mt][nt][rg];
      }
    }
}

// ---------------- bf16x3 MFMA genA GEMM (split-K) ----------------
template <int AMODE>
__global__ __launch_bounds__(256) void k_mfma_genA(
    const float* __restrict__ P, const float* __restrict__ mv,
    const float* __restrict__ col1, const float* __restrict__ col2,
    const unsigned short* __restrict__ Bthi, const unsigned short* __restrict__ Btlo,
    float* __restrict__ partial, int KC) {
  __shared__ __align__(16) unsigned short sAh[128 * PAD];
  __shared__ __align__(16) unsigned short sAl[128 * PAD];
  __shared__ __align__(16) unsigned short sBh[128 * PAD];
  __shared__ __align__(16) unsigned short sBl[128 * PAD];
  int tid = threadIdx.x;
  int bm = blockIdx.y * 128;
  int k0 = blockIdx.z * KC;
  int lane = tid & 63, w = tid >> 6;
  int wm = (w & 1) * 64, wn = (w >> 1) * 64;
  int l15 = lane & 15, quad = lane >> 4;
  f32x4 zero = {0.f, 0.f, 0.f, 0.f};
  f32x4 acc[4][4];
#pragma unroll
  for (int mt = 0; mt < 4; mt++)
#pragma unroll
    for (int nt = 0; nt < 4; nt++) acc[mt][nt] = zero;

  for (int kt = 0; kt < KC; kt += 32) {
    int kr = tid >> 3;
    int mc = (tid & 7) * 16;
    int k = k0 + kt + kr;
    float mvk = (AMODE == 1) ? mv[k] : 0.f;
#pragma unroll
    for (int q = 0; q < 4; q++) {
      int m0 = mc + q * 4;
      float4 pv = *(const float4*)&P[(size_t)k * C + bm + m0];
      float4 c1 = *(const float4*)&col1[bm + m0];
      float wv[4];
      if (AMODE == 1) {
        wv[0] = pv.x * mvk / (c1.x * pv.x + 1.f);
        wv[1] = pv.y * mvk / (c1.y * pv.y + 1.f);
        wv[2] = pv.z * mvk / (c1.z * pv.z + 1.f);
        wv[3] = pv.w * mvk / (c1.w * pv.w + 1.f);
      } else {
        float4 c2 = *(const float4*)&col2[bm + m0];
        wv[0] = __expf(pv.x - c1.x) / c2.x;
        wv[1] = __expf(pv.y - c1.y) / c2.y;
        wv[2] = __expf(pv.z - c1.z) / c2.z;
        wv[3] = __expf(pv.w - c1.w) / c2.w;
      }
#pragma unroll
      for (int j = 0; j < 4; j++) {
        unsigned short hh = f2bf(wv[j]);
        sAh[(m0 + j) * PAD + kr] = hh;
        sAl[(m0 + j) * PAD + kr] = f2bf(wv[j] - bf2f(hh));
      }
    }
#pragma unroll
    for (int q = 0; q < 2; q++) {
      int f = q * 256 + tid;
      int row = f >> 2, ch = f & 3;
      size_t gb = (size_t)row * N + k0 + kt + ch * 8;
      int ls = row * PAD + ch * 8;
      *(uint4*)&sBh[ls] = *(const uint4*)&Bthi[gb];
      *(uint4*)&sBl[ls] = *(const uint4*)&Btlo[gb];
    }
    __syncthreads();
    bf16x8 ah[4], al[4], bh[4], bl[4];
#pragma unroll
    for (int t = 0; t < 4; t++) {
      int ar = (wm + t * 16 + l15) * PAD + quad * 8;
      ah[t] = *(const bf16x8*)&sAh[ar];
      al[t] = *(const bf16x8*)&sAl[ar];
      int br = (wn + t * 16 + l15) * PAD + quad * 8;
      bh[t] = *(const bf16x8*)&sBh[br];
      bl[t] = *(const bf16x8*)&sBl[br];
    }
#pragma unroll
    for (int mt = 0; mt < 4; mt++)
#pragma unroll
      for (int nt = 0; nt < 4; nt++) {
        acc[mt][nt] = __builtin_amdgcn_mfma_f32_16x16x32_bf16(ah[mt], bh[nt], acc[mt][nt], 0, 0, 0);
        acc[mt][nt] = __builtin_amdgcn_mfma_f32_16x16x32_bf16(ah[mt], bl[nt], acc[mt][nt], 0, 0, 0);
        acc[mt][nt] = __builtin_amdgcn_mfma_f32_16x16x32_bf16(al[mt], bh[nt], acc[mt][nt], 0, 0, 0);
      }
    __syncthreads();
  }
  float* pp = partial + (size_t)blockIdx.z * C * 128;
#pragma unroll
  for (int mt = 0; mt < 4; mt++)
#pragma unroll
    for (int nt = 0; nt < 4; nt++) {
      int col = wn + nt * 16 + l15;
#pragma unroll
      for (int rg = 0; rg < 4; rg++) {
        int row = bm + wm + mt * 16 + quad * 4 + rg;
        pp[(size_t)row * 128 + col] = acc[mt][nt][rg];
      }
    }
}

// reduce split-K partials (C*H shapes); optional per-row scale; pair emission;
// row-norm / row-valid emission
__global__ __launch_bounds__(256) void k_reduce(
    const float* __restrict__ partial, float* __restrict__ out, int cnt,
    size_t slot, size_t size4, const float* __restrict__ scalem,
    unsigned short* __restrict__ hi, unsigned short* __restrict__ lo,
    float* __restrict__ nrmout, float* __restrict__ validout) {
  size_t idx = (size_t)blockIdx.x * 256 + threadIdx.x;
  if (idx >= size4) return;
  float4 s = {0, 0, 0, 0};
  for (int c = 0; c < cnt; c++) {
    float4 v = *(const float4*)&partial[c * slot + idx * 4];
    s.x += v.x; s.y += v.y; s.z += v.z; s.w += v.w;
  }
  if (scalem) {
    float sc = scalem[idx >> 5];
    s.x *= sc; s.y *= sc; s.z *= sc; s.w *= sc;
  }
  *(float4*)&out[idx * 4] = s;
  if (hi) {
    float vv[4] = {s.x, s.y, s.z, s.w};
    unsigned short h[4], l[4];
#pragma unroll
    for (int c = 0; c < 4; c++) {
      h[c] = f2bf(vv[c]);
      l[c] = f2bf(vv[c] - bf2f(h[c]));
    }
    uint2 ph = {(unsigned)h[0] | ((unsigned)h[1] << 16),
                (unsigned)h[2] | ((unsigned)h[3] << 16)};
    uint2 pl = {(unsigned)l[0] | ((unsigned)l[1] << 16),
                (unsigned)l[2] | ((unsigned)l[3] << 16)};
    *(uint2*)&hi[idx * 4] = ph;
    *(uint2*)&lo[idx * 4] = pl;
  }
  if (nrmout || validout) {
    float rs = s.x + s.y + s.z + s.w;
    float rq = s.x * s.x + s.y * s.y + s.z * s.z + s.w * s.w;
#pragma unroll
    for (int m = 16; m; m >>= 1) { rs += __shfl_xor(rs, m); rq += __shfl_xor(rq, m); }
    if ((threadIdx.x & 31) == 0) {
      if (nrmout) nrmout[idx >> 5] = sqrtf(rq);
      if (validout) validout[idx >> 5] = (rs != 0.f) ? 1.f : 0.f;
    }
  }
}

// ---------------- fused branch-tail kernels (16 rows/block, 256 blocks) ------

#define LOAD_W(Wt)                                                        \
  do {                                                                    \
    _Pragma("unroll") for (int q = 0; q < 16; q++) {                      \
      int f = q * 256 + tid;                                              \
      int wr = f >> 5, wc = (f & 31) * 4;                                 \
      float4 wv = *(const float4*)&(Wt)[(size_t)wr * 128 + wc];           \
      float ww[4] = {wv.x, wv.y, wv.z, wv.w};                             \
      _Pragma("unroll") for (int c = 0; c < 4; c++) {                     \
        unsigned short hh = f2bf(ww[c]);                                  \
        sWh[wr * WP + wc + c] = hh;                                       \
        sWl[wr * WP + wc + c] = f2bf(ww[c] - bf2f(hh));                   \
      }                                                                   \
    }                                                                     \
  } while (0)

// 16-row GEMM: each wave owns a 16x32 quadrant (cn = w*32, nt<2)
#define GEMM16(accv)                                                              \
  do {                                                                            \
    _Pragma("unroll") for (int nt = 0; nt < 2; nt++) accv[nt] = zero;             \
    _Pragma("unroll") for (int kt = 0; kt < 128; kt += 32) {                      \
      bf16x8 ah = *(const bf16x8*)&sAh[l15 * WP + kt + quad * 8];                 \
      bf16x8 al = *(const bf16x8*)&sAl[l15 * WP + kt + quad * 8];                 \
      _Pragma("unroll") for (int nt = 0; nt < 2; nt++) {                          \
        int br = (cn + nt * 16 + l15) * WP + kt + quad * 8;                       \
        bf16x8 bh = *(const bf16x8*)&sWh[br];                                     \
        bf16x8 bl = *(const bf16x8*)&sWl[br];                                     \
        accv[nt] = __builtin_amdgcn_mfma_f32_16x16x32_bf16(ah, bh, accv[nt], 0, 0, 0); \
        accv[nt] = __builtin_amdgcn_mfma_f32_16x16x32_bf16(ah, bl, accv[nt], 0, 0, 0); \
        accv[nt] = __builtin_amdgcn_mfma_f32_16x16x32_bf16(al, bh, accv[nt], 0, 0, 0); \
      }                                                                           \
    }                                                                             \
  } while (0)

// ps tail: ps_pre = sum_z partial; p_shared = lin(ps_pre,W_ps);
// h = x - lin(p_shared,W_psb); out_ps -> all_info; hhat/pairs/diagv from h.
__global__ __launch_bounds__(256) void k_ps_tail(
    const float* __restrict__ partial, int zcnt, const float* __restrict__ x,
    const float* __restrict__ W_ps, const float* __restrict__ b_ps,
    const float* __restrict__ W_psb, const float* __restrict__ b_psb,
    const float* __restrict__ W_psf, const float* __restrict__ b_psf,
    float* __restrict__ hbuf, float* __restrict__ hhat,
    unsigned short* __restrict__ hhi, unsigned short* __restrict__ hlo,
    float* __restrict__ diagv, float* __restrict__ all_info) {
  __shared__ __align__(16) unsigned short sWh[128 * WP];
  __shared__ __align__(16) unsigned short sWl[128 * WP];
  __shared__ __align__(16) unsigned short sAh[16 * WP];
  __shared__ __align__(16) unsigned short sAl[16 * WP];
  __shared__ __align__(16) float sF[16][132];
  int tid = threadIdx.x;
  int bm = blockIdx.x * 16;
  int lane = tid & 63, w = tid >> 6;
  int cn = w * 32;
  int l15 = lane & 15, quad = lane >> 4;
  f32x4 zero = {0.f, 0.f, 0.f, 0.f};
  f32x4 acc[2];

  // stage ps_pre tile (sum of split-K partials) -> pairs
  {
    int row = tid >> 4, c0 = (tid & 15) * 8;
    size_t off0 = (size_t)(bm + row) * 128 + c0;
#pragma unroll
    for (int q = 0; q < 2; q++) {
      float vv[4] = {0.f, 0.f, 0.f, 0.f};
      for (int z = 0; z < zcnt; z++) {
        float4 v = *(const float4*)&partial[(size_t)z * N * H + off0 + q * 4];
        vv[0] += v.x; vv[1] += v.y; vv[2] += v.z; vv[3] += v.w;
      }
#pragma unroll
      for (int c = 0; c < 4; c++) {
        unsigned short hh = f2bf(vv[c]);
        sAh[row * WP + c0 + q * 4 + c] = hh;
        sAl[row * WP + c0 + q * 4 + c] = f2bf(vv[c] - bf2f(hh));
      }
    }
  }
  LOAD_W(W_ps);
  __syncthreads();
  GEMM16(acc);  // p_shared (pre-bias)
  __syncthreads();
#pragma unroll
  for (int nt = 0; nt < 2; nt++) {
    int col = cn + nt * 16 + l15;
    float bv = b_ps[col];
#pragma unroll
    for (int rg = 0; rg < 4; rg++) {
      int row = quad * 4 + rg;
      float v = acc[nt][rg] + bv;
      unsigned short hh = f2bf(v);
      sAh[row * WP + col] = hh;
      sAl[row * WP + col] = f2bf(v - bf2f(hh));
    }
  }
  LOAD_W(W_psb);
  __syncthreads();
  GEMM16(acc);  // p_back (pre-bias)
#pragma unroll
  for (int nt = 0; nt < 2; nt++) {
    int col = cn + nt * 16 + l15;
    float bv = b_psb[col];
#pragma unroll
    for (int rg = 0; rg < 4; rg++) {
      int row = quad * 4 + rg;
      size_t off = (size_t)(bm + row) * 128 + col;
      float hv = x[off] - (acc[nt][rg] + bv);
      hbuf[off] = hv;
      sF[row][col] = hv;
    }
  }
  __syncthreads();
  // hhat substage (reads sF)
  {
    int row = tid >> 4, c0 = (tid & 15) * 8;
    float hv8[8];
    float ssp = 0.f;
#pragma unroll
    for (int q = 0; q < 8; q++) {
      float v = sF[row][c0 + q];
      hv8[q] = v;
      ssp += v * v;
    }
    ssp += __shfl_xor(ssp, 1);
    ssp += __shfl_xor(ssp, 2);
    ssp += __shfl_xor(ssp, 4);
    ssp += __shfl_xor(ssp, 8);
    float ss = ssp;
    float hn = sqrtf(ss);
    float den = hn * hn;
    float dg = (den == 0.f) ? 0.f : ss / den;
    float inv = (ss > 0.f) ? (1.f / hn) : 1.f;
    size_t base = (size_t)(bm + row) * H + c0;
    float va8[8];
    unsigned short hh8[8], ll8[8];
#pragma unroll
    for (int q = 0; q < 8; q++) {
      va8[q] = hv8[q] * inv;
      hh8[q] = f2bf(va8[q]);
      ll8[q] = f2bf(va8[q] - bf2f(hh8[q]));
    }
#pragma unroll
    for (int q4 = 0; q4 < 2; q4++) {
      float4 fv = {va8[q4 * 4], va8[q4 * 4 + 1], va8[q4 * 4 + 2], va8[q4 * 4 + 3]};
      *(float4*)&hhat[base + q4 * 4] = fv;
    }
    uint4 ph = {(unsigned)hh8[0] | ((unsigned)hh8[1] << 16), (unsigned)hh8[2] | ((unsigned)hh8[3] << 16),
                (unsigned)hh8[4] | ((unsigned)hh8[5] << 16), (unsigned)hh8[6] | ((unsigned)hh8[7] << 16)};
    uint4 pl = {(unsigned)ll8[0] | ((unsigned)ll8[1] << 16), (unsigned)ll8[2] | ((unsigned)ll8[3] << 16),
                (unsigned)ll8[4] | ((unsigned)ll8[5] << 16), (unsigned)ll8[6] | ((unsigned)ll8[7] << 16)};
    *(uint4*)&hhi[base] = ph;
    *(uint4*)&hlo[base] = pl;
    if ((tid & 15) == 0) diagv[bm + row] = dg;
  }
  LOAD_W(W_psf);
  __syncthreads();
  GEMM16(acc);  // out_ps (pre-bias)
#pragma unroll
  for (int nt = 0; nt < 2; nt++) {
    int col = cn + nt * 16 + l15;
    float bv = b_psf[col];
#pragma unroll
    for (int rg = 0; rg < 4; rg++) {
      int row = quad * 4 + rg;
      size_t off = (size_t)(bm + row) * 128 + col;
      all_info[off] = lrelu(acc[nt][rg] + bv);
    }
  }
}

// hs tail: hs_pre = (sum_z partialU)/lsum; h_shared = lin(hs_pre,W_hs);
// all = all_info + lrelu(lin(h_shared,W_hsf)); indiv = h - lin(h_shared,W_hsb);
// all += lrelu(lin(indiv,W_in)); out = all @ W_out + b.
__global__ __launch_bounds__(256) void k_hs_tail(
    const float* __restrict__ partial, const float* __restrict__ plsum, int zcnt,
    const float* __restrict__ hbuf, const float* __restrict__ all_info,
    const float* __restrict__ W_hs, const float* __restrict__ b_hs,
    const float* __restrict__ W_hsf, const float* __restrict__ b_hsf,
    const float* __restrict__ W_hsb, const float* __restrict__ b_hsb,
    const float* __restrict__ W_in, const float* __restrict__ b_in,
    const float* __restrict__ W_out, const float* __restrict__ b_out,
    float* __restrict__ out) {
  __shared__ __align__(16) unsigned short sWh[128 * WP];
  __shared__ __align__(16) unsigned short sWl[128 * WP];
  __shared__ __align__(16) unsigned short sAh[16 * WP];
  __shared__ __align__(16) unsigned short sAl[16 * WP];
  __shared__ __align__(16) float sF[16][132];
  int tid = threadIdx.x;
  int bm = blockIdx.x * 16;
  int lane = tid & 63, w = tid >> 6;
  int cn = w * 32;
  int l15 = lane & 15, quad = lane >> 4;
  f32x4 zero = {0.f, 0.f, 0.f, 0.f};
  f32x4 acc[2];
  float allv[2][4];

  // stage hs_pre tile: sum of split-KV partials / total lsum
  {
    int row = tid >> 4, c0 = (tid & 15) * 8;
    float d = 0.f;
    for (int z = 0; z < zcnt; z++) d += plsum[(size_t)z * N + bm + row];
    float sc = 1.f / d;
    size_t off0 = (size_t)(bm + row) * 128 + c0;
#pragma unroll
    for (int q = 0; q < 2; q++) {
      float vv[4] = {0.f, 0.f, 0.f, 0.f};
      for (int z = 0; z < zcnt; z++) {
        float4 v = *(const float4*)&partial[(size_t)z * N * H + off0 + q * 4];
        vv[0] += v.x; vv[1] += v.y; vv[2] += v.z; vv[3] += v.w;
      }
#pragma unroll
      for (int c = 0; c < 4; c++) {
        float val = vv[c] * sc;
        unsigned short hh = f2bf(val);
        sAh[row * WP + c0 + q * 4 + c] = hh;
        sAl[row * WP + c0 + q * 4 + c] = f2bf(val - bf2f(hh));
      }
    }
  }
  LOAD_W(W_hs);
  __syncthreads();
  GEMM16(acc);  // h_shared (pre-bias)
  __syncthreads();
#pragma unroll
  for (int nt = 0; nt < 2; nt++) {
    int col = cn + nt * 16 + l15;
    float bv = b_hs[col];
#pragma unroll
    for (int rg = 0; rg < 4; rg++) {
      int row = quad * 4 + rg;
      float v = acc[nt][rg] + bv;
      unsigned short hh = f2bf(v);
      sAh[row * WP + col] = hh;
      sAl[row * WP + col] = f2bf(v - bf2f(hh));
    }
  }
  LOAD_W(W_hsf);
  __syncthreads();
  GEMM16(acc);  // out_hs (pre-bias)
#pragma unroll
  for (int nt = 0; nt < 2; nt++) {
    int col = cn + nt * 16 + l15;
    float bv = b_hsf[col];
#pragma unroll
    for (int rg = 0; rg < 4; rg++) {
      int row = quad * 4 + rg;
      size_t off = (size_t)(bm + row) * 128 + col;
      allv[nt][rg] = all_info[off] + lrelu(acc[nt][rg] + bv);
    }
  }
  __syncthreads();
  LOAD_W(W_hsb);
  __syncthreads();
  GEMM16(acc);  // h_back (pre-bias)
  float iv[2][4];
#pragma unroll
  for (int nt = 0; nt < 2; nt++) {
    int col = cn + nt * 16 + l15;
    float bv = b_hsb[col];
#pragma unroll
    for (int rg = 0; rg < 4; rg++) {
      int row = quad * 4 + rg;
      size_t off = (size_t)(bm + row) * 128 + col;
      iv[nt][rg] = hbuf[off] - (acc[nt][rg] + bv);
    }
  }
  __syncthreads();
#pragma unroll
  for (int nt = 0; nt < 2; nt++) {
    int col = cn + nt * 16 + l15;
#pragma unroll
    for (int rg = 0; rg < 4; rg++) {
      int row = quad * 4 + rg;
      unsigned short hh = f2bf(iv[nt][rg]);
      sAh[row * WP + col] = hh;
      sAl[row * WP + col] = f2bf(iv[nt][rg] - bf2f(hh));
    }
  }
  LOAD_W(W_in);
  __syncthreads();
  GEMM16(acc);  // out_indi (pre-bias)
#pragma unroll
  for (int nt = 0; nt < 2; nt++) {
    int col = cn + nt * 16 + l15;
    float bv = b_in[col];
#pragma unroll
    for (int rg = 0; rg < 4; rg++) {
      int row = quad * 4 + rg;
      allv[nt][rg] += lrelu(acc[nt][rg] + bv);
      sF[row][col] = allv[nt][rg];
    }
  }
  __syncthreads();
  {
    int row = tid >> 4, c0 = (tid & 15) * 8;
    float s = 0.f;
#pragma unroll
    for (int q = 0; q < 8; q++) s += sF[row][c0 + q] * W_out[c0 + q];
    s += __shfl_xor(s, 1);
    s += __shfl_xor(s, 2);
    s += __shfl_xor(s, 4);
    s += __shfl_xor(s, 8);
    if ((tid & 15) == 0) out[bm + row] = s + b_out[0];
  }
}

// ---------------- launch ----------------

extern "C" void kernel_launch(void* const* d_in, const int* in_sizes, int n_in,
                              void* d_out, int out_size, void* d_ws, size_t ws_size,
                              hipStream_t stream) {
  (void)in_sizes; (void)n_in; (void)out_size; (void)ws_size;
  const float* x   = (const float*)d_in[0];
  const float* cm  = (const float*)d_in[1];
  const float* mv  = (const float*)d_in[2];
  const float* W_ps = (const float*)d_in[3],  *b_ps = (const float*)d_in[4];
  const float* W_psf = (const float*)d_in[5], *b_psf = (const float*)d_in[6];
  const float* W_psb = (const float*)d_in[7], *b_psb = (const float*)d_in[8];
  const float* W_hs = (const float*)d_in[9],  *b_hs = (const float*)d_in[10];
  const float* W_hsf = (const float*)d_in[11], *b_hsf = (const float*)d_in[12];
  const float* W_hsb = (const float*)d_in[13], *b_hsb = (const float*)d_in[14];
  const float* W_in = (const float*)d_in[15], *b_in = (const float*)d_in[16];
  const float* W_out = (const float*)d_in[17], *b_out = (const float*)d_in[18];
  float* out = (float*)d_out;

  float* W = (float*)d_ws;
  size_t o = 0;
  auto alloc = [&](size_t n) { float* p = W + o; o += n; return p; };
  float* colsum_c = alloc(C);
  float* colmax   = alloc(C);
  float* colsumexp= alloc(C);
  float* valid1   = alloc(C);
  float* hnorm_ps = alloc(C);
  float* xnorm    = alloc(N);
  float* diagv    = alloc(N);
  float* colsum_m = alloc(N);
  float* valid2f  = alloc(N);
  float* plsum    = alloc((size_t)8 * N);
  float* hidden1  = alloc((size_t)C * H);
  float* hidden_ps= alloc((size_t)C * H);
  float* scores   = alloc((size_t)N * C);
  float* all_info = alloc((size_t)N * H);
  float* hbuf     = alloc((size_t)N * H);   // h
  float* hhat     = alloc((size_t)N * H);
  float* hidden2  = alloc((size_t)N * H);
  unsigned short* xhi    = (unsigned short*)alloc((size_t)N * H / 2);
  unsigned short* xlo    = (unsigned short*)alloc((size_t)N * H / 2);
  unsigned short* hhathi = (unsigned short*)alloc((size_t)N * H / 2);
  unsigned short* hhatlo = (unsigned short*)alloc((size_t)N * H / 2);
  unsigned short* h2hi   = (unsigned short*)alloc((size_t)N * H / 2);
  unsigned short* h2lo   = (unsigned short*)alloc((size_t)N * H / 2);
  unsigned short* h1hi   = (unsigned short*)alloc((size_t)C * H / 2);
  unsigned short* h1lo   = (unsigned short*)alloc((size_t)C * H / 2);
  unsigned short* hpshi  = (unsigned short*)alloc((size_t)C * H / 2);
  unsigned short* hpslo  = (unsigned short*)alloc((size_t)C * H / 2);
  unsigned short* cshi   = (unsigned short*)alloc((size_t)N * C / 2);
  unsigned short* cslo   = (unsigned short*)alloc((size_t)N * C / 2);
  unsigned short* hpst_hi= (unsigned short*)alloc((size_t)H * C / 2);
  unsigned short* hpst_lo= (unsigned short*)alloc((size_t)H * C / 2);
  unsigned short* h2t_hi = (unsigned short*)alloc((size_t)H * N / 2);
  unsigned short* h2t_lo = (unsigned short*)alloc((size_t)H * N / 2);
  unsigned short* xt_hi  = (unsigned short*)alloc((size_t)H * N / 2);
  unsigned short* xt_lo  = (unsigned short*)alloc((size_t)H * N / 2);
  float2* cand    = (float2*)alloc((size_t)N * 128 * 5 * 2);
  float* partial  = W + o;
  const int Z = 8;        // flash split-KV (8*N*128 fp32)
  const int ZG = 64;      // genA split-K (64*C*128 fp32); same region
  const int ZK = 8;       // cs-GEMM split-K (8*N*128 fp32); same region

  dim3 blk(256);
  // --- ps branch ---
  k_xprep<<<dim3(N / 32), blk, 0, stream>>>(x, xhi, xlo, xnorm, xt_hi, xt_lo,
                                            hidden2, colsum_c, colsum_m);
  k_colsum_s2c<<<dim3(C / 64, 16), dim3(64), 0, stream>>>(cm, mv, colsum_c);
  k_mfma_genA<1><<<dim3(1, C / 128, ZG), blk, 0, stream>>>(
      cm, mv, colsum_c, nullptr, xt_hi, xt_lo, partial, N / ZG);
  k_reduce<<<dim3(C * H / 4 / 256), blk, 0, stream>>>(
      partial, hidden1, ZG, (size_t)C * H, (size_t)C * H / 4, nullptr,
      h1hi, h1lo, nullptr, valid1);
  k_mfma_nt<<<dim3(C / 128, N / 64), blk, 0, stream>>>(
      xhi, xlo, h1hi, h1lo, scores, C);
  k_colstats<<<dim3(C), blk, 0, stream>>>(scores, colmax, colsumexp);
  k_mfma_genA<2><<<dim3(1, C / 128, ZG), blk, 0, stream>>>(
      scores, nullptr, colmax, colsumexp, xt_hi, xt_lo, partial, N / ZG);
  k_reduce<<<dim3(C * H / 4 / 256), blk, 0, stream>>>(
      partial, hidden_ps, ZG, (size_t)C * H, (size_t)C * H / 4, valid1,
      hpshi, hpslo, hnorm_ps, nullptr);
  k_mfma_nt<<<dim3(C / 128, N / 64), blk, 0, stream>>>(
      xhi, xlo, hpshi, hpslo, scores, C);
  k_cs_softmax<<<dim3(N), blk, 0, stream>>>(scores, xnorm, hnorm_ps, valid1,
                                            cshi, cslo);
  k_tsplit<<<dim3(C / 32), blk, 0, stream>>>(hidden_ps, hpst_hi, hpst_lo, C);
  k_mfma_kn<<<dim3(1, N / 128, ZK), blk, 0, stream>>>(
      cshi, cslo, hpst_hi, hpst_lo, partial, C, C / ZK);
  k_ps_tail<<<dim3(N / 16), blk, 0, stream>>>(
      partial, ZK, x, W_ps, b_ps, W_psb, b_psb, W_psf, b_psf,
      hbuf, hhat, hhathi, hhatlo, diagv, all_info);
  // --- hs branch ---
  k_snt<<<dim3(N / 128, N / 128), dim3(512), 0, stream>>>(
      hhathi, hhatlo, cand);
  k_rowtop2s<<<dim3(N / 4), blk, 0, stream>>>(cand, hhat, hbuf, hidden2,
                                              colsum_m);
  k_fin2t<<<dim3(N / 32), blk, 0, stream>>>(hbuf, diagv, colsum_m, hidden2,
                                            h2hi, h2lo, valid2f, h2t_hi, h2t_lo);
  k_flash<<<dim3(Z, N / 128), dim3(512), 0, stream>>>(
      hhathi, hhatlo, h2hi, h2lo, h2t_hi, h2t_lo, valid2f, partial, plsum,
      N / Z);
  k_hs_tail<<<dim3(N / 16), blk, 0, stream>>>(
      partial, plsum, Z, hbuf, all_info, W_hs, b_hs, W_hsf, b_hsf, W_hsb, b_hsb,
      W_in, b_in, W_out, b_out, out);
}

// Round 13
// 346.211 us; speedup vs baseline: 1.2664x; 1.0120x over previous
//
#include <hip/hip_runtime.h>
#include <hip/hip_fp16.h>
#include <math.h>

#define N 4096
#define C 512
#define H 128
#define PAD 40  // ushort row pitch for 32-col MFMA LDS staging tiles
#define WP 136  // ushort row pitch for full-K (128 col) LDS tiles
#define FWP 136 // ushort row pitch for flash Q/P tiles
#define SP 136  // ushort row pitch for S-tile scan buffer

typedef __attribute__((ext_vector_type(8))) short bf16x8;
typedef __attribute__((ext_vector_type(4))) float f32x4;

// ---------------- helpers ----------------

__device__ inline float wave_reduce_sum(float v) {
#pragma unroll
  for (int m = 32; m; m >>= 1) v += __shfl_xor(v, m);
  return v;
}

__device__ inline float lrelu(float v) { return v > 0.f ? v : 0.01f * v; }

__device__ inline bool better(float v, int j, float w, int k) {
  return (v > w) || (v == w && j < k);
}

__device__ inline void top3_ins(float v, int j, float& v0, int& j0,
                                float& v1, int& j1, float& v2, int& j2) {
  if (better(v, j, v0, j0)) { v2 = v1; j2 = j1; v1 = v0; j1 = j0; v0 = v; j0 = j; }
  else if (better(v, j, v1, j1)) { v2 = v1; j2 = j1; v1 = v; j1 = j; }
  else if (better(v, j, v2, j2)) { v2 = v; j2 = j; }
}

__device__ inline void ins5(float s, int j, float v[5], int jx[5]) {
  if (!better(s, j, v[4], jx[4])) return;
  if (better(s, j, v[0], jx[0])) {
    v[4]=v[3]; jx[4]=jx[3]; v[3]=v[2]; jx[3]=jx[2]; v[2]=v[1]; jx[2]=jx[1];
    v[1]=v[0]; jx[1]=jx[0]; v[0]=s; jx[0]=j;
  } else if (better(s, j, v[1], jx[1])) {
    v[4]=v[3]; jx[4]=jx[3]; v[3]=v[2]; jx[3]=jx[2]; v[2]=v[1]; jx[2]=jx[1];
    v[1]=s; jx[1]=j;
  } else if (better(s, j, v[2], jx[2])) {
    v[4]=v[3]; jx[4]=jx[3]; v[3]=v[2]; jx[3]=jx[2]; v[2]=s; jx[2]=j;
  } else if (better(s, j, v[3], jx[3])) {
    v[4]=v[3]; jx[4]=jx[3]; v[3]=s; jx[3]=j;
  } else {
    v[4]=s; jx[4]=j;
  }
}

// top-5 on packed u32 keys (larger = better; col tie-break embedded in key)
__device__ inline void ins5u(unsigned s, unsigned v[5]) {
  if (s <= v[4]) return;
  if (s > v[0]) { v[4]=v[3]; v[3]=v[2]; v[2]=v[1]; v[1]=v[0]; v[0]=s; }
  else if (s > v[1]) { v[4]=v[3]; v[3]=v[2]; v[2]=v[1]; v[1]=s; }
  else if (s > v[2]) { v[4]=v[3]; v[3]=v[2]; v[2]=s; }
  else if (s > v[3]) { v[4]=v[3]; v[3]=s; }
  else { v[4]=s; }
}

__device__ inline unsigned short f2bf(float f) {
  unsigned u = __float_as_uint(f);
  unsigned r = u + 0x7fffu + ((u >> 16) & 1u);
  return (unsigned short)(r >> 16);
}
__device__ inline float bf2f(unsigned short h) {
  return __uint_as_float(((unsigned)h) << 16);
}

// ---- x prep: linear pairs + xnorm + transposed pairs + workspace zeroing ----
__global__ __launch_bounds__(256) void k_xprep(
    const float* __restrict__ in, unsigned short* __restrict__ hi,
    unsigned short* __restrict__ lo, float* __restrict__ nrm,
    unsigned short* __restrict__ thi, unsigned short* __restrict__ tlo,
    float* __restrict__ hidden2, float* __restrict__ colsum_c,
    float* __restrict__ colsum_m) {
  __shared__ float tile[32][132];
  int r0 = blockIdx.x * 32, tid = threadIdx.x;
  float4 zf = {0.f, 0.f, 0.f, 0.f};
#pragma unroll
  for (int q = 0; q < 4; q++) {
    size_t zi = ((size_t)blockIdx.x * 1024 + q * 256 + tid) * 4;
    *(float4*)&hidden2[zi] = zf;
  }
  if (blockIdx.x == 0 && tid < 128) *(float4*)&colsum_c[tid * 4] = zf;
  if (blockIdx.x == 1) {
#pragma unroll
    for (int q = 0; q < 4; q++) *(float4*)&colsum_m[(q * 256 + tid) * 4] = zf;
  }
#pragma unroll
  for (int q = 0; q < 4; q++) {
    int f = q * 256 + tid;
    int row = f >> 5, ch = f & 31;
    size_t gi = (size_t)(r0 + row) * 128 + ch * 4;
    float4 v = *(const float4*)&in[gi];
    *(float4*)&tile[row][ch * 4] = v;
    float vv[4] = {v.x, v.y, v.z, v.w};
    unsigned short hq[4], lq[4];
    float ss = 0.f;
#pragma unroll
    for (int c = 0; c < 4; c++) {
      ss += vv[c] * vv[c];
      hq[c] = f2bf(vv[c]);
      lq[c] = f2bf(vv[c] - bf2f(hq[c]));
    }
    uint2 ph = {(unsigned)hq[0] | ((unsigned)hq[1] << 16),
                (unsigned)hq[2] | ((unsigned)hq[3] << 16)};
    uint2 pl = {(unsigned)lq[0] | ((unsigned)lq[1] << 16),
                (unsigned)lq[2] | ((unsigned)lq[3] << 16)};
    *(uint2*)&hi[gi] = ph;
    *(uint2*)&lo[gi] = pl;
#pragma unroll
    for (int m = 16; m; m >>= 1) ss += __shfl_xor(ss, m);
    if ((tid & 31) == 0) nrm[r0 + row] = sqrtf(ss);
  }
  __syncthreads();
  int c = tid & 127, half = tid >> 7;
  unsigned short hh[16], ll[16];
#pragma unroll
  for (int rr = 0; rr < 16; rr++) {
    float v = tile[half * 16 + rr][c];
    hh[rr] = f2bf(v);
    ll[rr] = f2bf(v - bf2f(hh[rr]));
  }
  size_t off = (size_t)c * N + r0 + half * 16;
  uint4 ph0 = {(unsigned)hh[0] | ((unsigned)hh[1] << 16), (unsigned)hh[2] | ((unsigned)hh[3] << 16),
               (unsigned)hh[4] | ((unsigned)hh[5] << 16), (unsigned)hh[6] | ((unsigned)hh[7] << 16)};
  uint4 ph1 = {(unsigned)hh[8] | ((unsigned)hh[9] << 16), (unsigned)hh[10] | ((unsigned)hh[11] << 16),
               (unsigned)hh[12] | ((unsigned)hh[13] << 16), (unsigned)hh[14] | ((unsigned)hh[15] << 16)};
  uint4 pl0 = {(unsigned)ll[0] | ((unsigned)ll[1] << 16), (unsigned)ll[2] | ((unsigned)ll[3] << 16),
               (unsigned)ll[4] | ((unsigned)ll[5] << 16), (unsigned)ll[6] | ((unsigned)ll[7] << 16)};
  uint4 pl1 = {(unsigned)ll[8] | ((unsigned)ll[9] << 16), (unsigned)ll[10] | ((unsigned)ll[11] << 16),
               (unsigned)ll[12] | ((unsigned)ll[13] << 16), (unsigned)ll[14] | ((unsigned)ll[15] << 16)};
  *(uint4*)&thi[off] = ph0; *(uint4*)&thi[off + 8] = ph1;
  *(uint4*)&tlo[off] = pl0; *(uint4*)&tlo[off + 8] = pl1;
}

// transpose + split: in [R,128] fp32 -> thi/tlo [128,R] ushort
__global__ __launch_bounds__(256) void k_tsplit(const float* __restrict__ in,
                                                unsigned short* __restrict__ thi,
                                                unsigned short* __restrict__ tlo,
                                                int R) {
  __shared__ float tile[32][132];
  int r0 = blockIdx.x * 32, tid = threadIdx.x;
#pragma unroll
  for (int q = 0; q < 4; q++) {
    int f = q * 256 + tid;
    int row = f >> 5, ch = f & 31;
    *(float4*)&tile[row][ch * 4] = *(const float4*)&in[(size_t)(r0 + row) * 128 + ch * 4];
  }
  __syncthreads();
  int c = tid & 127, half = tid >> 7;
  unsigned short hh[16], ll[16];
#pragma unroll
  for (int rr = 0; rr < 16; rr++) {
    float v = tile[half * 16 + rr][c];
    hh[rr] = f2bf(v);
    ll[rr] = f2bf(v - bf2f(hh[rr]));
  }
  size_t off = (size_t)c * R + r0 + half * 16;
  uint4 ph0 = {(unsigned)hh[0] | ((unsigned)hh[1] << 16), (unsigned)hh[2] | ((unsigned)hh[3] << 16),
               (unsigned)hh[4] | ((unsigned)hh[5] << 16), (unsigned)hh[6] | ((unsigned)hh[7] << 16)};
  uint4 ph1 = {(unsigned)hh[8] | ((unsigned)hh[9] << 16), (unsigned)hh[10] | ((unsigned)hh[11] << 16),
               (unsigned)hh[12] | ((unsigned)hh[13] << 16), (unsigned)hh[14] | ((unsigned)hh[15] << 16)};
  uint4 pl0 = {(unsigned)ll[0] | ((unsigned)ll[1] << 16), (unsigned)ll[2] | ((unsigned)ll[3] << 16),
               (unsigned)ll[4] | ((unsigned)ll[5] << 16), (unsigned)ll[6] | ((unsigned)ll[7] << 16)};
  uint4 pl1 = {(unsigned)ll[8] | ((unsigned)ll[9] << 16), (unsigned)ll[10] | ((unsigned)ll[11] << 16),
               (unsigned)ll[12] | ((unsigned)ll[13] << 16), (unsigned)ll[14] | ((unsigned)ll[15] << 16)};
  *(uint4*)&thi[off] = ph0; *(uint4*)&thi[off + 8] = ph1;
  *(uint4*)&tlo[off] = pl0; *(uint4*)&tlo[off + 8] = pl1;
}

// ---------------- small kernels ----------------

__global__ __launch_bounds__(64) void k_colsum_s2c(
    const float* __restrict__ cm, const float* __restrict__ mv,
    float* __restrict__ colsum_c) {
  int c = blockIdx.x * 64 + threadIdx.x;
  int i0 = blockIdx.y * 256;
  float acc = 0.f;
  for (int i = i0; i < i0 + 256; i++) acc += cm[(size_t)i * C + c] * mv[i];
  atomicAdd(&colsum_c[c], acc);
}

__global__ __launch_bounds__(256) void k_colstats(const float* __restrict__ sc,
                                                  float* __restrict__ colmax,
                                                  float* __restrict__ colsum) {
  __shared__ float red[256];
  int c = blockIdx.x, t = threadIdx.x;
  float v[16];
  float m = -3e38f;
#pragma unroll
  for (int q = 0; q < 16; q++) {
    v[q] = sc[(size_t)(q * 256 + t) * C + c];
    m = fmaxf(m, v[q]);
  }
  red[t] = m; __syncthreads();
  for (int s = 128; s; s >>= 1) { if (t < s) red[t] = fmaxf(red[t], red[t + s]); __syncthreads(); }
  m = red[0]; __syncthreads();
  float sum = 0.f;
#pragma unroll
  for (int q = 0; q < 16; q++) sum += __expf(v[q] - m);
  red[t] = sum; __syncthreads();
  for (int s = 128; s; s >>= 1) { if (t < s) red[t] += red[t + s]; __syncthreads(); }
  if (t == 0) { colmax[c] = m; colsum[c] = red[0]; }
}

// row softmax of cos-sim -> bf16 hi/lo pairs
__global__ __launch_bounds__(256) void k_cs_softmax(
    const float* __restrict__ sc, const float* __restrict__ xnorm,
    const float* __restrict__ hnorm, const float* __restrict__ valid1,
    unsigned short* __restrict__ cshi, unsigned short* __restrict__ cslo) {
  __shared__ float red[256];
  int i = blockIdx.x, t = threadIdx.x;
  float xn = xnorm[i];
  float r0 = sc[(size_t)i * C + t], r1 = sc[(size_t)i * C + 256 + t];
  float d0 = xn * hnorm[t], d1 = xn * hnorm[256 + t];
  float c0 = r0 / (d0 == 0.f ? 1.f : d0);
  float c1 = r1 / (d1 == 0.f ? 1.f : d1);
  float s0 = (valid1[t] != 0.f) ? c0 : -3e38f;
  float s1 = (valid1[256 + t] != 0.f) ? c1 : -3e38f;
  red[t] = fmaxf(s0, s1); __syncthreads();
  for (int s = 128; s; s >>= 1) { if (t < s) red[t] = fmaxf(red[t], red[t + s]); __syncthreads(); }
  float m = red[0]; __syncthreads();
  float p0 = (s0 > -1e37f) ? __expf(s0 - m) : 0.f;
  float p1 = (s1 > -1e37f) ? __expf(s1 - m) : 0.f;
  red[t] = p0 + p1; __syncthreads();
  for (int s = 128; s; s >>= 1) { if (t < s) red[t] += red[t + s]; __syncthreads(); }
  float inv = 1.f / red[0];
  float a = p0 * inv, b = p1 * inv;
  unsigned short ha = f2bf(a), hb = f2bf(b);
  cshi[(size_t)i * C + t] = ha;
  cslo[(size_t)i * C + t] = f2bf(a - bf2f(ha));
  cshi[(size_t)i * C + 256 + t] = hb;
  cslo[(size_t)i * C + 256 + t] = f2bf(b - bf2f(hb));
}

// finalize hidden2 (32 rows/block) + h2hat pairs + valid2f + transposed pairs
__global__ __launch_bounds__(256) void k_fin2t(
    const float* __restrict__ h, const float* __restrict__ diagv,
    const float* __restrict__ colsum_m, float* __restrict__ hidden2,
    unsigned short* __restrict__ h2hi, unsigned short* __restrict__ h2lo,
    float* __restrict__ valid2f, unsigned short* __restrict__ thi,
    unsigned short* __restrict__ tlo) {
  __shared__ float tile[32][132];
  int j0 = blockIdx.x * 32, tid = threadIdx.x;
  int row = tid >> 3, c0 = (tid & 7) * 16;
  int j = j0 + row;
  float add = (colsum_m[j] != 0.f) ? diagv[j] : 0.f;
  float a16[16];
  float s = 0.f, ss = 0.f;
#pragma unroll
  for (int q = 0; q < 16; q++) {
    float a = hidden2[(size_t)j * H + c0 + q] + add * h[(size_t)j * H + c0 + q];
    a16[q] = a;
    s += a; ss += a * a;
  }
#pragma unroll
  for (int m = 4; m; m >>= 1) { s += __shfl_xor(s, m); ss += __shfl_xor(ss, m); }
  bool valid = (s != 0.f);
  float inv = (valid && ss > 0.f) ? (1.f / sqrtf(ss)) : 1.f;
  size_t base = (size_t)j * H + c0;
  unsigned short hh16[16], ll16[16];
#pragma unroll
  for (int q = 0; q < 16; q++) {
    a16[q] = valid ? a16[q] : 0.f;
    float va = a16[q] * inv;
    hh16[q] = f2bf(va);
    ll16[q] = f2bf(va - bf2f(hh16[q]));
    tile[row][c0 + q] = a16[q];
  }
#pragma unroll
  for (int q4 = 0; q4 < 4; q4++) {
    float4 fv = {a16[q4 * 4], a16[q4 * 4 + 1], a16[q4 * 4 + 2], a16[q4 * 4 + 3]};
    *(float4*)&hidden2[base + q4 * 4] = fv;
  }
  uint4 ph0 = {(unsigned)hh16[0] | ((unsigned)hh16[1] << 16), (unsigned)hh16[2] | ((unsigned)hh16[3] << 16),
               (unsigned)hh16[4] | ((unsigned)hh16[5] << 16), (unsigned)hh16[6] | ((unsigned)hh16[7] << 16)};
  uint4 ph1 = {(unsigned)hh16[8] | ((unsigned)hh16[9] << 16), (unsigned)hh16[10] | ((unsigned)hh16[11] << 16),
               (unsigned)hh16[12] | ((unsigned)hh16[13] << 16), (unsigned)hh16[14] | ((unsigned)hh16[15] << 16)};
  uint4 pl0 = {(unsigned)ll16[0] | ((unsigned)ll16[1] << 16), (unsigned)ll16[2] | ((unsigned)ll16[3] << 16),
               (unsigned)ll16[4] | ((unsigned)ll16[5] << 16), (unsigned)ll16[6] | ((unsigned)ll16[7] << 16)};
  uint4 pl1 = {(unsigned)ll16[8] | ((unsigned)ll16[9] << 16), (unsigned)ll16[10] | ((unsigned)ll16[11] << 16),
               (unsigned)ll16[12] | ((unsigned)ll16[13] << 16), (unsigned)ll16[14] | ((unsigned)ll16[15] << 16)};
  *(uint4*)&h2hi[base] = ph0; *(uint4*)&h2hi[base + 8] = ph1;
  *(uint4*)&h2lo[base] = pl0; *(uint4*)&h2lo[base + 8] = pl1;
  if ((tid & 7) == 0) valid2f[j] = valid ? 1.f : 0.f;
  __syncthreads();
  int c = tid & 127, half = tid >> 7;
  unsigned short th[16], tl[16];
#pragma unroll
  for (int rr = 0; rr < 16; rr++) {
    float v = tile[half * 16 + rr][c];
    th[rr] = f2bf(v);
    tl[rr] = f2bf(v - bf2f(th[rr]));
  }
  size_t off = (size_t)c * N + j0 + half * 16;
  uint4 tp0 = {(unsigned)th[0] | ((unsigned)th[1] << 16), (unsigned)th[2] | ((unsigned)th[3] << 16),
               (unsigned)th[4] | ((unsigned)th[5] << 16), (unsigned)th[6] | ((unsigned)th[7] << 16)};
  uint4 tp1 = {(unsigned)th[8] | ((unsigned)th[9] << 16), (unsigned)th[10] | ((unsigned)th[11] << 16),
               (unsigned)th[12] | ((unsigned)th[13] << 16), (unsigned)th[14] | ((unsigned)th[15] << 16)};
  uint4 tq0 = {(unsigned)tl[0] | ((unsigned)tl[1] << 16), (unsigned)tl[2] | ((unsigned)tl[3] << 16),
               (unsigned)tl[4] | ((unsigned)tl[5] << 16), (unsigned)tl[6] | ((unsigned)tl[7] << 16)};
  uint4 tq1 = {(unsigned)tl[8] | ((unsigned)tl[9] << 16), (unsigned)tl[10] | ((unsigned)tl[11] << 16),
               (unsigned)tl[12] | ((unsigned)tl[13] << 16), (unsigned)tl[14] | ((unsigned)tl[15] << 16)};
  *(uint4*)&thi[off] = tp0; *(uint4*)&thi[off + 8] = tp1;
  *(uint4*)&tlo[off] = tq0; *(uint4*)&tlo[off + 8] = tq1;
}

// ---------------- bf16x3 MFMA NT GEMM: A[64,128] @ B[128,128]^T, fp32 out ----
__global__ __launch_bounds__(256) void k_mfma_nt(
    const unsigned short* __restrict__ Ahi, const unsigned short* __restrict__ Alo,
    const unsigned short* __restrict__ Bhi, const unsigned short* __restrict__ Blo,
    float* __restrict__ out, int Nn) {
  __shared__ __align__(16) unsigned short sAh[64 * PAD];
  __shared__ __align__(16) unsigned short sAl[64 * PAD];
  __shared__ __align__(16) unsigned short sBh[128 * PAD];
  __shared__ __align__(16) unsigned short sBl[128 * PAD];
  int tid = threadIdx.x;
  int bm = blockIdx.y * 64, bn = blockIdx.x * 128;
  int lane = tid & 63, w = tid >> 6;
  int wm = (w & 1) * 32, wn = (w >> 1) * 64;
  int l15 = lane & 15, quad = lane >> 4;
  f32x4 zero = {0.f, 0.f, 0.f, 0.f};
  f32x4 acc[2][4];
#pragma unroll
  for (int mt = 0; mt < 2; mt++)
#pragma unroll
    for (int nt = 0; nt < 4; nt++) acc[mt][nt] = zero;

  for (int kt = 0; kt < 128; kt += 32) {
    {
      int row = tid >> 2, ch = tid & 3;
      size_t ga = (size_t)(bm + row) * 128 + kt + ch * 8;
      int ls = row * PAD + ch * 8;
      *(uint4*)&sAh[ls] = *(const uint4*)&Ahi[ga];
      *(uint4*)&sAl[ls] = *(const uint4*)&Alo[ga];
    }
#pragma unroll
    for (int q = 0; q < 2; q++) {
      int f = q * 256 + tid;
      int row = f >> 2, ch = f & 3;
      size_t gb = (size_t)(bn + row) * 128 + kt + ch * 8;
      int ls = row * PAD + ch * 8;
      *(uint4*)&sBh[ls] = *(const uint4*)&Bhi[gb];
      *(uint4*)&sBl[ls] = *(const uint4*)&Blo[gb];
    }
    __syncthreads();
    bf16x8 ah[2], al[2], bh[4], bl[4];
#pragma unroll
    for (int t = 0; t < 2; t++) {
      int ar = (wm + t * 16 + l15) * PAD + quad * 8;
      ah[t] = *(const bf16x8*)&sAh[ar];
      al[t] = *(const bf16x8*)&sAl[ar];
    }
#pragma unroll
    for (int t = 0; t < 4; t++) {
      int br = (wn + t * 16 + l15) * PAD + quad * 8;
      bh[t] = *(const bf16x8*)&sBh[br];
      bl[t] = *(const bf16x8*)&sBl[br];
    }
#pragma unroll
    for (int mt = 0; mt < 2; mt++)
#pragma unroll
      for (int nt = 0; nt < 4; nt++) {
        acc[mt][nt] = __builtin_amdgcn_mfma_f32_16x16x32_bf16(ah[mt], bh[nt], acc[mt][nt], 0, 0, 0);
        acc[mt][nt] = __builtin_amdgcn_mfma_f32_16x16x32_bf16(ah[mt], bl[nt], acc[mt][nt], 0, 0, 0);
        acc[mt][nt] = __builtin_amdgcn_mfma_f32_16x16x32_bf16(al[mt], bh[nt], acc[mt][nt], 0, 0, 0);
      }
    __syncthreads();
  }
#pragma unroll
  for (int mt = 0; mt < 2; mt++) {
#pragma unroll
    for (int nt = 0; nt < 4; nt++) {
      int col = bn + wn + nt * 16 + l15;
#pragma unroll
      for (int rg = 0; rg < 4; rg++) {
        int row = bm + wm + mt * 16 + quad * 4 + rg;
        out[(size_t)row * Nn + col] = acc[mt][nt][rg];
      }
    }
  }
}

// ---------------- S = hhat@hhat^T + fused quarter-row top-5 screen -----------
// S dumped to LDS as SORTABLE fp16 bits (monotone u16 transform); scan builds
// packed keys (val<<5 | 31-localcol) and selects top-5 with pure u32 compares.
__global__ __launch_bounds__(512) void k_snt(
    const unsigned short* __restrict__ Ahi, const unsigned short* __restrict__ Alo,
    float2* __restrict__ cand) {
  __shared__ __align__(16) unsigned short sAh[128 * PAD];
  __shared__ __align__(16) unsigned short sAl[128 * PAD];
  __shared__ __align__(16) unsigned short sBh[128 * PAD];
  __shared__ __align__(16) unsigned short sBl[128 * PAD];
  __shared__ __align__(16) unsigned short sS[128 * SP];
  int tid = threadIdx.x;
  int bm = blockIdx.y * 128, bn = blockIdx.x * 128;
  int lane = tid & 63, w = tid >> 6;
  int wm = (w & 3) * 32, wn = (w >> 2) * 64;
  int l15 = lane & 15, quad = lane >> 4;
  f32x4 zero = {0.f, 0.f, 0.f, 0.f};
  f32x4 acc[2][4];
#pragma unroll
  for (int mt = 0; mt < 2; mt++)
#pragma unroll
    for (int nt = 0; nt < 4; nt++) acc[mt][nt] = zero;

  for (int kt = 0; kt < 128; kt += 32) {
    {
      int row = tid >> 2, ch = tid & 3;
      size_t ga = (size_t)(bm + row) * 128 + kt + ch * 8;
      size_t gb = (size_t)(bn + row) * 128 + kt + ch * 8;
      int ls = row * PAD + ch * 8;
      *(uint4*)&sAh[ls] = *(const uint4*)&Ahi[ga];
      *(uint4*)&sAl[ls] = *(const uint4*)&Alo[ga];
      *(uint4*)&sBh[ls] = *(const uint4*)&Ahi[gb];
      *(uint4*)&sBl[ls] = *(const uint4*)&Alo[gb];
    }
    __syncthreads();
    bf16x8 ah[2], al[2], bh[4], bl[4];
#pragma unroll
    for (int t = 0; t < 2; t++) {
      int ar = (wm + t * 16 + l15) * PAD + quad * 8;
      ah[t] = *(const bf16x8*)&sAh[ar];
      al[t] = *(const bf16x8*)&sAl[ar];
    }
#pragma unroll
    for (int t = 0; t < 4; t++) {
      int br = (wn + t * 16 + l15) * PAD + quad * 8;
      bh[t] = *(const bf16x8*)&sBh[br];
      bl[t] = *(const bf16x8*)&sBl[br];
    }
#pragma unroll
    for (int mt = 0; mt < 2; mt++)
#pragma unroll
      for (int nt = 0; nt < 4; nt++) {
        acc[mt][nt] = __builtin_amdgcn_mfma_f32_16x16x32_bf16(ah[mt], bh[nt], acc[mt][nt], 0, 0, 0);
        acc[mt][nt] = __builtin_amdgcn_mfma_f32_16x16x32_bf16(ah[mt], bl[nt], acc[mt][nt], 0, 0, 0);
        acc[mt][nt] = __builtin_amdgcn_mfma_f32_16x16x32_bf16(al[mt], bh[nt], acc[mt][nt], 0, 0, 0);
      }
    __syncthreads();
  }
  // dump S tile as sortable fp16 bits (diag zeroed)
#pragma unroll
  for (int mt = 0; mt < 2; mt++)
#pragma unroll
    for (int nt = 0; nt < 4; nt++) {
      int coll = wn + nt * 16 + l15;
#pragma unroll
      for (int rg = 0; rg < 4; rg++) {
        int rowl = wm + mt * 16 + quad * 4 + rg;
        float v = (bm + rowl == bn + coll) ? 0.f : acc[mt][nt][rg];
        unsigned hb = (unsigned)__half_as_ushort(__float2half(v));
        hb ^= (hb & 0x8000u) ? 0xFFFFu : 0x8000u;
        sS[rowl * SP + coll] = (unsigned short)hb;
      }
    }
  __syncthreads();
  // serial top-5 scan on packed integer keys: thread -> quarter-row
  int r = tid >> 2, qf = tid & 3;
  const unsigned short* rowp = &sS[r * SP + qf * 32];
  int cbase = bn + qf * 32;
  unsigned k5[5] = {0u, 0u, 0u, 0u, 0u};
#pragma unroll
  for (int q = 0; q < 4; q++) {
    uint4 p = *(const uint4*)&rowp[q * 8];
    unsigned pk[4] = {p.x, p.y, p.z, p.w};
#pragma unroll
    for (int c2 = 0; c2 < 4; c2++) {
      int base = q * 8 + c2 * 2;
      unsigned e0 = ((pk[c2] & 0xffffu) << 5) | (unsigned)(31 - base);
      unsigned e1 = ((pk[c2] >> 16) << 5) | (unsigned)(31 - (base + 1));
      ins5u(e0, k5);
      ins5u(e1, k5);
    }
  }
  int slot = (bn >> 5) + qf;
  float2* cp = &cand[((size_t)(bm + r) * 128 + slot) * 5];
#pragma unroll
  for (int c2 = 0; c2 < 5; c2++) {
    unsigned key = k5[c2];
    int local = 31 - (int)(key & 31u);
    unsigned sb = key >> 5;
    unsigned hb = (sb & 0x8000u) ? (sb ^ 0x8000u) : (sb ^ 0xFFFFu);
    float val = __half2float(__ushort_as_half((unsigned short)hb));
    cp[c2] = {val, __int_as_float(cbase + local)};
  }
}

// -------- row top-k merge + exact fp32 rescore + fused scatter --------
__global__ __launch_bounds__(256) void k_rowtop2s(
    const float2* __restrict__ cand, const float* __restrict__ hhat,
    const float* __restrict__ h, float* __restrict__ hidden2,
    float* __restrict__ colsum_m) {
  int i = blockIdx.x * 4 + (threadIdx.x >> 6);
  int lane = threadIdx.x & 63;
  const float2* cr = &cand[(size_t)i * 640];
  float v[5] = {-3e38f, -3e38f, -3e38f, -3e38f, -3e38f};
  int jx[5] = {0x7fffffff, 0x7fffffff, 0x7fffffff, 0x7fffffff, 0x7fffffff};
#pragma unroll
  for (int c = 0; c < 10; c++) {
    float2 p = cr[lane * 10 + c];
    ins5(p.x, __float_as_int(p.y), v, jx);
  }
#pragma unroll
  for (int d = 1; d < 64; d <<= 1) {
    float fv[5]; int fj[5];
#pragma unroll
    for (int c = 0; c < 5; c++) { fv[c] = __shfl_xor(v[c], d); fj[c] = __shfl_xor(jx[c], d); }
#pragma unroll
    for (int c = 0; c < 5; c++) ins5(fv[c], fj[c], v, jx);
  }
  const float* hi = &hhat[(size_t)i * H];
  float b0 = -3e38f, b1 = -3e38f, b2 = -3e38f;
  int q0 = 0, q1 = 0, q2 = 0;
#pragma unroll
  for (int c = 0; c < 5; c++) {
    int j = jx[c];
    float s;
    if (j == i) {
      s = 0.f;
    } else {
      const float* hj = &hhat[(size_t)j * H];
      float p = hi[lane] * hj[lane] + hi[lane + 64] * hj[lane + 64];
      s = wave_reduce_sum(p);
    }
    top3_ins(s, j, b0, q0, b1, q1, b2, q2);
  }
  float h0 = h[(size_t)i * H + lane], h1 = h[(size_t)i * H + 64 + lane];
  float bv[3] = {b0, b1, b2};
  int qv[3] = {q0, q1, q2};
#pragma unroll
  for (int s = 0; s < 3; s++) {
    float vv = bv[s];
    int j = qv[s];
    atomicAdd(&hidden2[(size_t)j * H + lane], vv * h0);
    atomicAdd(&hidden2[(size_t)j * H + 64 + lane], vv * h1);
    if (lane == s) atomicAdd(&colsum_m[j], vv);
  }
}

// ---------------- flash-fused hs_pre numerator (ring double-buffer) ----------
__global__ __launch_bounds__(512) void k_flash(
    const unsigned short* __restrict__ Qhi, const unsigned short* __restrict__ Qlo,
    const unsigned short* __restrict__ Khi, const unsigned short* __restrict__ Klo,
    const unsigned short* __restrict__ Vthi, const unsigned short* __restrict__ Vtlo,
    const float* __restrict__ valid2f, float* __restrict__ partialU,
    float* __restrict__ plsum, int KVC) {
  __shared__ __align__(16) unsigned short sQh[128 * FWP];
  __shared__ __align__(16) unsigned short sQl[128 * FWP];
  __shared__ __align__(16) unsigned short sP[128 * FWP];
  __shared__ __align__(16) unsigned short sBh[2][128 * PAD];
  __shared__ __align__(16) unsigned short sBl[2][128 * PAD];
  __shared__ float lsum_s[128];
  int tid = threadIdx.x;
  int z = blockIdx.x;
  int bm = blockIdx.y * 128;
  int j0 = z * KVC;
  int lane = tid & 63, w = tid >> 6;
  int wm = (w & 3) * 32, wn = (w >> 2) * 64;
  int l15 = lane & 15, quad = lane >> 4;
  int srow = tid >> 2, sch = tid & 3;
  int sls = srow * PAD + sch * 8;
#pragma unroll
  for (int q = 0; q < 4; q++) {
    int f = q * 512 + tid;
    int row = f >> 4, ch = f & 15;
    size_t ga = (size_t)(bm + row) * 128 + ch * 8;
    int ls = row * FWP + ch * 8;
    *(uint4*)&sQh[ls] = *(const uint4*)&Qhi[ga];
    *(uint4*)&sQl[ls] = *(const uint4*)&Qlo[ga];
  }
  if (tid < 128) lsum_s[tid] = 0.f;
  {
    size_t a = (size_t)(j0 + srow) * 128 + sch * 8;
    uint4 rh = *(const uint4*)&Khi[a];
    uint4 rl = *(const uint4*)&Klo[a];
    __syncthreads();
    *(uint4*)&sBh[0][sls] = rh;
    *(uint4*)&sBl[0][sls] = rl;
  }
  __syncthreads();
  int cur = 0;
  f32x4 zero = {0.f, 0.f, 0.f, 0.f};
  f32x4 uacc[2][4];
#pragma unroll
  for (int mt = 0; mt < 2; mt++)
#pragma unroll
    for (int nt = 0; nt < 4; nt++) uacc[mt][nt] = zero;

  for (int jb = j0; jb < j0 + KVC; jb += 128) {
    float vm[4];
#pragma unroll
    for (int nt = 0; nt < 4; nt++) vm[nt] = valid2f[jb + wn + nt * 16 + l15];
    f32x4 qacc[2][4];
#pragma unroll
    for (int mt = 0; mt < 2; mt++)
#pragma unroll
      for (int nt = 0; nt < 4; nt++) qacc[mt][nt] = zero;
#pragma unroll
    for (int t = 0; t < 4; t++) {
      uint4 nrh, nrl;
      if (t < 3) {
        size_t a = (size_t)(jb + srow) * 128 + (t + 1) * 32 + sch * 8;
        nrh = *(const uint4*)&Khi[a];
        nrl = *(const uint4*)&Klo[a];
      } else {
        size_t a = (size_t)srow * N + jb + sch * 8;
        nrh = *(const uint4*)&Vthi[a];
        nrl = *(const uint4*)&Vtlo[a];
      }
      int kt = t * 32;
      bf16x8 ah[2], al[2], bh[4], bl[4];
#pragma unroll
      for (int tt = 0; tt < 2; tt++) {
        int ar = (wm + tt * 16 + l15) * FWP + kt + quad * 8;
        ah[tt] = *(const bf16x8*)&sQh[ar];
        al[tt] = *(const bf16x8*)&sQl[ar];
      }
#pragma unroll
      for (int tt = 0; tt < 4; tt++) {
        int br = (wn + tt * 16 + l15) * PAD + quad * 8;
        bh[tt] = *(const bf16x8*)&sBh[cur][br];
        bl[tt] = *(const bf16x8*)&sBl[cur][br];
      }
#pragma unroll
      for (int mt = 0; mt < 2; mt++)
#pragma unroll
        for (int nt = 0; nt < 4; nt++) {
          qacc[mt][nt] = __builtin_amdgcn_mfma_f32_16x16x32_bf16(ah[mt], bh[nt], qacc[mt][nt], 0, 0, 0);
          qacc[mt][nt] = __builtin_amdgcn_mfma_f32_16x16x32_bf16(ah[mt], bl[nt], qacc[mt][nt], 0, 0, 0);
          qacc[mt][nt] = __builtin_amdgcn_mfma_f32_16x16x32_bf16(al[mt], bh[nt], qacc[mt][nt], 0, 0, 0);
        }
      *(uint4*)&sBh[cur ^ 1][sls] = nrh;
      *(uint4*)&sBl[cur ^ 1][sls] = nrl;
      __syncthreads();
      cur ^= 1;
    }
#pragma unroll
    for (int mt = 0; mt < 2; mt++) {
#pragma unroll
      for (int rg = 0; rg < 4; rg++) {
        int row = wm + mt * 16 + quad * 4 + rg;
        float rs = 0.f;
#pragma unroll
        for (int nt = 0; nt < 4; nt++) {
          float e = (vm[nt] != 0.f) ? __expf(qacc[mt][nt][rg] - 1.f) : 0.f;
          rs += e;
          sP[row * FWP + wn + nt * 16 + l15] = f2bf(e);
        }
#pragma unroll
        for (int d = 1; d < 16; d <<= 1) rs += __shfl_xor(rs, d);
        if (l15 == 0) atomicAdd(&lsum_s[row], rs);
      }
    }
    __syncthreads();
#pragma unroll
    for (int t = 0; t < 4; t++) {
      uint4 nrh = {0, 0, 0, 0}, nrl = {0, 0, 0, 0};
      bool have;
      if (t < 3) {
        have = true;
        size_t a = (size_t)srow * N + jb + (t + 1) * 32 + sch * 8;
        nrh = *(const uint4*)&Vthi[a];
        nrl = *(const uint4*)&Vtlo[a];
      } else {
        have = (jb + 128 < j0 + KVC);
        if (have) {
          size_t a = (size_t)(jb + 128 + srow) * 128 + sch * 8;
          nrh = *(const uint4*)&Khi[a];
          nrl = *(const uint4*)&Klo[a];
        }
      }
      int kt = t * 32;
      bf16x8 pa[2], vh[4], vl[4];
#pragma unroll
      for (int tt = 0; tt < 2; tt++) {
        int ar = (wm + tt * 16 + l15) * FWP + kt + quad * 8;
        pa[tt] = *(const bf16x8*)&sP[ar];
      }
#pragma unroll
      for (int tt = 0; tt < 4; tt++) {
        int br = (wn + tt * 16 + l15) * PAD + quad * 8;
        vh[tt] = *(const bf16x8*)&sBh[cur][br];
        vl[tt] = *(const bf16x8*)&sBl[cur][br];
      }
#pragma unroll
      for (int mt = 0; mt < 2; mt++)
#pragma unroll
        for (int nt = 0; nt < 4; nt++) {
          uacc[mt][nt] = __builtin_amdgcn_mfma_f32_16x16x32_bf16(pa[mt], vh[nt], uacc[mt][nt], 0, 0, 0);
          uacc[mt][nt] = __builtin_amdgcn_mfma_f32_16x16x32_bf16(pa[mt], vl[nt], uacc[mt][nt], 0, 0, 0);
        }
      if (have) {
        *(uint4*)&sBh[cur ^ 1][sls] = nrh;
        *(uint4*)&sBl[cur ^ 1][sls] = nrl;
      }
      __syncthreads();
      cur ^= 1;
    }
  }
  float* pU = partialU + (size_t)z * N * 128;
#pragma unroll
  for (int mt = 0; mt < 2; mt++)
#pragma unroll
    for (int nt = 0; nt < 4; nt++) {
      int col = wn + nt * 16 + l15;
#pragma unroll
      for (int rg = 0; rg < 4; rg++) {
        int row = bm + wm + mt * 16 + quad * 4 + rg;
        pU[(size_t)row * 128 + col] = uacc[mt][nt][rg];
      }
    }
  if (tid < 128) plsum[(size_t)z * N + bm + tid] = lsum_s[tid];
}

// ---------------- bf16 MFMA KN GEMM (split-K): partial[z] = A @ B ------------
__global__ __launch_bounds__(256) void k_mfma_kn(
    const unsigned short* __restrict__ Ahi, const unsigned short* __restrict__ Alo,
    const unsigned short* __restrict__ Bthi, const unsigned short* __restrict__ Btlo,
    float* __restrict__ partial, int lda, int KC) {
  __shared__ __align__(16) unsigned short sAh[128 * PAD];
  __shared__ __align__(16) unsigned short sAl[128 * PAD];
  __shared__ __align__(16) unsigned short sBh[128 * PAD];
  __shared__ __align__(16) unsigned short sBl[128 * PAD];
  int tid = threadIdx.x;
  int bm = blockIdx.y * 128;
  int k0 = blockIdx.z * KC;
  int lane = tid & 63, w = tid >> 6;
  int wm = (w & 1) * 64, wn = (w >> 1) * 64;
  int l15 = lane & 15, quad = lane >> 4;
  f32x4 zero = {0.f, 0.f, 0.f, 0.f};
  f32x4 acc[4][4];
#pragma unroll
  for (int mt = 0; mt < 4; mt++)
#pragma unroll
    for (int nt = 0; nt < 4; nt++) acc[mt][nt] = zero;

  for (int kt = 0; kt < KC; kt += 32) {
#pragma unroll
    for (int q = 0; q < 2; q++) {
      int f = tid * 2 + q;
      int row = f >> 2, ch = f & 3;
      size_t ga = (size_t)(bm + row) * lda + k0 + kt + ch * 8;
      size_t gb = (size_t)row * lda + k0 + kt + ch * 8;
      int ls = row * PAD + ch * 8;
      *(uint4*)&sAh[ls] = *(const uint4*)&Ahi[ga];
      *(uint4*)&sAl[ls] = *(const uint4*)&Alo[ga];
      *(uint4*)&sBh[ls] = *(const uint4*)&Bthi[gb];
      *(uint4*)&sBl[ls] = *(const uint4*)&Btlo[gb];
    }
    __syncthreads();
    bf16x8 ah[4], al[4], bh[4], bl[4];
#pragma unroll
    for (int t = 0; t < 4; t++) {
      int ar = (wm + t * 16 + l15) * PAD + quad * 8;
      ah[t] = *(const bf16x8*)&sAh[ar];
      al[t] = *(const bf16x8*)&sAl[ar];
      int br = (wn + t * 16 + l15) * PAD + quad * 8;
      bh[t] = *(const bf16x8*)&sBh[br];
      bl[t] = *(const bf16x8*)&sBl[br];
    }
#pragma unroll
    for (int mt = 0; mt < 4; mt++)
#pragma unroll
      for (int nt = 0; nt < 4; nt++) {
        acc[mt][nt] = __builtin_amdgcn_mfma_f32_16x16x32_bf16(ah[mt], bh[nt], acc[mt][nt], 0, 0, 0);
        acc[mt][nt] = __builtin_amdgcn_mfma_f32_16x16x32_bf16(ah[mt], bl[nt], acc[mt][nt], 0, 0, 0);
        acc[mt][nt] = __builtin_amdgcn_mfma_f32_16x16x32_bf16(al[mt], bh[nt], acc[mt][nt], 0, 0, 0);
      }
    __syncthreads();
  }
  float* pp = partial + (size_t)blockIdx.z * N * 128;
#pragma unroll
  for (int mt = 0; mt < 4; mt++)
#pragma unroll
    for (int nt = 0; nt < 4; nt++) {
      int col = wn + nt * 16 + l15;
#pragma unroll
      for (int rg = 0; rg < 4; rg++) {
        int row = bm + wm + mt * 16 + quad * 4 + rg;
        pp[(size_t)row * 128 + col] = acc[mt][nt][rg];
      }
    }
}

// ---------------- bf16x3 MFMA genA GEMM (split-K) ----------------
template <int AMODE>
__global__ __launch_bounds__(256) void k_mfma_genA(
    const float* __restrict__ P, const float* __restrict__ mv,
    const float* __restrict__ col1, const float* __restrict__ col2,
    const unsigned short* __restrict__ Bthi, const unsigned short* __restrict__ Btlo,
    float* __restrict__ partial, int KC) {
  __shared__ __align__(16) unsigned short sAh[128 * PAD];
  __shared__ __align__(16) unsigned short sAl[128 * PAD];
  __shared__ __align__(16) unsigned short sBh[128 * PAD];
  __shared__ __align__(16) unsigned short sBl[128 * PAD];
  int tid = threadIdx.x;
  int bm = blockIdx.y * 128;
  int k0 = blockIdx.z * KC;
  int lane = tid & 63, w = tid >> 6;
  int wm = (w & 1) * 64, wn = (w >> 1) * 64;
  int l15 = lane & 15, quad = lane >> 4;
  f32x4 zero = {0.f, 0.f, 0.f, 0.f};
  f32x4 acc[4][4];
#pragma unroll
  for (int mt = 0; mt < 4; mt++)
#pragma unroll
    for (int nt = 0; nt < 4; nt++) acc[mt][nt] = zero;

  for (int kt = 0; kt < KC; kt += 32) {
    int kr = tid >> 3;
    int mc = (tid & 7) * 16;
    int k = k0 + kt + kr;
    float mvk = (AMODE == 1) ? mv[k] : 0.f;
#pragma unroll
    for (int q = 0; q < 4; q++) {
      int m0 = mc + q * 4;
      float4 pv = *(const float4*)&P[(size_t)k * C + bm + m0];
      float4 c1 = *(const float4*)&col1[bm + m0];
      float wv[4];
      if (AMODE == 1) {
        wv[0] = pv.x * mvk / (c1.x * pv.x + 1.f);
        wv[1] = pv.y * mvk / (c1.y * pv.y + 1.f);
        wv[2] = pv.z * mvk / (c1.z * pv.z + 1.f);
        wv[3] = pv.w * mvk / (c1.w * pv.w + 1.f);
      } else {
        float4 c2 = *(const float4*)&col2[bm + m0];
        wv[0] = __expf(pv.x - c1.x) / c2.x;
        wv[1] = __expf(pv.y - c1.y) / c2.y;
        wv[2] = __expf(pv.z - c1.z) / c2.z;
        wv[3] = __expf(pv.w - c1.w) / c2.w;
      }
#pragma unroll
      for (int j = 0; j < 4; j++) {
        unsigned short hh = f2bf(wv[j]);
        sAh[(m0 + j) * PAD + kr] = hh;
        sAl[(m0 + j) * PAD + kr] = f2bf(wv[j] - bf2f(hh));
      }
    }
#pragma unroll
    for (int q = 0; q < 2; q++) {
      int f = q * 256 + tid;
      int row = f >> 2, ch = f & 3;
      size_t gb = (size_t)row * N + k0 + kt + ch * 8;
      int ls = row * PAD + ch * 8;
      *(uint4*)&sBh[ls] = *(const uint4*)&Bthi[gb];
      *(uint4*)&sBl[ls] = *(const uint4*)&Btlo[gb];
    }
    __syncthreads();
    bf16x8 ah[4], al[4], bh[4], bl[4];
#pragma unroll
    for (int t = 0; t < 4; t++) {
      int ar = (wm + t * 16 + l15) * PAD + quad * 8;
      ah[t] = *(const bf16x8*)&sAh[ar];
      al[t] = *(const bf16x8*)&sAl[ar];
      int br = (wn + t * 16 + l15) * PAD + quad * 8;
      bh[t] = *(const bf16x8*)&sBh[br];
      bl[t] = *(const bf16x8*)&sBl[br];
    }
#pragma unroll
    for (int mt = 0; mt < 4; mt++)
#pragma unroll
      for (int nt = 0; nt < 4; nt++) {
        acc[mt][nt] = __builtin_amdgcn_mfma_f32_16x16x32_bf16(ah[mt], bh[nt], acc[mt][nt], 0, 0, 0);
        acc[mt][nt] = __builtin_amdgcn_mfma_f32_16x16x32_bf16(ah[mt], bl[nt], acc[mt][nt], 0, 0, 0);
        acc[mt][nt] = __builtin_amdgcn_mfma_f32_16x16x32_bf16(al[mt], bh[nt], acc[mt][nt], 0, 0, 0);
      }
    __syncthreads();
  }
  float* pp = partial + (size_t)blockIdx.z * C * 128;
#pragma unroll
  for (int mt = 0; mt < 4; mt++)
#pragma unroll
    for (int nt = 0; nt < 4; nt++) {
      int col = wn + nt * 16 + l15;
#pragma unroll
      for (int rg = 0; rg < 4; rg++) {
        int row = bm + wm + mt * 16 + quad * 4 + rg;
        pp[(size_t)row * 128 + col] = acc[mt][nt][rg];
      }
    }
}

// reduce split-K partials (C*H shapes); optional per-row scale; pair emission;
// row-norm / row-valid emission
__global__ __launch_bounds__(256) void k_reduce(
    const float* __restrict__ partial, float* __restrict__ out, int cnt,
    size_t slot, size_t size4, const float* __restrict__ scalem,
    unsigned short* __restrict__ hi, unsigned short* __restrict__ lo,
    float* __restrict__ nrmout, float* __restrict__ validout) {
  size_t idx = (size_t)blockIdx.x * 256 + threadIdx.x;
  if (idx >= size4) return;
  float4 s = {0, 0, 0, 0};
  for (int c = 0; c < cnt; c++) {
    float4 v = *(const float4*)&partial[c * slot + idx * 4];
    s.x += v.x; s.y += v.y; s.z += v.z; s.w += v.w;
  }
  if (scalem) {
    float sc = scalem[idx >> 5];
    s.x *= sc; s.y *= sc; s.z *= sc; s.w *= sc;
  }
  *(float4*)&out[idx * 4] = s;
  if (hi) {
    float vv[4] = {s.x, s.y, s.z, s.w};
    unsigned short h[4], l[4];
#pragma unroll
    for (int c = 0; c < 4; c++) {
      h[c] = f2bf(vv[c]);
      l[c] = f2bf(vv[c] - bf2f(h[c]));
    }
    uint2 ph = {(unsigned)h[0] | ((unsigned)h[1] << 16),
                (unsigned)h[2] | ((unsigned)h[3] << 16)};
    uint2 pl = {(unsigned)l[0] | ((unsigned)l[1] << 16),
                (unsigned)l[2] | ((unsigned)l[3] << 16)};
    *(uint2*)&hi[idx * 4] = ph;
    *(uint2*)&lo[idx * 4] = pl;
  }
  if (nrmout || validout) {
    float rs = s.x + s.y + s.z + s.w;
    float rq = s.x * s.x + s.y * s.y + s.z * s.z + s.w * s.w;
#pragma unroll
    for (int m = 16; m; m >>= 1) { rs += __shfl_xor(rs, m); rq += __shfl_xor(rq, m); }
    if ((threadIdx.x & 31) == 0) {
      if (nrmout) nrmout[idx >> 5] = sqrtf(rq);
      if (validout) validout[idx >> 5] = (rs != 0.f) ? 1.f : 0.f;
    }
  }
}

// ---------------- fused branch-tail kernels (16 rows/block, 256 blocks) ------

#define LOAD_W(Wt)                                                        \
  do {                                                                    \
    _Pragma("unroll") for (int q = 0; q < 16; q++) {                      \
      int f = q * 256 + tid;                                              \
      int wr = f >> 5, wc = (f & 31) * 4;                                 \
      float4 wv = *(const float4*)&(Wt)[(size_t)wr * 128 + wc];           \
      float ww[4] = {wv.x, wv.y, wv.z, wv.w};                             \
      _Pragma("unroll") for (int c = 0; c < 4; c++) {                     \
        unsigned short hh = f2bf(ww[c]);                                  \
        sWh[wr * WP + wc + c] = hh;                                       \
        sWl[wr * WP + wc + c] = f2bf(ww[c] - bf2f(hh));                   \
      }                                                                   \
    }                                                                     \
  } while (0)

// 16-row GEMM: each wave owns a 16x32 quadrant (cn = w*32, nt<2)
#define GEMM16(accv)                                                              \
  do {                                                                            \
    _Pragma("unroll") for (int nt = 0; nt < 2; nt++) accv[nt] = zero;             \
    _Pragma("unroll") for (int kt = 0; kt < 128; kt += 32) {                      \
      bf16x8 ah = *(const bf16x8*)&sAh[l15 * WP + kt + quad * 8];                 \
      bf16x8 al = *(const bf16x8*)&sAl[l15 * WP + kt + quad * 8];                 \
      _Pragma("unroll") for (int nt = 0; nt < 2; nt++) {                          \
        int br = (cn + nt * 16 + l15) * WP + kt + quad * 8;                       \
        bf16x8 bh = *(const bf16x8*)&sWh[br];                                     \
        bf16x8 bl = *(const bf16x8*)&sWl[br];                                     \
        accv[nt] = __builtin_amdgcn_mfma_f32_16x16x32_bf16(ah, bh, accv[nt], 0, 0, 0); \
        accv[nt] = __builtin_amdgcn_mfma_f32_16x16x32_bf16(ah, bl, accv[nt], 0, 0, 0); \
        accv[nt] = __builtin_amdgcn_mfma_f32_16x16x32_bf16(al, bh, accv[nt], 0, 0, 0); \
      }                                                                           \
    }                                                                             \
  } while (0)

// ps tail: ps_pre = sum_z partial; p_shared = lin(ps_pre,W_ps);
// h = x - lin(p_shared,W_psb); out_ps -> all_info; hhat/pairs/diagv from h.
__global__ __launch_bounds__(256) void k_ps_tail(
    const float* __restrict__ partial, int zcnt, const float* __restrict__ x,
    const float* __restrict__ W_ps, const float* __restrict__ b_ps,
    const float* __restrict__ W_psb, const float* __restrict__ b_psb,
    const float* __restrict__ W_psf, const float* __restrict__ b_psf,
    float* __restrict__ hbuf, float* __restrict__ hhat,
    unsigned short* __restrict__ hhi, unsigned short* __restrict__ hlo,
    float* __restrict__ diagv, float* __restrict__ all_info) {
  __shared__ __align__(16) unsigned short sWh[128 * WP];
  __shared__ __align__(16) unsigned short sWl[128 * WP];
  __shared__ __align__(16) unsigned short sAh[16 * WP];
  __shared__ __align__(16) unsigned short sAl[16 * WP];
  __shared__ __align__(16) float sF[16][132];
  int tid = threadIdx.x;
  int bm = blockIdx.x * 16;
  int lane = tid & 63, w = tid >> 6;
  int cn = w * 32;
  int l15 = lane & 15, quad = lane >> 4;
  f32x4 zero = {0.f, 0.f, 0.f, 0.f};
  f32x4 acc[2];

  // stage ps_pre tile (sum of split-K partials) -> pairs
  {
    int row = tid >> 4, c0 = (tid & 15) * 8;
    size_t off0 = (size_t)(bm + row) * 128 + c0;
#pragma unroll
    for (int q = 0; q < 2; q++) {
      float vv[4] = {0.f, 0.f, 0.f, 0.f};
      for (int z = 0; z < zcnt; z++) {
        float4 v = *(const float4*)&partial[(size_t)z * N * H + off0 + q * 4];
        vv[0] += v.x; vv[1] += v.y; vv[2] += v.z; vv[3] += v.w;
      }
#pragma unroll
      for (int c = 0; c < 4; c++) {
        unsigned short hh = f2bf(vv[c]);
        sAh[row * WP + c0 + q * 4 + c] = hh;
        sAl[row * WP + c0 + q * 4 + c] = f2bf(vv[c] - bf2f(hh));
      }
    }
  }
  LOAD_W(W_ps);
  __syncthreads();
  GEMM16(acc);  // p_shared (pre-bias)
  __syncthreads();
#pragma unroll
  for (int nt = 0; nt < 2; nt++) {
    int col = cn + nt * 16 + l15;
    float bv = b_ps[col];
#pragma unroll
    for (int rg = 0; rg < 4; rg++) {
      int row = quad * 4 + rg;
      float v = acc[nt][rg] + bv;
      unsigned short hh = f2bf(v);
      sAh[row * WP + col] = hh;
      sAl[row * WP + col] = f2bf(v - bf2f(hh));
    }
  }
  LOAD_W(W_psb);
  __syncthreads();
  GEMM16(acc);  // p_back (pre-bias)
#pragma unroll
  for (int nt = 0; nt < 2; nt++) {
    int col = cn + nt * 16 + l15;
    float bv = b_psb[col];
#pragma unroll
    for (int rg = 0; rg < 4; rg++) {
      int row = quad * 4 + rg;
      size_t off = (size_t)(bm + row) * 128 + col;
      float hv = x[off] - (acc[nt][rg] + bv);
      hbuf[off] = hv;
      sF[row][col] = hv;
    }
  }
  __syncthreads();
  // hhat substage (reads sF)
  {
    int row = tid >> 4, c0 = (tid & 15) * 8;
    float hv8[8];
    float ssp = 0.f;
#pragma unroll
    for (int q = 0; q < 8; q++) {
      float v = sF[row][c0 + q];
      hv8[q] = v;
      ssp += v * v;
    }
    ssp += __shfl_xor(ssp, 1);
    ssp += __shfl_xor(ssp, 2);
    ssp += __shfl_xor(ssp, 4);
    ssp += __shfl_xor(ssp, 8);
    float ss = ssp;
    float hn = sqrtf(ss);
    float den = hn * hn;
    float dg = (den == 0.f) ? 0.f : ss / den;
    float inv = (ss > 0.f) ? (1.f / hn) : 1.f;
    size_t base = (size_t)(bm + row) * H + c0;
    float va8[8];
    unsigned short hh8[8], ll8[8];
#pragma unroll
    for (int q = 0; q < 8; q++) {
      va8[q] = hv8[q] * inv;
      hh8[q] = f2bf(va8[q]);
      ll8[q] = f2bf(va8[q] - bf2f(hh8[q]));
    }
#pragma unroll
    for (int q4 = 0; q4 < 2; q4++) {
      float4 fv = {va8[q4 * 4], va8[q4 * 4 + 1], va8[q4 * 4 + 2], va8[q4 * 4 + 3]};
      *(float4*)&hhat[base + q4 * 4] = fv;
    }
    uint4 ph = {(unsigned)hh8[0] | ((unsigned)hh8[1] << 16), (unsigned)hh8[2] | ((unsigned)hh8[3] << 16),
                (unsigned)hh8[4] | ((unsigned)hh8[5] << 16), (unsigned)hh8[6] | ((unsigned)hh8[7] << 16)};
    uint4 pl = {(unsigned)ll8[0] | ((unsigned)ll8[1] << 16), (unsigned)ll8[2] | ((unsigned)ll8[3] << 16),
                (unsigned)ll8[4] | ((unsigned)ll8[5] << 16), (unsigned)ll8[6] | ((unsigned)ll8[7] << 16)};
    *(uint4*)&hhi[base] = ph;
    *(uint4*)&hlo[base] = pl;
    if ((tid & 15) == 0) diagv[bm + row] = dg;
  }
  LOAD_W(W_psf);
  __syncthreads();
  GEMM16(acc);  // out_ps (pre-bias)
#pragma unroll
  for (int nt = 0; nt < 2; nt++) {
    int col = cn + nt * 16 + l15;
    float bv = b_psf[col];
#pragma unroll
    for (int rg = 0; rg < 4; rg++) {
      int row = quad * 4 + rg;
      size_t off = (size_t)(bm + row) * 128 + col;
      all_info[off] = lrelu(acc[nt][rg] + bv);
    }
  }
}

// hs tail: hs_pre = (sum_z partialU)/lsum; h_shared = lin(hs_pre,W_hs);
// all = all_info + lrelu(lin(h_shared,W_hsf)); indiv = h - lin(h_shared,W_hsb);
// all += lrelu(lin(indiv,W_in)); out = all @ W_out + b.
__global__ __launch_bounds__(256) void k_hs_tail(
    const float* __restrict__ partial, const float* __restrict__ plsum, int zcnt,
    const float* __restrict__ hbuf, const float* __restrict__ all_info,
    const float* __restrict__ W_hs, const float* __restrict__ b_hs,
    const float* __restrict__ W_hsf, const float* __restrict__ b_hsf,
    const float* __restrict__ W_hsb, const float* __restrict__ b_hsb,
    const float* __restrict__ W_in, const float* __restrict__ b_in,
    const float* __restrict__ W_out, const float* __restrict__ b_out,
    float* __restrict__ out) {
  __shared__ __align__(16) unsigned short sWh[128 * WP];
  __shared__ __align__(16) unsigned short sWl[128 * WP];
  __shared__ __align__(16) unsigned short sAh[16 * WP];
  __shared__ __align__(16) unsigned short sAl[16 * WP];
  __shared__ __align__(16) float sF[16][132];
  int tid = threadIdx.x;
  int bm = blockIdx.x * 16;
  int lane = tid & 63, w = tid >> 6;
  int cn = w * 32;
  int l15 = lane & 15, quad = lane >> 4;
  f32x4 zero = {0.f, 0.f, 0.f, 0.f};
  f32x4 acc[2];
  float allv[2][4];

  // stage hs_pre tile: sum of split-KV partials / total lsum
  {
    int row = tid >> 4, c0 = (tid & 15) * 8;
    float d = 0.f;
    for (int z = 0; z < zcnt; z++) d += plsum[(size_t)z * N + bm + row];
    float sc = 1.f / d;
    size_t off0 = (size_t)(bm + row) * 128 + c0;
#pragma unroll
    for (int q = 0; q < 2; q++) {
      float vv[4] = {0.f, 0.f, 0.f, 0.f};
      for (int z = 0; z < zcnt; z++) {
        float4 v = *(const float4*)&partial[(size_t)z * N * H + off0 + q * 4];
        vv[0] += v.x; vv[1] += v.y; vv[2] += v.z; vv[3] += v.w;
      }
#pragma unroll
      for (int c = 0; c < 4; c++) {
        float val = vv[c] * sc;
        unsigned short hh = f2bf(val);
        sAh[row * WP + c0 + q * 4 + c] = hh;
        sAl[row * WP + c0 + q * 4 + c] = f2bf(val - bf2f(hh));
      }
    }
  }
  LOAD_W(W_hs);
  __syncthreads();
  GEMM16(acc);  // h_shared (pre-bias)
  __syncthreads();
#pragma unroll
  for (int nt = 0; nt < 2; nt++) {
    int col = cn + nt * 16 + l15;
    float bv = b_hs[col];
#pragma unroll
    for (int rg = 0; rg < 4; rg++) {
      int row = quad * 4 + rg;
      float v = acc[nt][rg] + bv;
      unsigned short hh = f2bf(v);
      sAh[row * WP + col] = hh;
      sAl[row * WP + col] = f2bf(v - bf2f(hh));
    }
  }
  LOAD_W(W_hsf);
  __syncthreads();
  GEMM16(acc);  // out_hs (pre-bias)
#pragma unroll
  for (int nt = 0; nt < 2; nt++) {
    int col = cn + nt * 16 + l15;
    float bv = b_hsf[col];
#pragma unroll
    for (int rg = 0; rg < 4; rg++) {
      int row = quad * 4 + rg;
      size_t off = (size_t)(bm + row) * 128 + col;
      allv[nt][rg] = all_info[off] + lrelu(acc[nt][rg] + bv);
    }
  }
  __syncthreads();
  LOAD_W(W_hsb);
  __syncthreads();
  GEMM16(acc);  // h_back (pre-bias)
  float iv[2][4];
#pragma unroll
  for (int nt = 0; nt < 2; nt++) {
    int col = cn + nt * 16 + l15;
    float bv = b_hsb[col];
#pragma unroll
    for (int rg = 0; rg < 4; rg++) {
      int row = quad * 4 + rg;
      size_t off = (size_t)(bm + row) * 128 + col;
      iv[nt][rg] = hbuf[off] - (acc[nt][rg] + bv);
    }
  }
  __syncthreads();
#pragma unroll
  for (int nt = 0; nt < 2; nt++) {
    int col = cn + nt * 16 + l15;
#pragma unroll
    for (int rg = 0; rg < 4; rg++) {
      int row = quad * 4 + rg;
      unsigned short hh = f2bf(iv[nt][rg]);
      sAh[row * WP + col] = hh;
      sAl[row * WP + col] = f2bf(iv[nt][rg] - bf2f(hh));
    }
  }
  LOAD_W(W_in);
  __syncthreads();
  GEMM16(acc);  // out_indi (pre-bias)
#pragma unroll
  for (int nt = 0; nt < 2; nt++) {
    int col = cn + nt * 16 + l15;
    float bv = b_in[col];
#pragma unroll
    for (int rg = 0; rg < 4; rg++) {
      int row = quad * 4 + rg;
      allv[nt][rg] += lrelu(acc[nt][rg] + bv);
      sF[row][col] = allv[nt][rg];
    }
  }
  __syncthreads();
  {
    int row = tid >> 4, c0 = (tid & 15) * 8;
    float s = 0.f;
#pragma unroll
    for (int q = 0; q < 8; q++) s += sF[row][c0 + q] * W_out[c0 + q];
    s += __shfl_xor(s, 1);
    s += __shfl_xor(s, 2);
    s += __shfl_xor(s, 4);
    s += __shfl_xor(s, 8);
    if ((tid & 15) == 0) out[bm + row] = s + b_out[0];
  }
}

// ---------------- launch ----------------

extern "C" void kernel_launch(void* const* d_in, const int* in_sizes, int n_in,
                              void* d_out, int out_size, void* d_ws, size_t ws_size,
                              hipStream_t stream) {
  (void)in_sizes; (void)n_in; (void)out_size; (void)ws_size;
  const float* x   = (const float*)d_in[0];
  const float* cm  = (const float*)d_in[1];
  const float* mv  = (const float*)d_in[2];
  const float* W_ps = (const float*)d_in[3],  *b_ps = (const float*)d_in[4];
  const float* W_psf = (const float*)d_in[5], *b_psf = (const float*)d_in[6];
  const float* W_psb = (const float*)d_in[7], *b_psb = (const float*)d_in[8];
  const float* W_hs = (const float*)d_in[9],  *b_hs = (const float*)d_in[10];
  const float* W_hsf = (const float*)d_in[11], *b_hsf = (const float*)d_in[12];
  const float* W_hsb = (const float*)d_in[13], *b_hsb = (const float*)d_in[14];
  const float* W_in = (const float*)d_in[15], *b_in = (const float*)d_in[16];
  const float* W_out = (const float*)d_in[17], *b_out = (const float*)d_in[18];
  float* out = (float*)d_out;

  float* W = (float*)d_ws;
  size_t o = 0;
  auto alloc = [&](size_t n) { float* p = W + o; o += n; return p; };
  float* colsum_c = alloc(C);
  float* colmax   = alloc(C);
  float* colsumexp= alloc(C);
  float* valid1   = alloc(C);
  float* hnorm_ps = alloc(C);
  float* xnorm    = alloc(N);
  float* diagv    = alloc(N);
  float* colsum_m = alloc(N);
  float* valid2f  = alloc(N);
  float* plsum    = alloc((size_t)8 * N);
  float* hidden1  = alloc((size_t)C * H);
  float* hidden_ps= alloc((size_t)C * H);
  float* scores   = alloc((size_t)N * C);
  float* all_info = alloc((size_t)N * H);
  float* hbuf     = alloc((size_t)N * H);   // h
  float* hhat     = alloc((size_t)N * H);
  float* hidden2  = alloc((size_t)N * H);
  unsigned short* xhi    = (unsigned short*)alloc((size_t)N * H / 2);
  unsigned short* xlo    = (unsigned short*)alloc((size_t)N * H / 2);
  unsigned short* hhathi = (unsigned short*)alloc((size_t)N * H / 2);
  unsigned short* hhatlo = (unsigned short*)alloc((size_t)N * H / 2);
  unsigned short* h2hi   = (unsigned short*)alloc((size_t)N * H / 2);
  unsigned short* h2lo   = (unsigned short*)alloc((size_t)N * H / 2);
  unsigned short* h1hi   = (unsigned short*)alloc((size_t)C * H / 2);
  unsigned short* h1lo   = (unsigned short*)alloc((size_t)C * H / 2);
  unsigned short* hpshi  = (unsigned short*)alloc((size_t)C * H / 2);
  unsigned short* hpslo  = (unsigned short*)alloc((size_t)C * H / 2);
  unsigned short* cshi   = (unsigned short*)alloc((size_t)N * C / 2);
  unsigned short* cslo   = (unsigned short*)alloc((size_t)N * C / 2);
  unsigned short* hpst_hi= (unsigned short*)alloc((size_t)H * C / 2);
  unsigned short* hpst_lo= (unsigned short*)alloc((size_t)H * C / 2);
  unsigned short* h2t_hi = (unsigned short*)alloc((size_t)H * N / 2);
  unsigned short* h2t_lo = (unsigned short*)alloc((size_t)H * N / 2);
  unsigned short* xt_hi  = (unsigned short*)alloc((size_t)H * N / 2);
  unsigned short* xt_lo  = (unsigned short*)alloc((size_t)H * N / 2);
  float2* cand    = (float2*)alloc((size_t)N * 128 * 5 * 2);
  float* partial  = W + o;
  const int Z = 8;        // flash split-KV (8*N*128 fp32)
  const int ZG = 64;      // genA split-K (64*C*128 fp32); same region
  const int ZK = 8;       // cs-GEMM split-K (8*N*128 fp32); same region

  dim3 blk(256);
  // --- ps branch ---
  k_xprep<<<dim3(N / 32), blk, 0, stream>>>(x, xhi, xlo, xnorm, xt_hi, xt_lo,
                                            hidden2, colsum_c, colsum_m);
  k_colsum_s2c<<<dim3(C / 64, 16), dim3(64), 0, stream>>>(cm, mv, colsum_c);
  k_mfma_genA<1><<<dim3(1, C / 128, ZG), blk, 0, stream>>>(
      cm, mv, colsum_c, nullptr, xt_hi, xt_lo, partial, N / ZG);
  k_reduce<<<dim3(C * H / 4 / 256), blk, 0, stream>>>(
      partial, hidden1, ZG, (size_t)C * H, (size_t)C * H / 4, nullptr,
      h1hi, h1lo, nullptr, valid1);
  k_mfma_nt<<<dim3(C / 128, N / 64), blk, 0, stream>>>(
      xhi, xlo, h1hi, h1lo, scores, C);
  k_colstats<<<dim3(C), blk, 0, stream>>>(scores, colmax, colsumexp);
  k_mfma_genA<2><<<dim3(1, C / 128, ZG), blk, 0, stream>>>(
      scores, nullptr, colmax, colsumexp, xt_hi, xt_lo, partial, N / ZG);
  k_reduce<<<dim3(C * H / 4 / 256), blk, 0, stream>>>(
      partial, hidden_ps, ZG, (size_t)C * H, (size_t)C * H / 4, valid1,
      hpshi, hpslo, hnorm_ps, nullptr);
  k_mfma_nt<<<dim3(C / 128, N / 64), blk, 0, stream>>>(
      xhi, xlo, hpshi, hpslo, scores, C);
  k_cs_softmax<<<dim3(N), blk, 0, stream>>>(scores, xnorm, hnorm_ps, valid1,
                                            cshi, cslo);
  k_tsplit<<<dim3(C / 32), blk, 0, stream>>>(hidden_ps, hpst_hi, hpst_lo, C);
  k_mfma_kn<<<dim3(1, N / 128, ZK), blk, 0, stream>>>(
      cshi, cslo, hpst_hi, hpst_lo, partial, C, C / ZK);
  k_ps_tail<<<dim3(N / 16), blk, 0, stream>>>(
      partial, ZK, x, W_ps, b_ps, W_psb, b_psb, W_psf, b_psf,
      hbuf, hhat, hhathi, hhatlo, diagv, all_info);
  // --- hs branch ---
  k_snt<<<dim3(N / 128, N / 128), dim3(512), 0, stream>>>(
      hhathi, hhatlo, cand);
  k_rowtop2s<<<dim3(N / 4), blk, 0, stream>>>(cand, hhat, hbuf, hidden2,
                                              colsum_m);
  k_fin2t<<<dim3(N / 32), blk, 0, stream>>>(hbuf, diagv, colsum_m, hidden2,
                                            h2hi, h2lo, valid2f, h2t_hi, h2t_lo);
  k_flash<<<dim3(Z, N / 128), dim3(512), 0, stream>>>(
      hhathi, hhatlo, h2hi, h2lo, h2t_hi, h2t_lo, valid2f, partial, plsum,
      N / Z);
  k_hs_tail<<<dim3(N / 16), blk, 0, stream>>>(
      partial, plsum, Z, hbuf, all_info, W_hs, b_hs, W_hsf, b_hsf, W_hsb, b_hsb,
      W_in, b_in, W_out, b_out, out);
}

// Round 14
// 343.579 us; speedup vs baseline: 1.2761x; 1.0077x over previous
//
#include <hip/hip_runtime.h>
#include <hip/hip_fp16.h>
#include <math.h>

#define N 4096
#define C 512
#define H 128
#define PAD 40  // ushort row pitch for 32-col MFMA LDS staging tiles
#define WP 136  // ushort row pitch for full-K (128 col) LDS tiles
#define FWP 136 // ushort row pitch for flash Q/P tiles
#define SP 136  // ushort row pitch for S-tile scan buffer

typedef __attribute__((ext_vector_type(8))) short bf16x8;
typedef __attribute__((ext_vector_type(4))) float f32x4;

// ---------------- helpers ----------------

__device__ inline float wave_reduce_sum(float v) {
#pragma unroll
  for (int m = 32; m; m >>= 1) v += __shfl_xor(v, m);
  return v;
}

__device__ inline float lrelu(float v) { return v > 0.f ? v : 0.01f * v; }

__device__ inline bool better(float v, int j, float w, int k) {
  return (v > w) || (v == w && j < k);
}

__device__ inline void top3_ins(float v, int j, float& v0, int& j0,
                                float& v1, int& j1, float& v2, int& j2) {
  if (better(v, j, v0, j0)) { v2 = v1; j2 = j1; v1 = v0; j1 = j0; v0 = v; j0 = j; }
  else if (better(v, j, v1, j1)) { v2 = v1; j2 = j1; v1 = v; j1 = j; }
  else if (better(v, j, v2, j2)) { v2 = v; j2 = j; }
}

__device__ inline void ins5(float s, int j, float v[5], int jx[5]) {
  if (!better(s, j, v[4], jx[4])) return;
  if (better(s, j, v[0], jx[0])) {
    v[4]=v[3]; jx[4]=jx[3]; v[3]=v[2]; jx[3]=jx[2]; v[2]=v[1]; jx[2]=jx[1];
    v[1]=v[0]; jx[1]=jx[0]; v[0]=s; jx[0]=j;
  } else if (better(s, j, v[1], jx[1])) {
    v[4]=v[3]; jx[4]=jx[3]; v[3]=v[2]; jx[3]=jx[2]; v[2]=v[1]; jx[2]=jx[1];
    v[1]=s; jx[1]=j;
  } else if (better(s, j, v[2], jx[2])) {
    v[4]=v[3]; jx[4]=jx[3]; v[3]=v[2]; jx[3]=jx[2]; v[2]=s; jx[2]=j;
  } else if (better(s, j, v[3], jx[3])) {
    v[4]=v[3]; jx[4]=jx[3]; v[3]=s; jx[3]=j;
  } else {
    v[4]=s; jx[4]=j;
  }
}

// top-5 on packed u32 keys (larger = better; col tie-break embedded in key)
__device__ inline void ins5u(unsigned s, unsigned v[5]) {
  if (s <= v[4]) return;
  if (s > v[0]) { v[4]=v[3]; v[3]=v[2]; v[2]=v[1]; v[1]=v[0]; v[0]=s; }
  else if (s > v[1]) { v[4]=v[3]; v[3]=v[2]; v[2]=v[1]; v[1]=s; }
  else if (s > v[2]) { v[4]=v[3]; v[3]=v[2]; v[2]=s; }
  else if (s > v[3]) { v[4]=v[3]; v[3]=s; }
  else { v[4]=s; }
}

__device__ inline unsigned short f2bf(float f) {
  unsigned u = __float_as_uint(f);
  unsigned r = u + 0x7fffu + ((u >> 16) & 1u);
  return (unsigned short)(r >> 16);
}
__device__ inline float bf2f(unsigned short h) {
  return __uint_as_float(((unsigned)h) << 16);
}

// ---- x prep: linear pairs + xnorm + transposed pairs + workspace zeroing ----
__global__ __launch_bounds__(256) void k_xprep(
    const float* __restrict__ in, unsigned short* __restrict__ hi,
    unsigned short* __restrict__ lo, float* __restrict__ nrm,
    unsigned short* __restrict__ thi, unsigned short* __restrict__ tlo,
    float* __restrict__ hidden2, float* __restrict__ colsum_c,
    float* __restrict__ colsum_m) {
  __shared__ float tile[32][132];
  int r0 = blockIdx.x * 32, tid = threadIdx.x;
  float4 zf = {0.f, 0.f, 0.f, 0.f};
#pragma unroll
  for (int q = 0; q < 4; q++) {
    size_t zi = ((size_t)blockIdx.x * 1024 + q * 256 + tid) * 4;
    *(float4*)&hidden2[zi] = zf;
  }
  if (blockIdx.x == 0 && tid < 128) *(float4*)&colsum_c[tid * 4] = zf;
  if (blockIdx.x == 1) {
#pragma unroll
    for (int q = 0; q < 4; q++) *(float4*)&colsum_m[(q * 256 + tid) * 4] = zf;
  }
#pragma unroll
  for (int q = 0; q < 4; q++) {
    int f = q * 256 + tid;
    int row = f >> 5, ch = f & 31;
    size_t gi = (size_t)(r0 + row) * 128 + ch * 4;
    float4 v = *(const float4*)&in[gi];
    *(float4*)&tile[row][ch * 4] = v;
    float vv[4] = {v.x, v.y, v.z, v.w};
    unsigned short hq[4], lq[4];
    float ss = 0.f;
#pragma unroll
    for (int c = 0; c < 4; c++) {
      ss += vv[c] * vv[c];
      hq[c] = f2bf(vv[c]);
      lq[c] = f2bf(vv[c] - bf2f(hq[c]));
    }
    uint2 ph = {(unsigned)hq[0] | ((unsigned)hq[1] << 16),
                (unsigned)hq[2] | ((unsigned)hq[3] << 16)};
    uint2 pl = {(unsigned)lq[0] | ((unsigned)lq[1] << 16),
                (unsigned)lq[2] | ((unsigned)lq[3] << 16)};
    *(uint2*)&hi[gi] = ph;
    *(uint2*)&lo[gi] = pl;
#pragma unroll
    for (int m = 16; m; m >>= 1) ss += __shfl_xor(ss, m);
    if ((tid & 31) == 0) nrm[r0 + row] = sqrtf(ss);
  }
  __syncthreads();
  int c = tid & 127, half = tid >> 7;
  unsigned short hh[16], ll[16];
#pragma unroll
  for (int rr = 0; rr < 16; rr++) {
    float v = tile[half * 16 + rr][c];
    hh[rr] = f2bf(v);
    ll[rr] = f2bf(v - bf2f(hh[rr]));
  }
  size_t off = (size_t)c * N + r0 + half * 16;
  uint4 ph0 = {(unsigned)hh[0] | ((unsigned)hh[1] << 16), (unsigned)hh[2] | ((unsigned)hh[3] << 16),
               (unsigned)hh[4] | ((unsigned)hh[5] << 16), (unsigned)hh[6] | ((unsigned)hh[7] << 16)};
  uint4 ph1 = {(unsigned)hh[8] | ((unsigned)hh[9] << 16), (unsigned)hh[10] | ((unsigned)hh[11] << 16),
               (unsigned)hh[12] | ((unsigned)hh[13] << 16), (unsigned)hh[14] | ((unsigned)hh[15] << 16)};
  uint4 pl0 = {(unsigned)ll[0] | ((unsigned)ll[1] << 16), (unsigned)ll[2] | ((unsigned)ll[3] << 16),
               (unsigned)ll[4] | ((unsigned)ll[5] << 16), (unsigned)ll[6] | ((unsigned)ll[7] << 16)};
  uint4 pl1 = {(unsigned)ll[8] | ((unsigned)ll[9] << 16), (unsigned)ll[10] | ((unsigned)ll[11] << 16),
               (unsigned)ll[12] | ((unsigned)ll[13] << 16), (unsigned)ll[14] | ((unsigned)ll[15] << 16)};
  *(uint4*)&thi[off] = ph0; *(uint4*)&thi[off + 8] = ph1;
  *(uint4*)&tlo[off] = pl0; *(uint4*)&tlo[off + 8] = pl1;
}

// transpose + split: in [R,128] fp32 -> thi/tlo [128,R] ushort
__global__ __launch_bounds__(256) void k_tsplit(const float* __restrict__ in,
                                                unsigned short* __restrict__ thi,
                                                unsigned short* __restrict__ tlo,
                                                int R) {
  __shared__ float tile[32][132];
  int r0 = blockIdx.x * 32, tid = threadIdx.x;
#pragma unroll
  for (int q = 0; q < 4; q++) {
    int f = q * 256 + tid;
    int row = f >> 5, ch = f & 31;
    *(float4*)&tile[row][ch * 4] = *(const float4*)&in[(size_t)(r0 + row) * 128 + ch * 4];
  }
  __syncthreads();
  int c = tid & 127, half = tid >> 7;
  unsigned short hh[16], ll[16];
#pragma unroll
  for (int rr = 0; rr < 16; rr++) {
    float v = tile[half * 16 + rr][c];
    hh[rr] = f2bf(v);
    ll[rr] = f2bf(v - bf2f(hh[rr]));
  }
  size_t off = (size_t)c * R + r0 + half * 16;
  uint4 ph0 = {(unsigned)hh[0] | ((unsigned)hh[1] << 16), (unsigned)hh[2] | ((unsigned)hh[3] << 16),
               (unsigned)hh[4] | ((unsigned)hh[5] << 16), (unsigned)hh[6] | ((unsigned)hh[7] << 16)};
  uint4 ph1 = {(unsigned)hh[8] | ((unsigned)hh[9] << 16), (unsigned)hh[10] | ((unsigned)hh[11] << 16),
               (unsigned)hh[12] | ((unsigned)hh[13] << 16), (unsigned)hh[14] | ((unsigned)hh[15] << 16)};
  uint4 pl0 = {(unsigned)ll[0] | ((unsigned)ll[1] << 16), (unsigned)ll[2] | ((unsigned)ll[3] << 16),
               (unsigned)ll[4] | ((unsigned)ll[5] << 16), (unsigned)ll[6] | ((unsigned)ll[7] << 16)};
  uint4 pl1 = {(unsigned)ll[8] | ((unsigned)ll[9] << 16), (unsigned)ll[10] | ((unsigned)ll[11] << 16),
               (unsigned)ll[12] | ((unsigned)ll[13] << 16), (unsigned)ll[14] | ((unsigned)ll[15] << 16)};
  *(uint4*)&thi[off] = ph0; *(uint4*)&thi[off + 8] = ph1;
  *(uint4*)&tlo[off] = pl0; *(uint4*)&tlo[off + 8] = pl1;
}

// ---------------- small kernels ----------------

__global__ __launch_bounds__(64) void k_colsum_s2c(
    const float* __restrict__ cm, const float* __restrict__ mv,
    float* __restrict__ colsum_c) {
  int c = blockIdx.x * 64 + threadIdx.x;
  int i0 = blockIdx.y * 256;
  float acc = 0.f;
  for (int i = i0; i < i0 + 256; i++) acc += cm[(size_t)i * C + c] * mv[i];
  atomicAdd(&colsum_c[c], acc);
}

__global__ __launch_bounds__(256) void k_colstats(const float* __restrict__ sc,
                                                  float* __restrict__ colmax,
                                                  float* __restrict__ colsum) {
  __shared__ float red[256];
  int c = blockIdx.x, t = threadIdx.x;
  float v[16];
  float m = -3e38f;
#pragma unroll
  for (int q = 0; q < 16; q++) {
    v[q] = sc[(size_t)(q * 256 + t) * C + c];
    m = fmaxf(m, v[q]);
  }
  red[t] = m; __syncthreads();
  for (int s = 128; s; s >>= 1) { if (t < s) red[t] = fmaxf(red[t], red[t + s]); __syncthreads(); }
  m = red[0]; __syncthreads();
  float sum = 0.f;
#pragma unroll
  for (int q = 0; q < 16; q++) sum += __expf(v[q] - m);
  red[t] = sum; __syncthreads();
  for (int s = 128; s; s >>= 1) { if (t < s) red[t] += red[t + s]; __syncthreads(); }
  if (t == 0) { colmax[c] = m; colsum[c] = red[0]; }
}

// row softmax of cos-sim -> bf16 hi/lo pairs
__global__ __launch_bounds__(256) void k_cs_softmax(
    const float* __restrict__ sc, const float* __restrict__ xnorm,
    const float* __restrict__ hnorm, const float* __restrict__ valid1,
    unsigned short* __restrict__ cshi, unsigned short* __restrict__ cslo) {
  __shared__ float red[256];
  int i = blockIdx.x, t = threadIdx.x;
  float xn = xnorm[i];
  float r0 = sc[(size_t)i * C + t], r1 = sc[(size_t)i * C + 256 + t];
  float d0 = xn * hnorm[t], d1 = xn * hnorm[256 + t];
  float c0 = r0 / (d0 == 0.f ? 1.f : d0);
  float c1 = r1 / (d1 == 0.f ? 1.f : d1);
  float s0 = (valid1[t] != 0.f) ? c0 : -3e38f;
  float s1 = (valid1[256 + t] != 0.f) ? c1 : -3e38f;
  red[t] = fmaxf(s0, s1); __syncthreads();
  for (int s = 128; s; s >>= 1) { if (t < s) red[t] = fmaxf(red[t], red[t + s]); __syncthreads(); }
  float m = red[0]; __syncthreads();
  float p0 = (s0 > -1e37f) ? __expf(s0 - m) : 0.f;
  float p1 = (s1 > -1e37f) ? __expf(s1 - m) : 0.f;
  red[t] = p0 + p1; __syncthreads();
  for (int s = 128; s; s >>= 1) { if (t < s) red[t] += red[t + s]; __syncthreads(); }
  float inv = 1.f / red[0];
  float a = p0 * inv, b = p1 * inv;
  unsigned short ha = f2bf(a), hb = f2bf(b);
  cshi[(size_t)i * C + t] = ha;
  cslo[(size_t)i * C + t] = f2bf(a - bf2f(ha));
  cshi[(size_t)i * C + 256 + t] = hb;
  cslo[(size_t)i * C + 256 + t] = f2bf(b - bf2f(hb));
}

// finalize hidden2 (32 rows/block) + h2hat pairs + valid2f + transposed pairs
__global__ __launch_bounds__(256) void k_fin2t(
    const float* __restrict__ h, const float* __restrict__ diagv,
    const float* __restrict__ colsum_m, float* __restrict__ hidden2,
    unsigned short* __restrict__ h2hi, unsigned short* __restrict__ h2lo,
    float* __restrict__ valid2f, unsigned short* __restrict__ thi,
    unsigned short* __restrict__ tlo) {
  __shared__ float tile[32][132];
  int j0 = blockIdx.x * 32, tid = threadIdx.x;
  int row = tid >> 3, c0 = (tid & 7) * 16;
  int j = j0 + row;
  float add = (colsum_m[j] != 0.f) ? diagv[j] : 0.f;
  float a16[16];
  float s = 0.f, ss = 0.f;
#pragma unroll
  for (int q = 0; q < 16; q++) {
    float a = hidden2[(size_t)j * H + c0 + q] + add * h[(size_t)j * H + c0 + q];
    a16[q] = a;
    s += a; ss += a * a;
  }
#pragma unroll
  for (int m = 4; m; m >>= 1) { s += __shfl_xor(s, m); ss += __shfl_xor(ss, m); }
  bool valid = (s != 0.f);
  float inv = (valid && ss > 0.f) ? (1.f / sqrtf(ss)) : 1.f;
  size_t base = (size_t)j * H + c0;
  unsigned short hh16[16], ll16[16];
#pragma unroll
  for (int q = 0; q < 16; q++) {
    a16[q] = valid ? a16[q] : 0.f;
    float va = a16[q] * inv;
    hh16[q] = f2bf(va);
    ll16[q] = f2bf(va - bf2f(hh16[q]));
    tile[row][c0 + q] = a16[q];
  }
#pragma unroll
  for (int q4 = 0; q4 < 4; q4++) {
    float4 fv = {a16[q4 * 4], a16[q4 * 4 + 1], a16[q4 * 4 + 2], a16[q4 * 4 + 3]};
    *(float4*)&hidden2[base + q4 * 4] = fv;
  }
  uint4 ph0 = {(unsigned)hh16[0] | ((unsigned)hh16[1] << 16), (unsigned)hh16[2] | ((unsigned)hh16[3] << 16),
               (unsigned)hh16[4] | ((unsigned)hh16[5] << 16), (unsigned)hh16[6] | ((unsigned)hh16[7] << 16)};
  uint4 ph1 = {(unsigned)hh16[8] | ((unsigned)hh16[9] << 16), (unsigned)hh16[10] | ((unsigned)hh16[11] << 16),
               (unsigned)hh16[12] | ((unsigned)hh16[13] << 16), (unsigned)hh16[14] | ((unsigned)hh16[15] << 16)};
  uint4 pl0 = {(unsigned)ll16[0] | ((unsigned)ll16[1] << 16), (unsigned)ll16[2] | ((unsigned)ll16[3] << 16),
               (unsigned)ll16[4] | ((unsigned)ll16[5] << 16), (unsigned)ll16[6] | ((unsigned)ll16[7] << 16)};
  uint4 pl1 = {(unsigned)ll16[8] | ((unsigned)ll16[9] << 16), (unsigned)ll16[10] | ((unsigned)ll16[11] << 16),
               (unsigned)ll16[12] | ((unsigned)ll16[13] << 16), (unsigned)ll16[14] | ((unsigned)ll16[15] << 16)};
  *(uint4*)&h2hi[base] = ph0; *(uint4*)&h2hi[base + 8] = ph1;
  *(uint4*)&h2lo[base] = pl0; *(uint4*)&h2lo[base + 8] = pl1;
  if ((tid & 7) == 0) valid2f[j] = valid ? 1.f : 0.f;
  __syncthreads();
  int c = tid & 127, half = tid >> 7;
  unsigned short th[16], tl[16];
#pragma unroll
  for (int rr = 0; rr < 16; rr++) {
    float v = tile[half * 16 + rr][c];
    th[rr] = f2bf(v);
    tl[rr] = f2bf(v - bf2f(th[rr]));
  }
  size_t off = (size_t)c * N + j0 + half * 16;
  uint4 tp0 = {(unsigned)th[0] | ((unsigned)th[1] << 16), (unsigned)th[2] | ((unsigned)th[3] << 16),
               (unsigned)th[4] | ((unsigned)th[5] << 16), (unsigned)th[6] | ((unsigned)th[7] << 16)};
  uint4 tp1 = {(unsigned)th[8] | ((unsigned)th[9] << 16), (unsigned)th[10] | ((unsigned)th[11] << 16),
               (unsigned)th[12] | ((unsigned)th[13] << 16), (unsigned)th[14] | ((unsigned)th[15] << 16)};
  uint4 tq0 = {(unsigned)tl[0] | ((unsigned)tl[1] << 16), (unsigned)tl[2] | ((unsigned)tl[3] << 16),
               (unsigned)tl[4] | ((unsigned)tl[5] << 16), (unsigned)tl[6] | ((unsigned)tl[7] << 16)};
  uint4 tq1 = {(unsigned)tl[8] | ((unsigned)tl[9] << 16), (unsigned)tl[10] | ((unsigned)tl[11] << 16),
               (unsigned)tl[12] | ((unsigned)tl[13] << 16), (unsigned)tl[14] | ((unsigned)tl[15] << 16)};
  *(uint4*)&thi[off] = tp0; *(uint4*)&thi[off + 8] = tp1;
  *(uint4*)&tlo[off] = tq0; *(uint4*)&tlo[off + 8] = tq1;
}

// ---------------- bf16x3 MFMA NT GEMM: A[64,128] @ B[128,128]^T, fp32 out ----
__global__ __launch_bounds__(256) void k_mfma_nt(
    const unsigned short* __restrict__ Ahi, const unsigned short* __restrict__ Alo,
    const unsigned short* __restrict__ Bhi, const unsigned short* __restrict__ Blo,
    float* __restrict__ out, int Nn) {
  __shared__ __align__(16) unsigned short sAh[64 * PAD];
  __shared__ __align__(16) unsigned short sAl[64 * PAD];
  __shared__ __align__(16) unsigned short sBh[128 * PAD];
  __shared__ __align__(16) unsigned short sBl[128 * PAD];
  int tid = threadIdx.x;
  int bm = blockIdx.y * 64, bn = blockIdx.x * 128;
  int lane = tid & 63, w = tid >> 6;
  int wm = (w & 1) * 32, wn = (w >> 1) * 64;
  int l15 = lane & 15, quad = lane >> 4;
  f32x4 zero = {0.f, 0.f, 0.f, 0.f};
  f32x4 acc[2][4];
#pragma unroll
  for (int mt = 0; mt < 2; mt++)
#pragma unroll
    for (int nt = 0; nt < 4; nt++) acc[mt][nt] = zero;

  for (int kt = 0; kt < 128; kt += 32) {
    {
      int row = tid >> 2, ch = tid & 3;
      size_t ga = (size_t)(bm + row) * 128 + kt + ch * 8;
      int ls = row * PAD + ch * 8;
      *(uint4*)&sAh[ls] = *(const uint4*)&Ahi[ga];
      *(uint4*)&sAl[ls] = *(const uint4*)&Alo[ga];
    }
#pragma unroll
    for (int q = 0; q < 2; q++) {
      int f = q * 256 + tid;
      int row = f >> 2, ch = f & 3;
      size_t gb = (size_t)(bn + row) * 128 + kt + ch * 8;
      int ls = row * PAD + ch * 8;
      *(uint4*)&sBh[ls] = *(const uint4*)&Bhi[gb];
      *(uint4*)&sBl[ls] = *(const uint4*)&Blo[gb];
    }
    __syncthreads();
    bf16x8 ah[2], al[2], bh[4], bl[4];
#pragma unroll
    for (int t = 0; t < 2; t++) {
      int ar = (wm + t * 16 + l15) * PAD + quad * 8;
      ah[t] = *(const bf16x8*)&sAh[ar];
      al[t] = *(const bf16x8*)&sAl[ar];
    }
#pragma unroll
    for (int t = 0; t < 4; t++) {
      int br = (wn + t * 16 + l15) * PAD + quad * 8;
      bh[t] = *(const bf16x8*)&sBh[br];
      bl[t] = *(const bf16x8*)&sBl[br];
    }
#pragma unroll
    for (int mt = 0; mt < 2; mt++)
#pragma unroll
      for (int nt = 0; nt < 4; nt++) {
        acc[mt][nt] = __builtin_amdgcn_mfma_f32_16x16x32_bf16(ah[mt], bh[nt], acc[mt][nt], 0, 0, 0);
        acc[mt][nt] = __builtin_amdgcn_mfma_f32_16x16x32_bf16(ah[mt], bl[nt], acc[mt][nt], 0, 0, 0);
        acc[mt][nt] = __builtin_amdgcn_mfma_f32_16x16x32_bf16(al[mt], bh[nt], acc[mt][nt], 0, 0, 0);
      }
    __syncthreads();
  }
#pragma unroll
  for (int mt = 0; mt < 2; mt++) {
#pragma unroll
    for (int nt = 0; nt < 4; nt++) {
      int col = bn + wn + nt * 16 + l15;
#pragma unroll
      for (int rg = 0; rg < 4; rg++) {
        int row = bm + wm + mt * 16 + quad * 4 + rg;
        out[(size_t)row * Nn + col] = acc[mt][nt][rg];
      }
    }
  }
}

// ---------------- S = hhat@hhat^T + fused quarter-row top-5 screen -----------
// S dumped as SORTABLE fp16 bits into LDS ALIASED over the dead staging
// buffers (40 KB arena instead of 75 KB) -> 3 blocks/CU instead of 1.
__global__ __launch_bounds__(512) void k_snt(
    const unsigned short* __restrict__ Ahi, const unsigned short* __restrict__ Alo,
    float2* __restrict__ cand) {
  __shared__ __align__(16) unsigned short smem[4 * 128 * PAD];
  unsigned short* sAh = smem;
  unsigned short* sAl = smem + 128 * PAD;
  unsigned short* sBh = smem + 2 * 128 * PAD;
  unsigned short* sBl = smem + 3 * 128 * PAD;
  unsigned short* sS  = smem;  // aliases staging; live only after final barrier
  int tid = threadIdx.x;
  int bm = blockIdx.y * 128, bn = blockIdx.x * 128;
  int lane = tid & 63, w = tid >> 6;
  int wm = (w & 3) * 32, wn = (w >> 2) * 64;
  int l15 = lane & 15, quad = lane >> 4;
  f32x4 zero = {0.f, 0.f, 0.f, 0.f};
  f32x4 acc[2][4];
#pragma unroll
  for (int mt = 0; mt < 2; mt++)
#pragma unroll
    for (int nt = 0; nt < 4; nt++) acc[mt][nt] = zero;

  for (int kt = 0; kt < 128; kt += 32) {
    {
      int row = tid >> 2, ch = tid & 3;
      size_t ga = (size_t)(bm + row) * 128 + kt + ch * 8;
      size_t gb = (size_t)(bn + row) * 128 + kt + ch * 8;
      int ls = row * PAD + ch * 8;
      *(uint4*)&sAh[ls] = *(const uint4*)&Ahi[ga];
      *(uint4*)&sAl[ls] = *(const uint4*)&Alo[ga];
      *(uint4*)&sBh[ls] = *(const uint4*)&Ahi[gb];
      *(uint4*)&sBl[ls] = *(const uint4*)&Alo[gb];
    }
    __syncthreads();
    bf16x8 ah[2], al[2], bh[4], bl[4];
#pragma unroll
    for (int t = 0; t < 2; t++) {
      int ar = (wm + t * 16 + l15) * PAD + quad * 8;
      ah[t] = *(const bf16x8*)&sAh[ar];
      al[t] = *(const bf16x8*)&sAl[ar];
    }
#pragma unroll
    for (int t = 0; t < 4; t++) {
      int br = (wn + t * 16 + l15) * PAD + quad * 8;
      bh[t] = *(const bf16x8*)&sBh[br];
      bl[t] = *(const bf16x8*)&sBl[br];
    }
#pragma unroll
    for (int mt = 0; mt < 2; mt++)
#pragma unroll
      for (int nt = 0; nt < 4; nt++) {
        acc[mt][nt] = __builtin_amdgcn_mfma_f32_16x16x32_bf16(ah[mt], bh[nt], acc[mt][nt], 0, 0, 0);
        acc[mt][nt] = __builtin_amdgcn_mfma_f32_16x16x32_bf16(ah[mt], bl[nt], acc[mt][nt], 0, 0, 0);
        acc[mt][nt] = __builtin_amdgcn_mfma_f32_16x16x32_bf16(al[mt], bh[nt], acc[mt][nt], 0, 0, 0);
      }
    __syncthreads();
  }
  // dump S tile as sortable fp16 bits (diag zeroed); staging is dead now
#pragma unroll
  for (int mt = 0; mt < 2; mt++)
#pragma unroll
    for (int nt = 0; nt < 4; nt++) {
      int coll = wn + nt * 16 + l15;
#pragma unroll
      for (int rg = 0; rg < 4; rg++) {
        int rowl = wm + mt * 16 + quad * 4 + rg;
        float v = (bm + rowl == bn + coll) ? 0.f : acc[mt][nt][rg];
        unsigned hb = (unsigned)__half_as_ushort(__float2half(v));
        hb ^= (hb & 0x8000u) ? 0xFFFFu : 0x8000u;
        sS[rowl * SP + coll] = (unsigned short)hb;
      }
    }
  __syncthreads();
  // serial top-5 scan on packed integer keys: thread -> quarter-row
  int r = tid >> 2, qf = tid & 3;
  const unsigned short* rowp = &sS[r * SP + qf * 32];
  int cbase = bn + qf * 32;
  unsigned k5[5] = {0u, 0u, 0u, 0u, 0u};
#pragma unroll
  for (int q = 0; q < 4; q++) {
    uint4 p = *(const uint4*)&rowp[q * 8];
    unsigned pk[4] = {p.x, p.y, p.z, p.w};
#pragma unroll
    for (int c2 = 0; c2 < 4; c2++) {
      int base = q * 8 + c2 * 2;
      unsigned e0 = ((pk[c2] & 0xffffu) << 5) | (unsigned)(31 - base);
      unsigned e1 = ((pk[c2] >> 16) << 5) | (unsigned)(31 - (base + 1));
      ins5u(e0, k5);
      ins5u(e1, k5);
    }
  }
  int slot = (bn >> 5) + qf;
  float2* cp = &cand[((size_t)(bm + r) * 128 + slot) * 5];
#pragma unroll
  for (int c2 = 0; c2 < 5; c2++) {
    unsigned key = k5[c2];
    int local = 31 - (int)(key & 31u);
    unsigned sb = key >> 5;
    unsigned hb = (sb & 0x8000u) ? (sb ^ 0x8000u) : (sb ^ 0xFFFFu);
    float val = __half2float(__ushort_as_half((unsigned short)hb));
    cp[c2] = {val, __int_as_float(cbase + local)};
  }
}

// -------- row top-k merge + exact fp32 rescore + fused scatter --------
__global__ __launch_bounds__(256) void k_rowtop2s(
    const float2* __restrict__ cand, const float* __restrict__ hhat,
    const float* __restrict__ h, float* __restrict__ hidden2,
    float* __restrict__ colsum_m) {
  int i = blockIdx.x * 4 + (threadIdx.x >> 6);
  int lane = threadIdx.x & 63;
  const float2* cr = &cand[(size_t)i * 640];
  float v[5] = {-3e38f, -3e38f, -3e38f, -3e38f, -3e38f};
  int jx[5] = {0x7fffffff, 0x7fffffff, 0x7fffffff, 0x7fffffff, 0x7fffffff};
#pragma unroll
  for (int c = 0; c < 10; c++) {
    float2 p = cr[lane * 10 + c];
    ins5(p.x, __float_as_int(p.y), v, jx);
  }
#pragma unroll
  for (int d = 1; d < 64; d <<= 1) {
    float fv[5]; int fj[5];
#pragma unroll
    for (int c = 0; c < 5; c++) { fv[c] = __shfl_xor(v[c], d); fj[c] = __shfl_xor(jx[c], d); }
#pragma unroll
    for (int c = 0; c < 5; c++) ins5(fv[c], fj[c], v, jx);
  }
  const float* hi = &hhat[(size_t)i * H];
  float b0 = -3e38f, b1 = -3e38f, b2 = -3e38f;
  int q0 = 0, q1 = 0, q2 = 0;
#pragma unroll
  for (int c = 0; c < 5; c++) {
    int j = jx[c];
    float s;
    if (j == i) {
      s = 0.f;
    } else {
      const float* hj = &hhat[(size_t)j * H];
      float p = hi[lane] * hj[lane] + hi[lane + 64] * hj[lane + 64];
      s = wave_reduce_sum(p);
    }
    top3_ins(s, j, b0, q0, b1, q1, b2, q2);
  }
  float h0 = h[(size_t)i * H + lane], h1 = h[(size_t)i * H + 64 + lane];
  float bv[3] = {b0, b1, b2};
  int qv[3] = {q0, q1, q2};
#pragma unroll
  for (int s = 0; s < 3; s++) {
    float vv = bv[s];
    int j = qv[s];
    atomicAdd(&hidden2[(size_t)j * H + lane], vv * h0);
    atomicAdd(&hidden2[(size_t)j * H + 64 + lane], vv * h1);
    if (lane == s) atomicAdd(&colsum_m[j], vv);
  }
}

// ---------------- flash-fused hs_pre numerator (ring double-buffer) ----------
__global__ __launch_bounds__(512) void k_flash(
    const unsigned short* __restrict__ Qhi, const unsigned short* __restrict__ Qlo,
    const unsigned short* __restrict__ Khi, const unsigned short* __restrict__ Klo,
    const unsigned short* __restrict__ Vthi, const unsigned short* __restrict__ Vtlo,
    const float* __restrict__ valid2f, float* __restrict__ partialU,
    float* __restrict__ plsum, int KVC) {
  __shared__ __align__(16) unsigned short sQh[128 * FWP];
  __shared__ __align__(16) unsigned short sQl[128 * FWP];
  __shared__ __align__(16) unsigned short sP[128 * FWP];
  __shared__ __align__(16) unsigned short sBh[2][128 * PAD];
  __shared__ __align__(16) unsigned short sBl[2][128 * PAD];
  __shared__ float lsum_s[128];
  int tid = threadIdx.x;
  int z = blockIdx.x;
  int bm = blockIdx.y * 128;
  int j0 = z * KVC;
  int lane = tid & 63, w = tid >> 6;
  int wm = (w & 3) * 32, wn = (w >> 2) * 64;
  int l15 = lane & 15, quad = lane >> 4;
  int srow = tid >> 2, sch = tid & 3;
  int sls = srow * PAD + sch * 8;
#pragma unroll
  for (int q = 0; q < 4; q++) {
    int f = q * 512 + tid;
    int row = f >> 4, ch = f & 15;
    size_t ga = (size_t)(bm + row) * 128 + ch * 8;
    int ls = row * FWP + ch * 8;
    *(uint4*)&sQh[ls] = *(const uint4*)&Qhi[ga];
    *(uint4*)&sQl[ls] = *(const uint4*)&Qlo[ga];
  }
  if (tid < 128) lsum_s[tid] = 0.f;
  {
    size_t a = (size_t)(j0 + srow) * 128 + sch * 8;
    uint4 rh = *(const uint4*)&Khi[a];
    uint4 rl = *(const uint4*)&Klo[a];
    __syncthreads();
    *(uint4*)&sBh[0][sls] = rh;
    *(uint4*)&sBl[0][sls] = rl;
  }
  __syncthreads();
  int cur = 0;
  f32x4 zero = {0.f, 0.f, 0.f, 0.f};
  f32x4 uacc[2][4];
#pragma unroll
  for (int mt = 0; mt < 2; mt++)
#pragma unroll
    for (int nt = 0; nt < 4; nt++) uacc[mt][nt] = zero;

  for (int jb = j0; jb < j0 + KVC; jb += 128) {
    float vm[4];
#pragma unroll
    for (int nt = 0; nt < 4; nt++) vm[nt] = valid2f[jb + wn + nt * 16 + l15];
    f32x4 qacc[2][4];
#pragma unroll
    for (int mt = 0; mt < 2; mt++)
#pragma unroll
      for (int nt = 0; nt < 4; nt++) qacc[mt][nt] = zero;
#pragma unroll
    for (int t = 0; t < 4; t++) {
      uint4 nrh, nrl;
      if (t < 3) {
        size_t a = (size_t)(jb + srow) * 128 + (t + 1) * 32 + sch * 8;
        nrh = *(const uint4*)&Khi[a];
        nrl = *(const uint4*)&Klo[a];
      } else {
        size_t a = (size_t)srow * N + jb + sch * 8;
        nrh = *(const uint4*)&Vthi[a];
        nrl = *(const uint4*)&Vtlo[a];
      }
      int kt = t * 32;
      bf16x8 ah[2], al[2], bh[4], bl[4];
#pragma unroll
      for (int tt = 0; tt < 2; tt++) {
        int ar = (wm + tt * 16 + l15) * FWP + kt + quad * 8;
        ah[tt] = *(const bf16x8*)&sQh[ar];
        al[tt] = *(const bf16x8*)&sQl[ar];
      }
#pragma unroll
      for (int tt = 0; tt < 4; tt++) {
        int br = (wn + tt * 16 + l15) * PAD + quad * 8;
        bh[tt] = *(const bf16x8*)&sBh[cur][br];
        bl[tt] = *(const bf16x8*)&sBl[cur][br];
      }
#pragma unroll
      for (int mt = 0; mt < 2; mt++)
#pragma unroll
        for (int nt = 0; nt < 4; nt++) {
          qacc[mt][nt] = __builtin_amdgcn_mfma_f32_16x16x32_bf16(ah[mt], bh[nt], qacc[mt][nt], 0, 0, 0);
          qacc[mt][nt] = __builtin_amdgcn_mfma_f32_16x16x32_bf16(ah[mt], bl[nt], qacc[mt][nt], 0, 0, 0);
          qacc[mt][nt] = __builtin_amdgcn_mfma_f32_16x16x32_bf16(al[mt], bh[nt], qacc[mt][nt], 0, 0, 0);
        }
      *(uint4*)&sBh[cur ^ 1][sls] = nrh;
      *(uint4*)&sBl[cur ^ 1][sls] = nrl;
      __syncthreads();
      cur ^= 1;
    }
#pragma unroll
    for (int mt = 0; mt < 2; mt++) {
#pragma unroll
      for (int rg = 0; rg < 4; rg++) {
        int row = wm + mt * 16 + quad * 4 + rg;
        float rs = 0.f;
#pragma unroll
        for (int nt = 0; nt < 4; nt++) {
          float e = (vm[nt] != 0.f) ? __expf(qacc[mt][nt][rg] - 1.f) : 0.f;
          rs += e;
          sP[row * FWP + wn + nt * 16 + l15] = f2bf(e);
        }
#pragma unroll
        for (int d = 1; d < 16; d <<= 1) rs += __shfl_xor(rs, d);
        if (l15 == 0) atomicAdd(&lsum_s[row], rs);
      }
    }
    __syncthreads();
#pragma unroll
    for (int t = 0; t < 4; t++) {
      uint4 nrh = {0, 0, 0, 0}, nrl = {0, 0, 0, 0};
      bool have;
      if (t < 3) {
        have = true;
        size_t a = (size_t)srow * N + jb + (t + 1) * 32 + sch * 8;
        nrh = *(const uint4*)&Vthi[a];
        nrl = *(const uint4*)&Vtlo[a];
      } else {
        have = (jb + 128 < j0 + KVC);
        if (have) {
          size_t a = (size_t)(jb + 128 + srow) * 128 + sch * 8;
          nrh = *(const uint4*)&Khi[a];
          nrl = *(const uint4*)&Klo[a];
        }
      }
      int kt = t * 32;
      bf16x8 pa[2], vh[4], vl[4];
#pragma unroll
      for (int tt = 0; tt < 2; tt++) {
        int ar = (wm + tt * 16 + l15) * FWP + kt + quad * 8;
        pa[tt] = *(const bf16x8*)&sP[ar];
      }
#pragma unroll
      for (int tt = 0; tt < 4; tt++) {
        int br = (wn + tt * 16 + l15) * PAD + quad * 8;
        vh[tt] = *(const bf16x8*)&sBh[cur][br];
        vl[tt] = *(const bf16x8*)&sBl[cur][br];
      }
#pragma unroll
      for (int mt = 0; mt < 2; mt++)
#pragma unroll
        for (int nt = 0; nt < 4; nt++) {
          uacc[mt][nt] = __builtin_amdgcn_mfma_f32_16x16x32_bf16(pa[mt], vh[nt], uacc[mt][nt], 0, 0, 0);
          uacc[mt][nt] = __builtin_amdgcn_mfma_f32_16x16x32_bf16(pa[mt], vl[nt], uacc[mt][nt], 0, 0, 0);
        }
      if (have) {
        *(uint4*)&sBh[cur ^ 1][sls] = nrh;
        *(uint4*)&sBl[cur ^ 1][sls] = nrl;
      }
      __syncthreads();
      cur ^= 1;
    }
  }
  float* pU = partialU + (size_t)z * N * 128;
#pragma unroll
  for (int mt = 0; mt < 2; mt++)
#pragma unroll
    for (int nt = 0; nt < 4; nt++) {
      int col = wn + nt * 16 + l15;
#pragma unroll
      for (int rg = 0; rg < 4; rg++) {
        int row = bm + wm + mt * 16 + quad * 4 + rg;
        pU[(size_t)row * 128 + col] = uacc[mt][nt][rg];
      }
    }
  if (tid < 128) plsum[(size_t)z * N + bm + tid] = lsum_s[tid];
}

// ---------------- bf16 MFMA KN GEMM (split-K): partial[z] = A @ B ------------
__global__ __launch_bounds__(256) void k_mfma_kn(
    const unsigned short* __restrict__ Ahi, const unsigned short* __restrict__ Alo,
    const unsigned short* __restrict__ Bthi, const unsigned short* __restrict__ Btlo,
    float* __restrict__ partial, int lda, int KC) {
  __shared__ __align__(16) unsigned short sAh[128 * PAD];
  __shared__ __align__(16) unsigned short sAl[128 * PAD];
  __shared__ __align__(16) unsigned short sBh[128 * PAD];
  __shared__ __align__(16) unsigned short sBl[128 * PAD];
  int tid = threadIdx.x;
  int bm = blockIdx.y * 128;
  int k0 = blockIdx.z * KC;
  int lane = tid & 63, w = tid >> 6;
  int wm = (w & 1) * 64, wn = (w >> 1) * 64;
  int l15 = lane & 15, quad = lane >> 4;
  f32x4 zero = {0.f, 0.f, 0.f, 0.f};
  f32x4 acc[4][4];
#pragma unroll
  for (int mt = 0; mt < 4; mt++)
#pragma unroll
    for (int nt = 0; nt < 4; nt++) acc[mt][nt] = zero;

  for (int kt = 0; kt < KC; kt += 32) {
#pragma unroll
    for (int q = 0; q < 2; q++) {
      int f = tid * 2 + q;
      int row = f >> 2, ch = f & 3;
      size_t ga = (size_t)(bm + row) * lda + k0 + kt + ch * 8;
      size_t gb = (size_t)row * lda + k0 + kt + ch * 8;
      int ls = row * PAD + ch * 8;
      *(uint4*)&sAh[ls] = *(const uint4*)&Ahi[ga];
      *(uint4*)&sAl[ls] = *(const uint4*)&Alo[ga];
      *(uint4*)&sBh[ls] = *(const uint4*)&Bthi[gb];
      *(uint4*)&sBl[ls] = *(const uint4*)&Btlo[gb];
    }
    __syncthreads();
    bf16x8 ah[4], al[4], bh[4], bl[4];
#pragma unroll
    for (int t = 0; t < 4; t++) {
      int ar = (wm + t * 16 + l15) * PAD + quad * 8;
      ah[t] = *(const bf16x8*)&sAh[ar];
      al[t] = *(const bf16x8*)&sAl[ar];
      int br = (wn + t * 16 + l15) * PAD + quad * 8;
      bh[t] = *(const bf16x8*)&sBh[br];
      bl[t] = *(const bf16x8*)&sBl[br];
    }
#pragma unroll
    for (int mt = 0; mt < 4; mt++)
#pragma unroll
      for (int nt = 0; nt < 4; nt++) {
        acc[mt][nt] = __builtin_amdgcn_mfma_f32_16x16x32_bf16(ah[mt], bh[nt], acc[mt][nt], 0, 0, 0);
        acc[mt][nt] = __builtin_amdgcn_mfma_f32_16x16x32_bf16(ah[mt], bl[nt], acc[mt][nt], 0, 0, 0);
        acc[mt][nt] = __builtin_amdgcn_mfma_f32_16x16x32_bf16(al[mt], bh[nt], acc[mt][nt], 0, 0, 0);
      }
    __syncthreads();
  }
  float* pp = partial + (size_t)blockIdx.z * N * 128;
#pragma unroll
  for (int mt = 0; mt < 4; mt++)
#pragma unroll
    for (int nt = 0; nt < 4; nt++) {
      int col = wn + nt * 16 + l15;
#pragma unroll
      for (int rg = 0; rg < 4; rg++) {
        int row = bm + wm + mt * 16 + quad * 4 + rg;
        pp[(size_t)row * 128 + col] = acc[mt][nt][rg];
      }
    }
}

// ---------------- bf16x3 MFMA genA GEMM (split-K) ----------------
template <int AMODE>
__global__ __launch_bounds__(256) void k_mfma_genA(
    const float* __restrict__ P, const float* __restrict__ mv,
    const float* __restrict__ col1, const float* __restrict__ col2,
    const unsigned short* __restrict__ Bthi, const unsigned short* __restrict__ Btlo,
    float* __restrict__ partial, int KC) {
  __shared__ __align__(16) unsigned short sAh[128 * PAD];
  __shared__ __align__(16) unsigned short sAl[128 * PAD];
  __shared__ __align__(16) unsigned short sBh[128 * PAD];
  __shared__ __align__(16) unsigned short sBl[128 * PAD];
  int tid = threadIdx.x;
  int bm = blockIdx.y * 128;
  int k0 = blockIdx.z * KC;
  int lane = tid & 63, w = tid >> 6;
  int wm = (w & 1) * 64, wn = (w >> 1) * 64;
  int l15 = lane & 15, quad = lane >> 4;
  f32x4 zero = {0.f, 0.f, 0.f, 0.f};
  f32x4 acc[4][4];
#pragma unroll
  for (int mt = 0; mt < 4; mt++)
#pragma unroll
    for (int nt = 0; nt < 4; nt++) acc[mt][nt] = zero;

  for (int kt = 0; kt < KC; kt += 32) {
    int kr = tid >> 3;
    int mc = (tid & 7) * 16;
    int k = k0 + kt + kr;
    float mvk = (AMODE == 1) ? mv[k] : 0.f;
#pragma unroll
    for (int q = 0; q < 4; q++) {
      int m0 = mc + q * 4;
      float4 pv = *(const float4*)&P[(size_t)k * C + bm + m0];
      float4 c1 = *(const float4*)&col1[bm + m0];
      float wv[4];
      if (AMODE == 1) {
        wv[0] = pv.x * mvk / (c1.x * pv.x + 1.f);
        wv[1] = pv.y * mvk / (c1.y * pv.y + 1.f);
        wv[2] = pv.z * mvk / (c1.z * pv.z + 1.f);
        wv[3] = pv.w * mvk / (c1.w * pv.w + 1.f);
      } else {
        float4 c2 = *(const float4*)&col2[bm + m0];
        wv[0] = __expf(pv.x - c1.x) / c2.x;
        wv[1] = __expf(pv.y - c1.y) / c2.y;
        wv[2] = __expf(pv.z - c1.z) / c2.z;
        wv[3] = __expf(pv.w - c1.w) / c2.w;
      }
#pragma unroll
      for (int j = 0; j < 4; j++) {
        unsigned short hh = f2bf(wv[j]);
        sAh[(m0 + j) * PAD + kr] = hh;
        sAl[(m0 + j) * PAD + kr] = f2bf(wv[j] - bf2f(hh));
      }
    }
#pragma unroll
    for (int q = 0; q < 2; q++) {
      int f = q * 256 + tid;
      int row = f >> 2, ch = f & 3;
      size_t gb = (size_t)row * N + k0 + kt + ch * 8;
      int ls = row * PAD + ch * 8;
      *(uint4*)&sBh[ls] = *(const uint4*)&Bthi[gb];
      *(uint4*)&sBl[ls] = *(const uint4*)&Btlo[gb];
    }
    __syncthreads();
    bf16x8 ah[4], al[4], bh[4], bl[4];
#pragma unroll
    for (int t = 0; t < 4; t++) {
      int ar = (wm + t * 16 + l15) * PAD + quad * 8;
      ah[t] = *(const bf16x8*)&sAh[ar];
      al[t] = *(const bf16x8*)&sAl[ar];
      int br = (wn + t * 16 + l15) * PAD + quad * 8;
      bh[t] = *(const bf16x8*)&sBh[br];
      bl[t] = *(const bf16x8*)&sBl[br];
    }
#pragma unroll
    for (int mt = 0; mt < 4; mt++)
#pragma unroll
      for (int nt = 0; nt < 4; nt++) {
        acc[mt][nt] = __builtin_amdgcn_mfma_f32_16x16x32_bf16(ah[mt], bh[nt], acc[mt][nt], 0, 0, 0);
        acc[mt][nt] = __builtin_amdgcn_mfma_f32_16x16x32_bf16(ah[mt], bl[nt], acc[mt][nt], 0, 0, 0);
        acc[mt][nt] = __builtin_amdgcn_mfma_f32_16x16x32_bf16(al[mt], bh[nt], acc[mt][nt], 0, 0, 0);
      }
    __syncthreads();
  }
  float* pp = partial + (size_t)blockIdx.z * C * 128;
#pragma unroll
  for (int mt = 0; mt < 4; mt++)
#pragma unroll
    for (int nt = 0; nt < 4; nt++) {
      int col = wn + nt * 16 + l15;
#pragma unroll
      for (int rg = 0; rg < 4; rg++) {
        int row = bm + wm + mt * 16 + quad * 4 + rg;
        pp[(size_t)row * 128 + col] = acc[mt][nt][rg];
      }
    }
}

// reduce split-K partials (C*H shapes); optional per-row scale; pair emission;
// row-norm / row-valid emission
__global__ __launch_bounds__(256) void k_reduce(
    const float* __restrict__ partial, float* __restrict__ out, int cnt,
    size_t slot, size_t size4, const float* __restrict__ scalem,
    unsigned short* __restrict__ hi, unsigned short* __restrict__ lo,
    float* __restrict__ nrmout, float* __restrict__ validout) {
  size_t idx = (size_t)blockIdx.x * 256 + threadIdx.x;
  if (idx >= size4) return;
  float4 s = {0, 0, 0, 0};
  for (int c = 0; c < cnt; c++) {
    float4 v = *(const float4*)&partial[c * slot + idx * 4];
    s.x += v.x; s.y += v.y; s.z += v.z; s.w += v.w;
  }
  if (scalem) {
    float sc = scalem[idx >> 5];
    s.x *= sc; s.y *= sc; s.z *= sc; s.w *= sc;
  }
  *(float4*)&out[idx * 4] = s;
  if (hi) {
    float vv[4] = {s.x, s.y, s.z, s.w};
    unsigned short h[4], l[4];
#pragma unroll
    for (int c = 0; c < 4; c++) {
      h[c] = f2bf(vv[c]);
      l[c] = f2bf(vv[c] - bf2f(h[c]));
    }
    uint2 ph = {(unsigned)h[0] | ((unsigned)h[1] << 16),
                (unsigned)h[2] | ((unsigned)h[3] << 16)};
    uint2 pl = {(unsigned)l[0] | ((unsigned)l[1] << 16),
                (unsigned)l[2] | ((unsigned)l[3] << 16)};
    *(uint2*)&hi[idx * 4] = ph;
    *(uint2*)&lo[idx * 4] = pl;
  }
  if (nrmout || validout) {
    float rs = s.x + s.y + s.z + s.w;
    float rq = s.x * s.x + s.y * s.y + s.z * s.z + s.w * s.w;
#pragma unroll
    for (int m = 16; m; m >>= 1) { rs += __shfl_xor(rs, m); rq += __shfl_xor(rq, m); }
    if ((threadIdx.x & 31) == 0) {
      if (nrmout) nrmout[idx >> 5] = sqrtf(rq);
      if (validout) validout[idx >> 5] = (rs != 0.f) ? 1.f : 0.f;
    }
  }
}

// ---------------- fused branch-tail kernels (16 rows/block, 256 blocks) ------

#define LOAD_W(Wt)                                                        \
  do {                                                                    \
    _Pragma("unroll") for (int q = 0; q < 16; q++) {                      \
      int f = q * 256 + tid;                                              \
      int wr = f >> 5, wc = (f & 31) * 4;                                 \
      float4 wv = *(const float4*)&(Wt)[(size_t)wr * 128 + wc];           \
      float ww[4] = {wv.x, wv.y, wv.z, wv.w};                             \
      _Pragma("unroll") for (int c = 0; c < 4; c++) {                     \
        unsigned short hh = f2bf(ww[c]);                                  \
        sWh[wr * WP + wc + c] = hh;                                       \
        sWl[wr * WP + wc + c] = f2bf(ww[c] - bf2f(hh));                   \
      }                                                                   \
    }                                                                     \
  } while (0)

// 16-row GEMM: each wave owns a 16x32 quadrant (cn = w*32, nt<2)
#define GEMM16(accv)                                                              \
  do {                                                                            \
    _Pragma("unroll") for (int nt = 0; nt < 2; nt++) accv[nt] = zero;             \
    _Pragma("unroll") for (int kt = 0; kt < 128; kt += 32) {                      \
      bf16x8 ah = *(const bf16x8*)&sAh[l15 * WP + kt + quad * 8];                 \
      bf16x8 al = *(const bf16x8*)&sAl[l15 * WP + kt + quad * 8];                 \
      _Pragma("unroll") for (int nt = 0; nt < 2; nt++) {                          \
        int br = (cn + nt * 16 + l15) * WP + kt + quad * 8;                       \
        bf16x8 bh = *(const bf16x8*)&sWh[br];                                     \
        bf16x8 bl = *(const bf16x8*)&sWl[br];                                     \
        accv[nt] = __builtin_amdgcn_mfma_f32_16x16x32_bf16(ah, bh, accv[nt], 0, 0, 0); \
        accv[nt] = __builtin_amdgcn_mfma_f32_16x16x32_bf16(ah, bl, accv[nt], 0, 0, 0); \
        accv[nt] = __builtin_amdgcn_mfma_f32_16x16x32_bf16(al, bh, accv[nt], 0, 0, 0); \
      }                                                                           \
    }                                                                             \
  } while (0)

// ps tail: ps_pre = sum_z partial; p_shared = lin(ps_pre,W_ps);
// h = x - lin(p_shared,W_psb); out_ps -> all_info; hhat/pairs/diagv from h.
__global__ __launch_bounds__(256) void k_ps_tail(
    const float* __restrict__ partial, int zcnt, const float* __restrict__ x,
    const float* __restrict__ W_ps, const float* __restrict__ b_ps,
    const float* __restrict__ W_psb, const float* __restrict__ b_psb,
    const float* __restrict__ W_psf, const float* __restrict__ b_psf,
    float* __restrict__ hbuf, float* __restrict__ hhat,
    unsigned short* __restrict__ hhi, unsigned short* __restrict__ hlo,
    float* __restrict__ diagv, float* __restrict__ all_info) {
  __shared__ __align__(16) unsigned short sWh[128 * WP];
  __shared__ __align__(16) unsigned short sWl[128 * WP];
  __shared__ __align__(16) unsigned short sAh[16 * WP];
  __shared__ __align__(16) unsigned short sAl[16 * WP];
  __shared__ __align__(16) float sF[16][132];
  int tid = threadIdx.x;
  int bm = blockIdx.x * 16;
  int lane = tid & 63, w = tid >> 6;
  int cn = w * 32;
  int l15 = lane & 15, quad = lane >> 4;
  f32x4 zero = {0.f, 0.f, 0.f, 0.f};
  f32x4 acc[2];

  // stage ps_pre tile (sum of split-K partials) -> pairs
  {
    int row = tid >> 4, c0 = (tid & 15) * 8;
    size_t off0 = (size_t)(bm + row) * 128 + c0;
#pragma unroll
    for (int q = 0; q < 2; q++) {
      float vv[4] = {0.f, 0.f, 0.f, 0.f};
      for (int z = 0; z < zcnt; z++) {
        float4 v = *(const float4*)&partial[(size_t)z * N * H + off0 + q * 4];
        vv[0] += v.x; vv[1] += v.y; vv[2] += v.z; vv[3] += v.w;
      }
#pragma unroll
      for (int c = 0; c < 4; c++) {
        unsigned short hh = f2bf(vv[c]);
        sAh[row * WP + c0 + q * 4 + c] = hh;
        sAl[row * WP + c0 + q * 4 + c] = f2bf(vv[c] - bf2f(hh));
      }
    }
  }
  LOAD_W(W_ps);
  __syncthreads();
  GEMM16(acc);  // p_shared (pre-bias)
  __syncthreads();
#pragma unroll
  for (int nt = 0; nt < 2; nt++) {
    int col = cn + nt * 16 + l15;
    float bv = b_ps[col];
#pragma unroll
    for (int rg = 0; rg < 4; rg++) {
      int row = quad * 4 + rg;
      float v = acc[nt][rg] + bv;
      unsigned short hh = f2bf(v);
      sAh[row * WP + col] = hh;
      sAl[row * WP + col] = f2bf(v - bf2f(hh));
    }
  }
  LOAD_W(W_psb);
  __syncthreads();
  GEMM16(acc);  // p_back (pre-bias)
#pragma unroll
  for (int nt = 0; nt < 2; nt++) {
    int col = cn + nt * 16 + l15;
    float bv = b_psb[col];
#pragma unroll
    for (int rg = 0; rg < 4; rg++) {
      int row = quad * 4 + rg;
      size_t off = (size_t)(bm + row) * 128 + col;
      float hv = x[off] - (acc[nt][rg] + bv);
      hbuf[off] = hv;
      sF[row][col] = hv;
    }
  }
  __syncthreads();
  // hhat substage (reads sF)
  {
    int row = tid >> 4, c0 = (tid & 15) * 8;
    float hv8[8];
    float ssp = 0.f;
#pragma unroll
    for (int q = 0; q < 8; q++) {
      float v = sF[row][c0 + q];
      hv8[q] = v;
      ssp += v * v;
    }
    ssp += __shfl_xor(ssp, 1);
    ssp += __shfl_xor(ssp, 2);
    ssp += __shfl_xor(ssp, 4);
    ssp += __shfl_xor(ssp, 8);
    float ss = ssp;
    float hn = sqrtf(ss);
    float den = hn * hn;
    float dg = (den == 0.f) ? 0.f : ss / den;
    float inv = (ss > 0.f) ? (1.f / hn) : 1.f;
    size_t base = (size_t)(bm + row) * H + c0;
    float va8[8];
    unsigned short hh8[8], ll8[8];
#pragma unroll
    for (int q = 0; q < 8; q++) {
      va8[q] = hv8[q] * inv;
      hh8[q] = f2bf(va8[q]);
      ll8[q] = f2bf(va8[q] - bf2f(hh8[q]));
    }
#pragma unroll
    for (int q4 = 0; q4 < 2; q4++) {
      float4 fv = {va8[q4 * 4], va8[q4 * 4 + 1], va8[q4 * 4 + 2], va8[q4 * 4 + 3]};
      *(float4*)&hhat[base + q4 * 4] = fv;
    }
    uint4 ph = {(unsigned)hh8[0] | ((unsigned)hh8[1] << 16), (unsigned)hh8[2] | ((unsigned)hh8[3] << 16),
                (unsigned)hh8[4] | ((unsigned)hh8[5] << 16), (unsigned)hh8[6] | ((unsigned)hh8[7] << 16)};
    uint4 pl = {(unsigned)ll8[0] | ((unsigned)ll8[1] << 16), (unsigned)ll8[2] | ((unsigned)ll8[3] << 16),
                (unsigned)ll8[4] | ((unsigned)ll8[5] << 16), (unsigned)ll8[6] | ((unsigned)ll8[7] << 16)};
    *(uint4*)&hhi[base] = ph;
    *(uint4*)&hlo[base] = pl;
    if ((tid & 15) == 0) diagv[bm + row] = dg;
  }
  LOAD_W(W_psf);
  __syncthreads();
  GEMM16(acc);  // out_ps (pre-bias)
#pragma unroll
  for (int nt = 0; nt < 2; nt++) {
    int col = cn + nt * 16 + l15;
    float bv = b_psf[col];
#pragma unroll
    for (int rg = 0; rg < 4; rg++) {
      int row = quad * 4 + rg;
      size_t off = (size_t)(bm + row) * 128 + col;
      all_info[off] = lrelu(acc[nt][rg] + bv);
    }
  }
}

// hs tail: hs_pre = (sum_z partialU)/lsum; h_shared = lin(hs_pre,W_hs);
// all = all_info + lrelu(lin(h_shared,W_hsf)); indiv = h - lin(h_shared,W_hsb);
// all += lrelu(lin(indiv,W_in)); out = all @ W_out + b.
__global__ __launch_bounds__(256) void k_hs_tail(
    const float* __restrict__ partial, const float* __restrict__ plsum, int zcnt,
    const float* __restrict__ hbuf, const float* __restrict__ all_info,
    const float* __restrict__ W_hs, const float* __restrict__ b_hs,
    const float* __restrict__ W_hsf, const float* __restrict__ b_hsf,
    const float* __restrict__ W_hsb, const float* __restrict__ b_hsb,
    const float* __restrict__ W_in, const float* __restrict__ b_in,
    const float* __restrict__ W_out, const float* __restrict__ b_out,
    float* __restrict__ out) {
  __shared__ __align__(16) unsigned short sWh[128 * WP];
  __shared__ __align__(16) unsigned short sWl[128 * WP];
  __shared__ __align__(16) unsigned short sAh[16 * WP];
  __shared__ __align__(16) unsigned short sAl[16 * WP];
  __shared__ __align__(16) float sF[16][132];
  int tid = threadIdx.x;
  int bm = blockIdx.x * 16;
  int lane = tid & 63, w = tid >> 6;
  int cn = w * 32;
  int l15 = lane & 15, quad = lane >> 4;
  f32x4 zero = {0.f, 0.f, 0.f, 0.f};
  f32x4 acc[2];
  float allv[2][4];

  // stage hs_pre tile: sum of split-KV partials / total lsum
  {
    int row = tid >> 4, c0 = (tid & 15) * 8;
    float d = 0.f;
    for (int z = 0; z < zcnt; z++) d += plsum[(size_t)z * N + bm + row];
    float sc = 1.f / d;
    size_t off0 = (size_t)(bm + row) * 128 + c0;
#pragma unroll
    for (int q = 0; q < 2; q++) {
      float vv[4] = {0.f, 0.f, 0.f, 0.f};
      for (int z = 0; z < zcnt; z++) {
        float4 v = *(const float4*)&partial[(size_t)z * N * H + off0 + q * 4];
        vv[0] += v.x; vv[1] += v.y; vv[2] += v.z; vv[3] += v.w;
      }
#pragma unroll
      for (int c = 0; c < 4; c++) {
        float val = vv[c] * sc;
        unsigned short hh = f2bf(val);
        sAh[row * WP + c0 + q * 4 + c] = hh;
        sAl[row * WP + c0 + q * 4 + c] = f2bf(val - bf2f(hh));
      }
    }
  }
  LOAD_W(W_hs);
  __syncthreads();
  GEMM16(acc);  // h_shared (pre-bias)
  __syncthreads();
#pragma unroll
  for (int nt = 0; nt < 2; nt++) {
    int col = cn + nt * 16 + l15;
    float bv = b_hs[col];
#pragma unroll
    for (int rg = 0; rg < 4; rg++) {
      int row = quad * 4 + rg;
      float v = acc[nt][rg] + bv;
      unsigned short hh = f2bf(v);
      sAh[row * WP + col] = hh;
      sAl[row * WP + col] = f2bf(v - bf2f(hh));
    }
  }
  LOAD_W(W_hsf);
  __syncthreads();
  GEMM16(acc);  // out_hs (pre-bias)
#pragma unroll
  for (int nt = 0; nt < 2; nt++) {
    int col = cn + nt * 16 + l15;
    float bv = b_hsf[col];
#pragma unroll
    for (int rg = 0; rg < 4; rg++) {
      int row = quad * 4 + rg;
      size_t off = (size_t)(bm + row) * 128 + col;
      allv[nt][rg] = all_info[off] + lrelu(acc[nt][rg] + bv);
    }
  }
  __syncthreads();
  LOAD_W(W_hsb);
  __syncthreads();
  GEMM16(acc);  // h_back (pre-bias)
  float iv[2][4];
#pragma unroll
  for (int nt = 0; nt < 2; nt++) {
    int col = cn + nt * 16 + l15;
    float bv = b_hsb[col];
#pragma unroll
    for (int rg = 0; rg < 4; rg++) {
      int row = quad * 4 + rg;
      size_t off = (size_t)(bm + row) * 128 + col;
      iv[nt][rg] = hbuf[off] - (acc[nt][rg] + bv);
    }
  }
  __syncthreads();
#pragma unroll
  for (int nt = 0; nt < 2; nt++) {
    int col = cn + nt * 16 + l15;
#pragma unroll
    for (int rg = 0; rg < 4; rg++) {
      int row = quad * 4 + rg;
      unsigned short hh = f2bf(iv[nt][rg]);
      sAh[row * WP + col] = hh;
      sAl[row * WP + col] = f2bf(iv[nt][rg] - bf2f(hh));
    }
  }
  LOAD_W(W_in);
  __syncthreads();
  GEMM16(acc);  // out_indi (pre-bias)
#pragma unroll
  for (int nt = 0; nt < 2; nt++) {
    int col = cn + nt * 16 + l15;
    float bv = b_in[col];
#pragma unroll
    for (int rg = 0; rg < 4; rg++) {
      int row = quad * 4 + rg;
      allv[nt][rg] += lrelu(acc[nt][rg] + bv);
      sF[row][col] = allv[nt][rg];
    }
  }
  __syncthreads();
  {
    int row = tid >> 4, c0 = (tid & 15) * 8;
    float s = 0.f;
#pragma unroll
    for (int q = 0; q < 8; q++) s += sF[row][c0 + q] * W_out[c0 + q];
    s += __shfl_xor(s, 1);
    s += __shfl_xor(s, 2);
    s += __shfl_xor(s, 4);
    s += __shfl_xor(s, 8);
    if ((tid & 15) == 0) out[bm + row] = s + b_out[0];
  }
}

// ---------------- launch ----------------

extern "C" void kernel_launch(void* const* d_in, const int* in_sizes, int n_in,
                              void* d_out, int out_size, void* d_ws, size_t ws_size,
                              hipStream_t stream) {
  (void)in_sizes; (void)n_in; (void)out_size; (void)ws_size;
  const float* x   = (const float*)d_in[0];
  const float* cm  = (const float*)d_in[1];
  const float* mv  = (const float*)d_in[2];
  const float* W_ps = (const float*)d_in[3],  *b_ps = (const float*)d_in[4];
  const float* W_psf = (const float*)d_in[5], *b_psf = (const float*)d_in[6];
  const float* W_psb = (const float*)d_in[7], *b_psb = (const float*)d_in[8];
  const float* W_hs = (const float*)d_in[9],  *b_hs = (const float*)d_in[10];
  const float* W_hsf = (const float*)d_in[11], *b_hsf = (const float*)d_in[12];
  const float* W_hsb = (const float*)d_in[13], *b_hsb = (const float*)d_in[14];
  const float* W_in = (const float*)d_in[15], *b_in = (const float*)d_in[16];
  const float* W_out = (const float*)d_in[17], *b_out = (const float*)d_in[18];
  float* out = (float*)d_out;

  float* W = (float*)d_ws;
  size_t o = 0;
  auto alloc = [&](size_t n) { float* p = W + o; o += n; return p; };
  float* colsum_c = alloc(C);
  float* colmax   = alloc(C);
  float* colsumexp= alloc(C);
  float* valid1   = alloc(C);
  float* hnorm_ps = alloc(C);
  float* xnorm    = alloc(N);
  float* diagv    = alloc(N);
  float* colsum_m = alloc(N);
  float* valid2f  = alloc(N);
  float* plsum    = alloc((size_t)8 * N);
  float* hidden1  = alloc((size_t)C * H);
  float* hidden_ps= alloc((size_t)C * H);
  float* scores   = alloc((size_t)N * C);
  float* all_info = alloc((size_t)N * H);
  float* hbuf     = alloc((size_t)N * H);   // h
  float* hhat     = alloc((size_t)N * H);
  float* hidden2  = alloc((size_t)N * H);
  unsigned short* xhi    = (unsigned short*)alloc((size_t)N * H / 2);
  unsigned short* xlo    = (unsigned short*)alloc((size_t)N * H / 2);
  unsigned short* hhathi = (unsigned short*)alloc((size_t)N * H / 2);
  unsigned short* hhatlo = (unsigned short*)alloc((size_t)N * H / 2);
  unsigned short* h2hi   = (unsigned short*)alloc((size_t)N * H / 2);
  unsigned short* h2lo   = (unsigned short*)alloc((size_t)N * H / 2);
  unsigned short* h1hi   = (unsigned short*)alloc((size_t)C * H / 2);
  unsigned short* h1lo   = (unsigned short*)alloc((size_t)C * H / 2);
  unsigned short* hpshi  = (unsigned short*)alloc((size_t)C * H / 2);
  unsigned short* hpslo  = (unsigned short*)alloc((size_t)C * H / 2);
  unsigned short* cshi   = (unsigned short*)alloc((size_t)N * C / 2);
  unsigned short* cslo   = (unsigned short*)alloc((size_t)N * C / 2);
  unsigned short* hpst_hi= (unsigned short*)alloc((size_t)H * C / 2);
  unsigned short* hpst_lo= (unsigned short*)alloc((size_t)H * C / 2);
  unsigned short* h2t_hi = (unsigned short*)alloc((size_t)H * N / 2);
  unsigned short* h2t_lo = (unsigned short*)alloc((size_t)H * N / 2);
  unsigned short* xt_hi  = (unsigned short*)alloc((size_t)H * N / 2);
  unsigned short* xt_lo  = (unsigned short*)alloc((size_t)H * N / 2);
  float2* cand    = (float2*)alloc((size_t)N * 128 * 5 * 2);
  float* partial  = W + o;
  const int Z = 8;        // flash split-KV (8*N*128 fp32)
  const int ZG = 64;      // genA split-K (64*C*128 fp32); same region
  const int ZK = 8;       // cs-GEMM split-K (8*N*128 fp32); same region

  dim3 blk(256);
  // --- ps branch ---
  k_xprep<<<dim3(N / 32), blk, 0, stream>>>(x, xhi, xlo, xnorm, xt_hi, xt_lo,
                                            hidden2, colsum_c, colsum_m);
  k_colsum_s2c<<<dim3(C / 64, 16), dim3(64), 0, stream>>>(cm, mv, colsum_c);
  k_mfma_genA<1><<<dim3(1, C / 128, ZG), blk, 0, stream>>>(
      cm, mv, colsum_c, nullptr, xt_hi, xt_lo, partial, N / ZG);
  k_reduce<<<dim3(C * H / 4 / 256), blk, 0, stream>>>(
      partial, hidden1, ZG, (size_t)C * H, (size_t)C * H / 4, nullptr,
      h1hi, h1lo, nullptr, valid1);
  k_mfma_nt<<<dim3(C / 128, N / 64), blk, 0, stream>>>(
      xhi, xlo, h1hi, h1lo, scores, C);
  k_colstats<<<dim3(C), blk, 0, stream>>>(scores, colmax, colsumexp);
  k_mfma_genA<2><<<dim3(1, C / 128, ZG), blk, 0, stream>>>(
      scores, nullptr, colmax, colsumexp, xt_hi, xt_lo, partial, N / ZG);
  k_reduce<<<dim3(C * H / 4 / 256), blk, 0, stream>>>(
      partial, hidden_ps, ZG, (size_t)C * H, (size_t)C * H / 4, valid1,
      hpshi, hpslo, hnorm_ps, nullptr);
  k_mfma_nt<<<dim3(C / 128, N / 64), blk, 0, stream>>>(
      xhi, xlo, hpshi, hpslo, scores, C);
  k_cs_softmax<<<dim3(N), blk, 0, stream>>>(scores, xnorm, hnorm_ps, valid1,
                                            cshi, cslo);
  k_tsplit<<<dim3(C / 32), blk, 0, stream>>>(hidden_ps, hpst_hi, hpst_lo, C);
  k_mfma_kn<<<dim3(1, N / 128, ZK), blk, 0, stream>>>(
      cshi, cslo, hpst_hi, hpst_lo, partial, C, C / ZK);
  k_ps_tail<<<dim3(N / 16), blk, 0, stream>>>(
      partial, ZK, x, W_ps, b_ps, W_psb, b_psb, W_psf, b_psf,
      hbuf, hhat, hhathi, hhatlo, diagv, all_info);
  // --- hs branch ---
  k_snt<<<dim3(N / 128, N / 128), dim3(512), 0, stream>>>(
      hhathi, hhatlo, cand);
  k_rowtop2s<<<dim3(N / 4), blk, 0, stream>>>(cand, hhat, hbuf, hidden2,
                                              colsum_m);
  k_fin2t<<<dim3(N / 32), blk, 0, stream>>>(hbuf, diagv, colsum_m, hidden2,
                                            h2hi, h2lo, valid2f, h2t_hi, h2t_lo);
  k_flash<<<dim3(Z, N / 128), dim3(512), 0, stream>>>(
      hhathi, hhatlo, h2hi, h2lo, h2t_hi, h2t_lo, valid2f, partial, plsum,
      N / Z);
  k_hs_tail<<<dim3(N / 16), blk, 0, stream>>>(
      partial, plsum, Z, hbuf, all_info, W_hs, b_hs, W_hsf, b_hsf, W_hsb, b_hsb,
      W_in, b_in, W_out, b_out, out);
}